// Round 14
// baseline (1739.426 us; speedup 1.0000x reference)
//
#include <hip/hip_runtime.h>
#include <cmath>

// Problem constants
#define DIMC   1024
#define SEQC   512
#define BC     4
#define MC     2048      // MAXMEM
#define CTXC   2560      // MC + SEQC
#define HEADSC 16
#define DHC    64
#define VOCABC 32000
#define MAXC   512       // compact-slot capacity (live keys ~64)

using short8 = __attribute__((ext_vector_type(8))) short;
using f32x4  = __attribute__((ext_vector_type(4))) float;
using u16x4  = __attribute__((ext_vector_type(4))) unsigned short;
using u16x8  = __attribute__((ext_vector_type(8))) unsigned short;

__device__ __forceinline__ unsigned short f2bf(float f) {
    unsigned u = __float_as_uint(f);
    unsigned r = (u + 0x7fffu + ((u >> 16) & 1u)) >> 16;
    return (unsigned short)r;
}

__device__ __forceinline__ void glds16(const unsigned short* g, char* l) {
    __builtin_amdgcn_global_load_lds(
        (const __attribute__((address_space(1))) void*)g,
        (__attribute__((address_space(3))) void*)l, 16, 0, 0);
}

// ---------------- embed ----------------
__global__ __launch_bounds__(256) void embed_kernel(const int* __restrict__ tokens,
                                                    const float* __restrict__ emb,
                                                    float* __restrict__ x) {
    int row = blockIdx.x;
    int tok = tokens[row];
    const float4 v = *(const float4*)(emb + (size_t)tok * DIMC + threadIdx.x * 4);
    *(float4*)(x + (size_t)row * DIMC + threadIdx.x * 4) = v;
}

// ---------------- new_times + aux zero ----------------
__global__ __launch_bounds__(256) void times_init_kernel(const int* __restrict__ times,
                                                         float* __restrict__ out_times,
                                                         float* __restrict__ aux) {
    int i = blockIdx.x * 256 + threadIdx.x;
    if (i == 0) aux[0] = 0.0f;
    if (i < 4 * MC) {
        int d = i >> 11, m = i & (MC - 1);
        out_times[i] = (m < MC - SEQC) ? (float)(times[d * MC + SEQC + m] + SEQC)
                                       : (float)(MC - 1 - m);
    }
}

// ---------------- fused per-layer prep ----------------
#define PREP_MEM 8192
#define PREP_XC  10240
#define PREP_LN  12288
#define PREP_TOT 24576
__global__ __launch_bounds__(256) void prep_kernel(
    const float* __restrict__ mem_d, const float* __restrict__ x,
    const float* __restrict__ eW, const float* __restrict__ eb,
    float* __restrict__ exps, float* __restrict__ aux,
    unsigned short* __restrict__ mem_b, float* __restrict__ out_mems_d,
    const float* __restrict__ g1, const float* __restrict__ b1v,
    unsigned short* __restrict__ xn_b,
    const float* __restrict__ Wq, const float* __restrict__ Wkv,
    const float* __restrict__ Wo, const float* __restrict__ W1,
    const float* __restrict__ W2,
    unsigned short* __restrict__ wq_t, unsigned short* __restrict__ wkv_t,
    unsigned short* __restrict__ wo_t, unsigned short* __restrict__ w1_t,
    unsigned short* __restrict__ w2_t) {
    __shared__ float sh[1056];
    const int bid = blockIdx.x, tid = threadIdx.x;
    if (bid < PREP_MEM) {
        int row = bid;                       // b*2048 + m
        int m = row & 2047, b = row >> 11;
        const float4 v = *(const float4*)(mem_d + (size_t)row * DIMC + tid * 4);
        const float4 w = *(const float4*)(eW + tid * 4);
        float s = v.x * w.x + v.y * w.y + v.z * w.z + v.w * w.w;
        for (int off = 32; off; off >>= 1) s += __shfl_down(s, off, 64);
        int wid = tid >> 6, lane = tid & 63;
        if (lane == 0) sh[wid] = s;
        u16x4 o = { f2bf(v.x), f2bf(v.y), f2bf(v.z), f2bf(v.w) };
        *(u16x4*)(mem_b + (size_t)row * DIMC + tid * 4) = o;
        if (m >= SEQC)
            *(float4*)(out_mems_d + ((size_t)(b * MC + m - SEQC)) * DIMC + tid * 4) = v;
        __syncthreads();
        if (tid == 0) {
            float z = sh[0] + sh[1] + sh[2] + sh[3] + eb[0];
            float e = (float)MC / (1.0f + expf(-z));
            exps[row] = e;
            atomicAdd(aux, e * (1e-6f / (float)SEQC));
        }
    } else if (bid < PREP_XC) {
        int r = bid - PREP_MEM;              // b*512 + i
        int b = r >> 9, i = r & 511;
        const float4 v = *(const float4*)(x + (size_t)r * DIMC + tid * 4);
        *(float4*)(out_mems_d + ((size_t)(b * MC + MC - SEQC + i)) * DIMC + tid * 4) = v;
    } else if (bid < PREP_LN) {
        int row = bid - PREP_XC;
        const float4 v = *(const float4*)(x + (size_t)row * DIMC + tid * 4);
        float s = v.x + v.y + v.z + v.w;
        float q = v.x * v.x + v.y * v.y + v.z * v.z + v.w * v.w;
        for (int off = 32; off; off >>= 1) {
            s += __shfl_down(s, off, 64);
            q += __shfl_down(q, off, 64);
        }
        int wid = tid >> 6, lane = tid & 63;
        if (lane == 0) { sh[wid] = s; sh[4 + wid] = q; }
        __syncthreads();
        if (tid == 0) {
            float S = sh[0] + sh[1] + sh[2] + sh[3];
            float Q = sh[4] + sh[5] + sh[6] + sh[7];
            float mu = S / DIMC;
            float var = Q / DIMC - mu * mu;
            sh[8] = mu;
            sh[9] = rsqrtf(var + 1e-5f);
        }
        __syncthreads();
        float mu = sh[8], rstd = sh[9];
        const float4 gg = *(const float4*)(g1 + tid * 4);
        const float4 bb = *(const float4*)(b1v + tid * 4);
        u16x4 o = { f2bf((v.x - mu) * rstd * gg.x + bb.x),
                    f2bf((v.y - mu) * rstd * gg.y + bb.y),
                    f2bf((v.z - mu) * rstd * gg.z + bb.z),
                    f2bf((v.w - mu) * rstd * gg.w + bb.w) };
        *(u16x4*)(xn_b + (size_t)row * DIMC + tid * 4) = o;
    } else {
        int t = bid - PREP_LN;
        const float* W; unsigned short* Wt; int K, N, tx, ty;
        if (t < 1024)      { W = Wq;  Wt = wq_t;  K = 1024; N = 1024; tx = t & 31;  ty = t >> 5; }
        else if (t < 3072) { int u = t - 1024; W = Wkv; Wt = wkv_t; K = 1024; N = 2048; tx = u & 63;  ty = u >> 6; }
        else if (t < 4096) { int u = t - 3072; W = Wo;  Wt = wo_t;  K = 1024; N = 1024; tx = u & 31;  ty = u >> 5; }
        else if (t < 8192) { int u = t - 4096; W = W1;  Wt = w1_t;  K = 1024; N = 4096; tx = u & 127; ty = u >> 7; }
        else               { int u = t - 8192; W = W2;  Wt = w2_t;  K = 4096; N = 1024; tx = u & 31;  ty = u >> 5; }
        int n0 = tx * 32, k0 = ty * 32;
        int r = tid >> 3, c = (tid & 7) * 4;
        const float4 v = *(const float4*)(W + (size_t)(k0 + r) * N + n0 + c);
        sh[r * 33 + c] = v.x; sh[r * 33 + c + 1] = v.y;
        sh[r * 33 + c + 2] = v.z; sh[r * 33 + c + 3] = v.w;
        __syncthreads();
        u16x4 o = { f2bf(sh[(c + 0) * 33 + r]), f2bf(sh[(c + 1) * 33 + r]),
                    f2bf(sh[(c + 2) * 33 + r]), f2bf(sh[(c + 3) * 33 + r]) };
        *(u16x4*)(Wt + (size_t)(n0 + r) * K + k0 + c) = o;
    }
}

// ---------------- compact live memory keys (deterministic ballot scan) ----------------
__global__ __launch_bounds__(64) void compact_kernel(
    const float* __restrict__ exps, const int* __restrict__ times_d,
    int* __restrict__ cidx, float* __restrict__ em_c, int* __restrict__ cnt) {
    int b = blockIdx.x, lane = threadIdx.x;
    int c = 0;
    for (int it = 0; it < 32; ++it) {
        int j = it * 64 + lane;
        float e = exps[b * MC + j];
        float rr = (e - (float)times_d[j]) * (1.0f / 128.0f) + 1.0f;
        float em = fminf(fmaxf(rr, 0.0f), 1.0f);
        unsigned long long mk = __ballot(em > 0.0f);
        int pos = c + __popcll(mk & ((1ull << lane) - 1ull));
        if (em > 0.0f) {
            cidx[b * 2048 + pos] = j;
            em_c[b * 2048 + pos] = em;
        }
        c += __popcll(mk);
    }
    int padded = (c + 63) & ~63;
    int fill_to = padded < MAXC ? MAXC : padded;
    for (int p = c + lane; p < fill_to; p += 64) {
        cidx[b * 2048 + p] = 0;     // valid row; em=0 kills contribution
        em_c[b * 2048 + p] = 0.0f;
    }
    int tiles = padded >> 6;
    if (tiles > (MAXC >> 6)) tiles = MAXC >> 6;
    if (lane == 0) cnt[b] = tiles;
}

// ---------------- LayerNorm (fp32 in, bf16 out) — LN2 ----------------
__global__ __launch_bounds__(256) void ln_kernel(const float* __restrict__ in,
                                                 const float* __restrict__ g,
                                                 const float* __restrict__ b,
                                                 unsigned short* __restrict__ outb) {
    int row = blockIdx.x;
    int tid = threadIdx.x;
    const float4 v = *(const float4*)(in + (size_t)row * DIMC + tid * 4);
    float s = v.x + v.y + v.z + v.w;
    float q = v.x * v.x + v.y * v.y + v.z * v.z + v.w * v.w;
    for (int off = 32; off; off >>= 1) {
        s += __shfl_down(s, off, 64);
        q += __shfl_down(q, off, 64);
    }
    __shared__ float ss[4], sq[4];
    int wid = tid >> 6, lane = tid & 63;
    if (lane == 0) { ss[wid] = s; sq[wid] = q; }
    __syncthreads();
    if (tid == 0) {
        float S = ss[0] + ss[1] + ss[2] + ss[3];
        float Q = sq[0] + sq[1] + sq[2] + sq[3];
        float mu = S / DIMC;
        float var = Q / DIMC - mu * mu;
        ss[0] = mu;
        sq[0] = rsqrtf(var + 1e-5f);
    }
    __syncthreads();
    float mu = ss[0], rstd = sq[0];
    const float4 gg = *(const float4*)(g + tid * 4);
    const float4 bb = *(const float4*)(b + tid * 4);
    u16x4 o = { f2bf((v.x - mu) * rstd * gg.x + bb.x),
                f2bf((v.y - mu) * rstd * gg.y + bb.y),
                f2bf((v.z - mu) * rstd * gg.z + bb.z),
                f2bf((v.w - mu) * rstd * gg.w + bb.w) };
    *(u16x4*)(outb + (size_t)row * DIMC + tid * 4) = o;
}

// ---------------- weight convert + transpose (logits_W only) ----------------
__global__ __launch_bounds__(256) void wt_kernel(const float* __restrict__ W,
                                                 unsigned short* __restrict__ Wt,
                                                 int K, int N) {
    __shared__ float t[32][33];
    int tid = threadIdx.x;
    int n0 = blockIdx.x * 32, k0 = blockIdx.y * 32;
    int r = tid >> 3, c = (tid & 7) * 4;
    const float4 v = *(const float4*)(W + (size_t)(k0 + r) * N + n0 + c);
    t[r][c] = v.x; t[r][c + 1] = v.y; t[r][c + 2] = v.z; t[r][c + 3] = v.w;
    __syncthreads();
    u16x4 o = { f2bf(t[c + 0][r]), f2bf(t[c + 1][r]),
                f2bf(t[c + 2][r]), f2bf(t[c + 3][r]) };
    *(u16x4*)(Wt + (size_t)(n0 + r) * K + k0 + c) = o;
}

// ---------------- bf16 MFMA GEMM body — depth-2 counted-vmcnt raw-barrier pipeline ----------------
// Triple-buffered LDS: at compute(t), stages t+1 and t+2 are in flight.
// AMODE: 0 = A[r][K]; 2 = gather A rows via cidx.
// OMODE: 0 direct; 1 mem->ctx rows; 2 local->ctx rows; 3 local V transposed; 4 compact V transposed.
template<int AMODE, bool BIAS, bool GELU, bool RES, int OMODE, int RT>
__device__ __forceinline__ void gemm_body(
    unsigned short* As, unsigned short* Bs,
    const unsigned short* __restrict__ A, const int* __restrict__ gidx,
    const unsigned short* __restrict__ Wt, const float* __restrict__ bias,
    const float* __restrict__ res, float* __restrict__ Cf,
    unsigned short* __restrict__ Cb, int K, int N, int bx, int by) {
    constexpr int MF = RT / 32;
    const int tid = threadIdx.x;
    const int lane = tid & 63, wave = tid >> 6;
    const int row0 = by * RT, col0 = bx * 128;

    const int seg = tid & 3;
    const int rr0 = tid >> 2;
    const unsigned short* arow[RT / 64];
    #pragma unroll
    for (int p = 0; p < RT / 64; ++p) {
        int r = row0 + p * 64 + rr0;
        if (AMODE == 2) {
            int b = r >> 9, slot = r & (MAXC - 1);
            arow[p] = A + ((size_t)(b * 2048 + gidx[b * 2048 + slot])) * K;
        } else {
            arow[p] = A + (size_t)r * K;
        }
        arow[p] += seg * 8;
    }
    const unsigned short* brow[2];
    #pragma unroll
    for (int p = 0; p < 2; ++p)
        brow[p] = Wt + (size_t)(col0 + p * 64 + rr0) * K + seg * 8;

    char* lA = (char*)As + (tid & 192) * 16;
    char* lB = (char*)Bs + (tid & 192) * 16;

    auto stage = [&](int k0, int q) {
        char* a = lA + q * (RT * 64);
        glds16(arow[0] + k0, a);
        if (RT == 128) glds16(arow[1] + k0, a + 4096);
        char* bp = lB + q * 8192;
        glds16(brow[0] + k0, bp);
        glds16(brow[1] + k0, bp + 4096);
    };

    f32x4 acc[MF][4] = {};

    const int wr = (wave >> 1) * (RT / 2), wc = (wave & 1) * 64;
    const int fr = lane & 15;
    const int k8 = (lane >> 4) * 8;

    stage(0, 0);
    if (K > 32) stage(32, 1);
    int cur = 0;
    for (int k0 = 0; k0 < K; k0 += 32) {
        if (k0 + 64 < K) {
            int nb = cur + 2; if (nb >= 3) nb -= 3;
            stage(k0 + 64, nb);
            // drain stage(k0) only; stages k0+32, k0+64 stay in flight
            if (RT == 128) asm volatile("s_waitcnt vmcnt(8)" ::: "memory");
            else           asm volatile("s_waitcnt vmcnt(6)" ::: "memory");
        } else if (k0 + 32 < K) {
            if (RT == 128) asm volatile("s_waitcnt vmcnt(4)" ::: "memory");
            else           asm volatile("s_waitcnt vmcnt(3)" ::: "memory");
        } else {
            asm volatile("s_waitcnt vmcnt(0)" ::: "memory");
        }
        __builtin_amdgcn_s_barrier();
        __builtin_amdgcn_sched_barrier(0);
        const unsigned short* Ar = As + cur * (RT * 32) + (size_t)(wr + fr) * 32 + k8;
        const unsigned short* Br = Bs + cur * (128 * 32) + (size_t)(wc + fr) * 32 + k8;
        short8 a[MF], b[4];
        #pragma unroll
        for (int m = 0; m < MF; ++m) a[m] = *(const short8*)(Ar + m * 16 * 32);
        #pragma unroll
        for (int n = 0; n < 4; ++n) b[n] = *(const short8*)(Br + n * 16 * 32);
        #pragma unroll
        for (int m = 0; m < MF; ++m)
            #pragma unroll
            for (int n = 0; n < 4; ++n)
                acc[m][n] = __builtin_amdgcn_mfma_f32_16x16x32_bf16(a[m], b[n], acc[m][n], 0, 0, 0);
        __builtin_amdgcn_s_barrier();
        cur += 1; if (cur >= 3) cur -= 3;
    }

    const int orow = row0 + wr + (lane >> 4) * 4;
    const int ocol = col0 + wc + fr;
    if (OMODE >= 3) {
        #pragma unroll
        for (int n = 0; n < 4; ++n) {
            int c = ocol + n * 16;
            #pragma unroll
            for (int m = 0; m < MF; ++m) {
                int r0 = orow + m * 16;
                int b = r0 >> 9, i = r0 & 511;
                size_t addr = (OMODE == 3)
                    ? ((size_t)(b * 1024 + c)) * 512 + i
                    : ((size_t)(b * 1024 + c)) * MAXC + i;
                u16x4 o = { f2bf(acc[m][n][0]), f2bf(acc[m][n][1]),
                            f2bf(acc[m][n][2]), f2bf(acc[m][n][3]) };
                *(u16x4*)(Cb + addr) = o;
            }
        }
        return;
    }
    #pragma unroll
    for (int n = 0; n < 4; ++n) {
        int c = ocol + n * 16;
        float bv = BIAS ? bias[c] : 0.0f;
        #pragma unroll
        for (int m = 0; m < MF; ++m) {
            #pragma unroll
            for (int i = 0; i < 4; ++i) {
                int r0 = orow + m * 16 + i;
                size_t orr = r0;
                if (OMODE == 1) orr = (size_t)r0 + (size_t)(r0 >> 11) * 512;
                if (OMODE == 2) orr = (size_t)r0 + (size_t)(r0 >> 9) * 2048 + 2048;
                size_t idx = orr * N + c;
                float v = acc[m][n][i] + bv;
                if (GELU) v = 0.5f * v * (1.0f + erff(v * 0.70710678118f));
                if (RES) v += res[idx];
                if (Cf) Cf[idx] = v;
                if (Cb) Cb[idx] = f2bf(v);
            }
        }
    }
}

// Fused: Q(128) + local-K(128) + mem-K(512) + local-V transposed(128) + compact-V transposed(256)
__global__ __launch_bounds__(256) void qkv_gemm_kernel(
    const unsigned short* __restrict__ xn_b, const unsigned short* __restrict__ mem_b,
    const unsigned short* __restrict__ wq_t, const unsigned short* __restrict__ wkv_t,
    const int* __restrict__ cidx, const int* __restrict__ cnt,
    unsigned short* __restrict__ qb, unsigned short* __restrict__ kvb,
    unsigned short* __restrict__ vTl, unsigned short* __restrict__ vTc) {
    __shared__ unsigned short As[3 * 128 * 32];
    __shared__ unsigned short Bs[3 * 128 * 32];
    int id = blockIdx.x;
    if (id < 128) {
        gemm_body<0, false, false, false, 0, 128>(As, Bs, xn_b, nullptr, wq_t,
            nullptr, nullptr, nullptr, qb, 1024, 1024, id & 7, id >> 3);
    } else if (id < 256) {
        id -= 128;  // local rows -> ctx rows, K half of wkv
        gemm_body<0, false, false, false, 2, 128>(As, Bs, xn_b, nullptr, wkv_t,
            nullptr, nullptr, nullptr, kvb, 1024, 1024, id & 7, id >> 3);
    } else if (id < 768) {
        id -= 256;  // mem rows -> ctx rows, K half of wkv
        gemm_body<0, false, false, false, 1, 128>(As, Bs, mem_b, nullptr, wkv_t,
            nullptr, nullptr, nullptr, kvb, 1024, 1024, id & 7, id >> 3);
    } else if (id < 896) {
        id -= 768;  // local V -> vTl transposed
        gemm_body<0, false, false, false, 3, 128>(As, Bs, xn_b, nullptr,
            wkv_t + (size_t)1024 * 1024, nullptr, nullptr, nullptr, vTl,
            1024, 1024, id & 7, id >> 3);
    } else {
        id -= 896;  // compact V: gather mem rows by cidx -> vTc transposed
        int by = id >> 3;
        int b = (by * 64) >> 9, slot0 = (by * 64) & (MAXC - 1);
        if (slot0 >= cnt[b] * 64) return;
        gemm_body<2, false, false, false, 4, 64>(As, Bs, mem_b, cidx,
            wkv_t + (size_t)1024 * 1024, nullptr, nullptr, nullptr, vTc,
            1024, 1024, id & 7, by);
    }
}

// RT=64 GEMM with bias+residual, N=1024 (Wo and FFN2)
__global__ __launch_bounds__(256) void gemm64_kernel(
    const unsigned short* __restrict__ A, const unsigned short* __restrict__ Wt,
    const float* __restrict__ bias, const float* __restrict__ res,
    float* __restrict__ Cf, unsigned short* __restrict__ Cb, int K) {
    __shared__ unsigned short As[3 * 64 * 32];
    __shared__ unsigned short Bs[3 * 128 * 32];
    gemm_body<0, true, false, true, 0, 64>(As, Bs, A, nullptr, Wt, bias, res,
        Cf, Cb, K, 1024, blockIdx.x, blockIdx.y);
}

// FFN1: gelu, bf16 out
__global__ __launch_bounds__(256) void ffn1_kernel(
    const unsigned short* __restrict__ A, const unsigned short* __restrict__ Wt,
    const float* __restrict__ bias, unsigned short* __restrict__ Cb) {
    __shared__ unsigned short As[3 * 128 * 32];
    __shared__ unsigned short Bs[3 * 128 * 32];
    gemm_body<0, true, true, false, 0, 128>(As, Bs, A, nullptr, Wt, bias, nullptr,
        nullptr, Cb, 1024, 4096, blockIdx.x, blockIdx.y);
}

// ---------------- logits: 256x256 tile, 512 threads, 8 waves (2x4), depth-1 counted-vmcnt ----------------
__global__ __launch_bounds__(512, 2) void logits_kernel(
    const unsigned short* __restrict__ A, const unsigned short* __restrict__ Wt,
    const float* __restrict__ bias, float* __restrict__ Cf) {
    __shared__ unsigned short As[2 * 256 * 32];
    __shared__ unsigned short Bs[2 * 256 * 32];
    const int L = blockIdx.x;
    const int wid = (L & 7) * 125 + (L >> 3);
    const int ct = wid / 8, rt = wid & 7;
    const int row0 = rt * 256, col0 = ct * 256;
    const int tid = threadIdx.x;
    const int lane = tid & 63, wave = tid >> 6;

    const int seg = tid & 3;
    const int rr0 = tid >> 2;                 // 0..127
    const unsigned short* arow[2];
    const unsigned short* brow[2];
    #pragma unroll
    for (int p = 0; p < 2; ++p) {
        arow[p] = A + (size_t)(row0 + p * 128 + rr0) * 1024 + seg * 8;
        brow[p] = Wt + (size_t)(col0 + p * 128 + rr0) * 1024 + seg * 8;
    }
    char* lA = (char*)As + (tid & 448) * 16;  // wave-uniform base (8 waves)
    char* lB = (char*)Bs + (tid & 448) * 16;

    auto stage = [&](int k0, int q) {
        char* a = lA + q * 16384;
        char* bp = lB + q * 16384;
        glds16(arow[0] + k0, a);
        glds16(arow[1] + k0, a + 8192);
        glds16(brow[0] + k0, bp);
        glds16(brow[1] + k0, bp + 8192);
    };

    f32x4 acc[8][4] = {};
    const int wr = (wave >> 2) * 128, wc = (wave & 3) * 64;
    const int fr = lane & 15;
    const int k8 = (lane >> 4) * 8;

    stage(0, 0);
    int cur = 0;
    for (int k0 = 0; k0 < 1024; k0 += 32) {
        if (k0 + 32 < 1024) {
            stage(k0 + 32, cur ^ 1);
            asm volatile("s_waitcnt vmcnt(4)" ::: "memory");
        } else {
            asm volatile("s_waitcnt vmcnt(0)" ::: "memory");
        }
        __builtin_amdgcn_s_barrier();
        __builtin_amdgcn_sched_barrier(0);
        const unsigned short* Ar = As + cur * 8192 + (size_t)(wr + fr) * 32 + k8;
        const unsigned short* Br = Bs + cur * 8192 + (size_t)(wc + fr) * 32 + k8;
        short8 a[8], b[4];
        #pragma unroll
        for (int m = 0; m < 8; ++m) a[m] = *(const short8*)(Ar + m * 16 * 32);
        #pragma unroll
        for (int n = 0; n < 4; ++n) b[n] = *(const short8*)(Br + n * 16 * 32);
        #pragma unroll
        for (int m = 0; m < 8; ++m)
            #pragma unroll
            for (int n = 0; n < 4; ++n)
                acc[m][n] = __builtin_amdgcn_mfma_f32_16x16x32_bf16(a[m], b[n], acc[m][n], 0, 0, 0);
        __builtin_amdgcn_s_barrier();
        cur ^= 1;
    }

    const int orow = row0 + wr + (lane >> 4) * 4;
    const int ocol = col0 + wc + fr;
    #pragma unroll
    for (int n = 0; n < 4; ++n) {
        int c = ocol + n * 16;
        float bv = bias[c];
        #pragma unroll
        for (int m = 0; m < 8; ++m) {
            #pragma unroll
            for (int i = 0; i < 4; ++i)
                Cf[(size_t)(orow + m * 16 + i) * VOCABC + c] = acc[m][n][i] + bv;
        }
    }
}

// ---------------- 3-phase MFMA flash attention — 256-thr/64-q blocks, 2 blocks/CU ----------------
// grid = 512 (8 qt x 16 h x 4 b), decoded so same-(h,b) blocks land on the same XCD.
// counted-vmcnt raw-barrier pipeline: stage(t+1) stays in flight across barriers.
__global__ __launch_bounds__(256) void attn_mfma_kernel(
    const unsigned short* __restrict__ qb,
    const unsigned short* __restrict__ kvb,   // K-only [b][2560][1024]
    const unsigned short* __restrict__ vTl,   // [b*1024+d][512] local V transposed
    const unsigned short* __restrict__ vTc,   // [b*1024+d][MAXC] compact V transposed
    const int* __restrict__ cidx,
    const float* __restrict__ em_c,
    const int* __restrict__ cnt,
    unsigned short* __restrict__ outb) {
    __shared__ unsigned short K_s[2][64 * 64];
    __shared__ unsigned short V_s[2][64 * 64];
    __shared__ unsigned short p_s[4][16][72];
    __shared__ float em_s[64];
    const int tid = threadIdx.x;
    const int lane = tid & 63, wave = tid >> 6;
    const int L = blockIdx.x;
    const int ix = L >> 3;
    const int qt = ix & 7;
    const int gidx = (L & 7) * 8 + (ix >> 3);   // same (h,b) group on same XCD
    const int h = gidx & 15, b = gidx >> 4;
    const int fr = lane & 15, g = lane >> 4;
    const int gq = qt * 64 + wave * 16;

    short8 aq[2];
    {
        const unsigned short* qp = qb + ((size_t)(b * SEQC + gq + fr)) * DIMC + h * DHC + g * 8;
        aq[0] = *(const short8*)qp;
        aq[1] = *(const short8*)(qp + 32);
    }

    const int sr = tid >> 3, ss = tid & 7;       // sr in [0,32)
    const int sw = (ss ^ (sr & 7)) * 8;          // same for both p (p*32 keeps r&7)
    const int wbase = (tid & 192) * 16;          // wave-uniform LDS byte base (4 waves)

    f32x4 acc_o[4] = {};
    float m_q = -1e30f, l_q = 0.0f;

    const int nt = 33 + qt;    // 32 mem tiles + qt+1 local tiles

    auto stage12 = [&](int t, int q) {
        const int jbase = t * 64;
        #pragma unroll
        for (int p = 0; p < 2; ++p) {
            int r = sr + p * 32;
            glds16(kvb + ((size_t)(b * CTXC + jbase + r)) * 1024 + h * DHC + sw,
                   (char*)K_s[q] + wbase + p * 4096);
            if (t >= 32)
                glds16(vTl + ((size_t)(b * 1024 + h * DHC + r)) * 512 + (jbase - 2048) + sw,
                       (char*)V_s[q] + wbase + p * 4096);
        }
    };

    stage12(0, 0);
    asm volatile("s_waitcnt vmcnt(0)" ::: "memory");
    __builtin_amdgcn_s_barrier();
    int cur = 0;
    for (int t = 0; t < nt; ++t) {
        if (t + 1 < nt) stage12(t + 1, cur ^ 1);
        // wait for stage(t)'s loads only; stage(t+1) stays in flight
        if (t + 1 >= nt)      asm volatile("s_waitcnt vmcnt(0)" ::: "memory");
        else if (t + 1 >= 32) asm volatile("s_waitcnt vmcnt(4)" ::: "memory");
        else                  asm volatile("s_waitcnt vmcnt(2)" ::: "memory");
        __builtin_amdgcn_s_barrier();
        __builtin_amdgcn_sched_barrier(0);

        // S^T = K @ Q : key axis lane-local
        f32x4 sT[4] = {};
        #pragma unroll
        for (int ks = 0; ks < 2; ++ks)
            #pragma unroll
            for (int mf = 0; mf < 4; ++mf) {
                int row = mf * 16 + fr, sg = (ks * 4 + g) ^ (row & 7);
                short8 kk = *(const short8*)((const char*)K_s[cur] + row * 128 + sg * 16);
                sT[mf] = __builtin_amdgcn_mfma_f32_16x16x32_bf16(kk, aq[ks], sT[mf], 0, 0, 0);
            }

        if (t < 32) {
            // denominator-only (acc_o still zero -> no rescale)
            float mx = sT[0][0];
            #pragma unroll
            for (int mf = 0; mf < 4; ++mf)
                #pragma unroll
                for (int i = 0; i < 4; ++i) mx = fmaxf(mx, sT[mf][i]);
            mx *= 0.125f;
            mx = fmaxf(mx, __shfl_xor(mx, 16, 64));
            mx = fmaxf(mx, __shfl_xor(mx, 32, 64));
            float mnew = fmaxf(m_q, mx);
            float fs = __expf(m_q - mnew);
            m_q = mnew;
            float ps = 0.0f;
            #pragma unroll
            for (int mf = 0; mf < 4; ++mf)
                #pragma unroll
                for (int i = 0; i < 4; ++i)
                    ps += __expf(sT[mf][i] * 0.125f - mnew);
            ps += __shfl_xor(ps, 16, 64);
            ps += __shfl_xor(ps, 32, 64);
            l_q = l_q * fs + ps;
        } else {
            const int lt = t - 32;
            const int kq = gq + fr - lt * 64;
            float sv[4][4];
            #pragma unroll
            for (int mf = 0; mf < 4; ++mf)
                #pragma unroll
                for (int i = 0; i < 4; ++i) {
                    int kl = mf * 16 + g * 4 + i;
                    sv[mf][i] = (kl <= kq) ? sT[mf][i] * 0.125f : -1e30f;
                }
            float mx = sv[0][0];
            #pragma unroll
            for (int mf = 0; mf < 4; ++mf)
                #pragma unroll
                for (int i = 0; i < 4; ++i) mx = fmaxf(mx, sv[mf][i]);
            mx = fmaxf(mx, __shfl_xor(mx, 16, 64));
            mx = fmaxf(mx, __shfl_xor(mx, 32, 64));
            float mnew = fmaxf(m_q, mx);
            float fs = __expf(m_q - mnew);
            m_q = mnew;
            float ps = 0.0f;
            #pragma unroll
            for (int mf = 0; mf < 4; ++mf)
                #pragma unroll
                for (int i = 0; i < 4; ++i) {
                    float pe = __expf(sv[mf][i] - mnew);
                    ps += pe;
                    p_s[wave][fr][mf * 16 + g * 4 + i] = f2bf(pe);
                }
            ps += __shfl_xor(ps, 16, 64);
            ps += __shfl_xor(ps, 32, 64);
            l_q = l_q * fs + ps;
            float fsr[4];
            #pragma unroll
            for (int i = 0; i < 4; ++i) fsr[i] = __shfl(fs, g * 4 + i, 64);
            #pragma unroll
            for (int n = 0; n < 4; ++n)
                #pragma unroll
                for (int i = 0; i < 4; ++i) acc_o[n][i] *= fsr[i];
            asm volatile("s_waitcnt lgkmcnt(0)" ::: "memory");
            #pragma unroll
            for (int ks = 0; ks < 2; ++ks) {
                short8 ap = *(const short8*)&p_s[wave][fr][ks * 32 + g * 8];
                #pragma unroll
                for (int n = 0; n < 4; ++n) {
                    int row = n * 16 + fr, sg = (ks * 4 + g) ^ (row & 7);
                    short8 bv = *(const short8*)((const char*)V_s[cur] + row * 128 + sg * 16);
                    acc_o[n] = __builtin_amdgcn_mfma_f32_16x16x32_bf16(ap, bv, acc_o[n], 0, 0, 0);
                }
            }
        }
        __builtin_amdgcn_s_barrier();   // protect buf[cur^1] (overwritten next iter)
        cur ^= 1;
    }

    // ---- phase 3: compact live-mem tiles (final m,l; no m/l update) ----
    const int nct = cnt[b];
    for (int ct = 0; ct < nct; ++ct) {
        __syncthreads();
        #pragma unroll
        for (int p = 0; p < 2; ++p) {
            int r = sr + p * 32;
            int row = cidx[b * 2048 + ct * 64 + r];
            glds16(kvb + ((size_t)(b * CTXC + row)) * 1024 + h * DHC + sw,
                   (char*)K_s[0] + wbase + p * 4096);
            glds16(vTc + ((size_t)(b * 1024 + h * DHC + r)) * MAXC + ct * 64 + sw,
                   (char*)V_s[0] + wbase + p * 4096);
        }
        if (tid < 64) em_s[tid] = em_c[b * 2048 + ct * 64 + tid];
        __syncthreads();
        f32x4 sT[4] = {};
        #pragma unroll
        for (int ks = 0; ks < 2; ++ks)
            #pragma unroll
            for (int mf = 0; mf < 4; ++mf) {
                int row = mf * 16 + fr, sg = (ks * 4 + g) ^ (row & 7);
                short8 kk = *(const short8*)((const char*)K_s[0] + row * 128 + sg * 16);
                sT[mf] = __builtin_amdgcn_mfma_f32_16x16x32_bf16(kk, aq[ks], sT[mf], 0, 0, 0);
            }
        #pragma unroll
        for (int mf = 0; mf < 4; ++mf)
            #pragma unroll
            for (int i = 0; i < 4; ++i) {
                int key = mf * 16 + g * 4 + i;
                float pe = __expf(sT[mf][i] * 0.125f - m_q) * em_s[key];
                p_s[wave][fr][key] = f2bf(pe);
            }
        asm volatile("s_waitcnt lgkmcnt(0)" ::: "memory");
        #pragma unroll
        for (int ks = 0; ks < 2; ++ks) {
            short8 ap = *(const short8*)&p_s[wave][fr][ks * 32 + g * 8];
            #pragma unroll
            for (int n = 0; n < 4; ++n) {
                int row = n * 16 + fr, sg = (ks * 4 + g) ^ (row & 7);
                short8 bv = *(const short8*)((const char*)V_s[0] + row * 128 + sg * 16);
                acc_o[n] = __builtin_amdgcn_mfma_f32_16x16x32_bf16(ap, bv, acc_o[n], 0, 0, 0);
            }
        }
    }

    float linv = 1.0f / l_q;
    float invr[4];
    #pragma unroll
    for (int i = 0; i < 4; ++i) invr[i] = __shfl(linv, g * 4 + i, 64);
    #pragma unroll
    for (int n = 0; n < 4; ++n) {
        #pragma unroll
        for (int i = 0; i < 4; ++i) {
            size_t idx = ((size_t)(b * SEQC + gq + g * 4 + i)) * DIMC + h * DHC + n * 16 + fr;
            outb[idx] = f2bf(acc_o[n][i] * invr[i]);
        }
    }
}

// ---------------- aux writeback ----------------
__global__ void aux_write_kernel(const float* __restrict__ aux, float* __restrict__ dst) {
    dst[0] = aux[0];
}

extern "C" void kernel_launch(void* const* d_in, const int* in_sizes, int n_in,
                              void* d_out, int out_size, void* d_ws, size_t ws_size,
                              hipStream_t stream) {
    const int*   tokens    = (const int*)d_in[0];
    const float* mems      = (const float*)d_in[1];
    const int*   times     = (const int*)d_in[2];
    const float* token_emb = (const float*)d_in[3];
    const float* expire_W  = (const float*)d_in[4];
    const float* expire_b  = (const float*)d_in[5];
    const float* ln1_g     = (const float*)d_in[6];
    const float* ln1_b     = (const float*)d_in[7];
    const float* Wq        = (const float*)d_in[8];
    const float* Wkv       = (const float*)d_in[9];
    const float* Wo        = (const float*)d_in[10];
    const float* bo        = (const float*)d_in[11];
    const float* ln2_g     = (const float*)d_in[12];
    const float* ln2_b     = (const float*)d_in[13];
    const float* W1        = (const float*)d_in[14];
    const float* b1        = (const float*)d_in[15];
    const float* W2        = (const float*)d_in[16];
    const float* b2        = (const float*)d_in[17];
    const float* logits_W  = (const float*)d_in[18];
    const float* logits_b  = (const float*)d_in[19];

    float* out = (float*)d_out;
    float* ws  = (float*)d_ws;

    // workspace layout (float offsets)
    float* x = ws;                                                  //  0       (2,097,152)
    unsigned short* qb_b  = (unsigned short*)(ws + 2097152);        //  1,048,576 f
    unsigned short* kv_b  = (unsigned short*)(ws + 3145728);        //  5,242,880 f (K-only)
    unsigned short* vTl   = (unsigned short*)(ws + 8388608);        //  1,048,576 f
    unsigned short* vTc   = (unsigned short*)(ws + 9437184);        //  1,048,576 f
    unsigned short* xn_b  = (unsigned short*)(ws + 10485760);       //  1,048,576 f
    unsigned short* attn_b= (unsigned short*)(ws + 11534336);       //  1,048,576 f
    unsigned short* ffn_b = (unsigned short*)(ws + 12582912);       //  4,194,304 f
    unsigned short* mem_b = (unsigned short*)(ws + 16777216);       //  4,194,304 f
    unsigned short* x_b   = (unsigned short*)(ws + 20971520);       //  1,048,576 f
    unsigned short* wq_t  = (unsigned short*)(ws + 22020096);       //    524,288 f
    unsigned short* wkv_t = (unsigned short*)(ws + 22544384);       //  1,048,576 f
    unsigned short* wo_t  = (unsigned short*)(ws + 23592960);       //    524,288 f
    unsigned short* w1_t  = (unsigned short*)(ws + 24117248);       //  2,097,152 f
    unsigned short* w2_t  = (unsigned short*)(ws + 26214400);       //  2,097,152 f
    float* exps = ws + 28311552;                                    //      8,192 f
    float* aux  = ws + 28319744;                                    //         16 f
    int*   cidx = (int*)(ws + 28319760);                            //      8,192
    float* em_c = ws + 28327952;                                    //      8,192
    int*   cnt  = (int*)(ws + 28336144);                            //          4
    // logits_W^T aliases qb_b..mem_b (all dead after last layer); ends before x_b
    unsigned short* lw_t = (unsigned short*)(ws + 2097152);         // needs 16,384,000 f

    float* out_logits = out;                // 65,536,000
    float* out_mems   = out + 65536000;     // 33,554,432
    float* out_times  = out + 99090432;     // 8,192

    embed_kernel<<<BC * SEQC, 256, 0, stream>>>(tokens, token_emb, x);
    times_init_kernel<<<32, 256, 0, stream>>>(times, out_times, aux);

    for (int d = 0; d < 4; ++d) {
        const float* mem_d = mems + (size_t)d * BC * MC * DIMC;
        prep_kernel<<<PREP_TOT, 256, 0, stream>>>(
            mem_d, x, expire_W + d * DIMC, expire_b + d, exps, aux,
            mem_b, out_mems + (size_t)d * BC * MC * DIMC,
            ln1_g + d * DIMC, ln1_b + d * DIMC, xn_b,
            Wq + (size_t)d * DIMC * DIMC, Wkv + (size_t)d * DIMC * 2 * DIMC,
            Wo + (size_t)d * DIMC * DIMC, W1 + (size_t)d * DIMC * 4 * DIMC,
            W2 + (size_t)d * 4 * DIMC * DIMC,
            wq_t, wkv_t, wo_t, w1_t, w2_t);
        compact_kernel<<<BC, 64, 0, stream>>>(exps, times + d * MC, cidx, em_c, cnt);
        qkv_gemm_kernel<<<1152, 256, 0, stream>>>(xn_b, mem_b, wq_t, wkv_t,
                                                  cidx, cnt, qb_b, kv_b, vTl, vTc);
        attn_mfma_kernel<<<512, 256, 0, stream>>>(
            qb_b, kv_b, vTl, vTc, cidx, em_c, cnt, attn_b);
        gemm64_kernel<<<dim3(8, 32), 256, 0, stream>>>(
            attn_b, wo_t, bo + d * DIMC, x, x, nullptr, DIMC);
        ln_kernel<<<BC * SEQC, 256, 0, stream>>>(x, ln2_g + d * DIMC, ln2_b + d * DIMC, xn_b);
        ffn1_kernel<<<dim3(32, 16), 256, 0, stream>>>(xn_b, w1_t, b1 + d * 4 * DIMC, ffn_b);
        if (d < 3) {
            gemm64_kernel<<<dim3(8, 32), 256, 0, stream>>>(
                ffn_b, w2_t, b2 + d * DIMC, x, x, nullptr, 4 * DIMC);
        } else {
            gemm64_kernel<<<dim3(8, 32), 256, 0, stream>>>(
                ffn_b, w2_t, b2 + d * DIMC, x, nullptr, x_b, 4 * DIMC);
        }
    }

    wt_kernel<<<dim3(1000, 32), 256, 0, stream>>>(logits_W, lw_t, DIMC, VOCABC);
    logits_kernel<<<1000, 512, 0, stream>>>(x_b, lw_t, logits_b, out_logits);
    aux_write_kernel<<<1, 1, 0, stream>>>(aux, out + 99098624);
}

// Round 15
// 1719.124 us; speedup vs baseline: 1.0118x; 1.0118x over previous
//
#include <hip/hip_runtime.h>
#include <cmath>

// Problem constants
#define DIMC   1024
#define SEQC   512
#define BC     4
#define MC     2048      // MAXMEM
#define CTXC   2560      // MC + SEQC
#define HEADSC 16
#define DHC    64
#define VOCABC 32000
#define MAXC   512       // compact-slot capacity (live keys ~64)

using short8 = __attribute__((ext_vector_type(8))) short;
using f32x4  = __attribute__((ext_vector_type(4))) float;
using u16x4  = __attribute__((ext_vector_type(4))) unsigned short;
using u16x8  = __attribute__((ext_vector_type(8))) unsigned short;

__device__ __forceinline__ unsigned short f2bf(float f) {
    unsigned u = __float_as_uint(f);
    unsigned r = (u + 0x7fffu + ((u >> 16) & 1u)) >> 16;
    return (unsigned short)r;
}

__device__ __forceinline__ void glds16(const unsigned short* g, char* l) {
    __builtin_amdgcn_global_load_lds(
        (const __attribute__((address_space(1))) void*)g,
        (__attribute__((address_space(3))) void*)l, 16, 0, 0);
}

// ---------------- embed ----------------
__global__ __launch_bounds__(256) void embed_kernel(const int* __restrict__ tokens,
                                                    const float* __restrict__ emb,
                                                    float* __restrict__ x) {
    int row = blockIdx.x;
    int tok = tokens[row];
    const float4 v = *(const float4*)(emb + (size_t)tok * DIMC + threadIdx.x * 4);
    *(float4*)(x + (size_t)row * DIMC + threadIdx.x * 4) = v;
}

// ---------------- new_times + aux zero ----------------
__global__ __launch_bounds__(256) void times_init_kernel(const int* __restrict__ times,
                                                         float* __restrict__ out_times,
                                                         float* __restrict__ aux) {
    int i = blockIdx.x * 256 + threadIdx.x;
    if (i == 0) aux[0] = 0.0f;
    if (i < 4 * MC) {
        int d = i >> 11, m = i & (MC - 1);
        out_times[i] = (m < MC - SEQC) ? (float)(times[d * MC + SEQC + m] + SEQC)
                                       : (float)(MC - 1 - m);
    }
}

// ---------------- fused per-layer prep ----------------
#define PREP_MEM 8192
#define PREP_XC  10240
#define PREP_LN  12288
#define PREP_TOT 24576
__global__ __launch_bounds__(256) void prep_kernel(
    const float* __restrict__ mem_d, const float* __restrict__ x,
    const float* __restrict__ eW, const float* __restrict__ eb,
    float* __restrict__ exps, float* __restrict__ aux,
    unsigned short* __restrict__ mem_b, float* __restrict__ out_mems_d,
    const float* __restrict__ g1, const float* __restrict__ b1v,
    unsigned short* __restrict__ xn_b,
    const float* __restrict__ Wq, const float* __restrict__ Wkv,
    const float* __restrict__ Wo, const float* __restrict__ W1,
    const float* __restrict__ W2,
    unsigned short* __restrict__ wq_t, unsigned short* __restrict__ wkv_t,
    unsigned short* __restrict__ wo_t, unsigned short* __restrict__ w1_t,
    unsigned short* __restrict__ w2_t) {
    __shared__ float sh[1056];
    const int bid = blockIdx.x, tid = threadIdx.x;
    if (bid < PREP_MEM) {
        int row = bid;                       // b*2048 + m
        int m = row & 2047, b = row >> 11;
        const float4 v = *(const float4*)(mem_d + (size_t)row * DIMC + tid * 4);
        const float4 w = *(const float4*)(eW + tid * 4);
        float s = v.x * w.x + v.y * w.y + v.z * w.z + v.w * w.w;
        for (int off = 32; off; off >>= 1) s += __shfl_down(s, off, 64);
        int wid = tid >> 6, lane = tid & 63;
        if (lane == 0) sh[wid] = s;
        u16x4 o = { f2bf(v.x), f2bf(v.y), f2bf(v.z), f2bf(v.w) };
        *(u16x4*)(mem_b + (size_t)row * DIMC + tid * 4) = o;
        if (m >= SEQC)
            *(float4*)(out_mems_d + ((size_t)(b * MC + m - SEQC)) * DIMC + tid * 4) = v;
        __syncthreads();
        if (tid == 0) {
            float z = sh[0] + sh[1] + sh[2] + sh[3] + eb[0];
            float e = (float)MC / (1.0f + expf(-z));
            exps[row] = e;
            atomicAdd(aux, e * (1e-6f / (float)SEQC));
        }
    } else if (bid < PREP_XC) {
        int r = bid - PREP_MEM;              // b*512 + i
        int b = r >> 9, i = r & 511;
        const float4 v = *(const float4*)(x + (size_t)r * DIMC + tid * 4);
        *(float4*)(out_mems_d + ((size_t)(b * MC + MC - SEQC + i)) * DIMC + tid * 4) = v;
    } else if (bid < PREP_LN) {
        int row = bid - PREP_XC;
        const float4 v = *(const float4*)(x + (size_t)row * DIMC + tid * 4);
        float s = v.x + v.y + v.z + v.w;
        float q = v.x * v.x + v.y * v.y + v.z * v.z + v.w * v.w;
        for (int off = 32; off; off >>= 1) {
            s += __shfl_down(s, off, 64);
            q += __shfl_down(q, off, 64);
        }
        int wid = tid >> 6, lane = tid & 63;
        if (lane == 0) { sh[wid] = s; sh[4 + wid] = q; }
        __syncthreads();
        if (tid == 0) {
            float S = sh[0] + sh[1] + sh[2] + sh[3];
            float Q = sh[4] + sh[5] + sh[6] + sh[7];
            float mu = S / DIMC;
            float var = Q / DIMC - mu * mu;
            sh[8] = mu;
            sh[9] = rsqrtf(var + 1e-5f);
        }
        __syncthreads();
        float mu = sh[8], rstd = sh[9];
        const float4 gg = *(const float4*)(g1 + tid * 4);
        const float4 bb = *(const float4*)(b1v + tid * 4);
        u16x4 o = { f2bf((v.x - mu) * rstd * gg.x + bb.x),
                    f2bf((v.y - mu) * rstd * gg.y + bb.y),
                    f2bf((v.z - mu) * rstd * gg.z + bb.z),
                    f2bf((v.w - mu) * rstd * gg.w + bb.w) };
        *(u16x4*)(xn_b + (size_t)row * DIMC + tid * 4) = o;
    } else {
        int t = bid - PREP_LN;
        const float* W; unsigned short* Wt; int K, N, tx, ty;
        if (t < 1024)      { W = Wq;  Wt = wq_t;  K = 1024; N = 1024; tx = t & 31;  ty = t >> 5; }
        else if (t < 3072) { int u = t - 1024; W = Wkv; Wt = wkv_t; K = 1024; N = 2048; tx = u & 63;  ty = u >> 6; }
        else if (t < 4096) { int u = t - 3072; W = Wo;  Wt = wo_t;  K = 1024; N = 1024; tx = u & 31;  ty = u >> 5; }
        else if (t < 8192) { int u = t - 4096; W = W1;  Wt = w1_t;  K = 1024; N = 4096; tx = u & 127; ty = u >> 7; }
        else               { int u = t - 8192; W = W2;  Wt = w2_t;  K = 4096; N = 1024; tx = u & 31;  ty = u >> 5; }
        int n0 = tx * 32, k0 = ty * 32;
        int r = tid >> 3, c = (tid & 7) * 4;
        const float4 v = *(const float4*)(W + (size_t)(k0 + r) * N + n0 + c);
        sh[r * 33 + c] = v.x; sh[r * 33 + c + 1] = v.y;
        sh[r * 33 + c + 2] = v.z; sh[r * 33 + c + 3] = v.w;
        __syncthreads();
        u16x4 o = { f2bf(sh[(c + 0) * 33 + r]), f2bf(sh[(c + 1) * 33 + r]),
                    f2bf(sh[(c + 2) * 33 + r]), f2bf(sh[(c + 3) * 33 + r]) };
        *(u16x4*)(Wt + (size_t)(n0 + r) * K + k0 + c) = o;
    }
}

// ---------------- compact live memory keys (deterministic ballot scan) ----------------
__global__ __launch_bounds__(64) void compact_kernel(
    const float* __restrict__ exps, const int* __restrict__ times_d,
    int* __restrict__ cidx, float* __restrict__ em_c, int* __restrict__ cnt) {
    int b = blockIdx.x, lane = threadIdx.x;
    int c = 0;
    for (int it = 0; it < 32; ++it) {
        int j = it * 64 + lane;
        float e = exps[b * MC + j];
        float rr = (e - (float)times_d[j]) * (1.0f / 128.0f) + 1.0f;
        float em = fminf(fmaxf(rr, 0.0f), 1.0f);
        unsigned long long mk = __ballot(em > 0.0f);
        int pos = c + __popcll(mk & ((1ull << lane) - 1ull));
        if (em > 0.0f) {
            cidx[b * 2048 + pos] = j;
            em_c[b * 2048 + pos] = em;
        }
        c += __popcll(mk);
    }
    int padded = (c + 63) & ~63;
    int fill_to = padded < MAXC ? MAXC : padded;
    for (int p = c + lane; p < fill_to; p += 64) {
        cidx[b * 2048 + p] = 0;     // valid row; em=0 kills contribution
        em_c[b * 2048 + p] = 0.0f;
    }
    int tiles = padded >> 6;
    if (tiles > (MAXC >> 6)) tiles = MAXC >> 6;
    if (lane == 0) cnt[b] = tiles;
}

// ---------------- LayerNorm (fp32 in, bf16 out) — LN2 ----------------
__global__ __launch_bounds__(256) void ln_kernel(const float* __restrict__ in,
                                                 const float* __restrict__ g,
                                                 const float* __restrict__ b,
                                                 unsigned short* __restrict__ outb) {
    int row = blockIdx.x;
    int tid = threadIdx.x;
    const float4 v = *(const float4*)(in + (size_t)row * DIMC + tid * 4);
    float s = v.x + v.y + v.z + v.w;
    float q = v.x * v.x + v.y * v.y + v.z * v.z + v.w * v.w;
    for (int off = 32; off; off >>= 1) {
        s += __shfl_down(s, off, 64);
        q += __shfl_down(q, off, 64);
    }
    __shared__ float ss[4], sq[4];
    int wid = tid >> 6, lane = tid & 63;
    if (lane == 0) { ss[wid] = s; sq[wid] = q; }
    __syncthreads();
    if (tid == 0) {
        float S = ss[0] + ss[1] + ss[2] + ss[3];
        float Q = sq[0] + sq[1] + sq[2] + sq[3];
        float mu = S / DIMC;
        float var = Q / DIMC - mu * mu;
        ss[0] = mu;
        sq[0] = rsqrtf(var + 1e-5f);
    }
    __syncthreads();
    float mu = ss[0], rstd = sq[0];
    const float4 gg = *(const float4*)(g + tid * 4);
    const float4 bb = *(const float4*)(b + tid * 4);
    u16x4 o = { f2bf((v.x - mu) * rstd * gg.x + bb.x),
                f2bf((v.y - mu) * rstd * gg.y + bb.y),
                f2bf((v.z - mu) * rstd * gg.z + bb.z),
                f2bf((v.w - mu) * rstd * gg.w + bb.w) };
    *(u16x4*)(outb + (size_t)row * DIMC + tid * 4) = o;
}

// ---------------- weight convert + transpose (logits_W only) ----------------
__global__ __launch_bounds__(256) void wt_kernel(const float* __restrict__ W,
                                                 unsigned short* __restrict__ Wt,
                                                 int K, int N) {
    __shared__ float t[32][33];
    int tid = threadIdx.x;
    int n0 = blockIdx.x * 32, k0 = blockIdx.y * 32;
    int r = tid >> 3, c = (tid & 7) * 4;
    const float4 v = *(const float4*)(W + (size_t)(k0 + r) * N + n0 + c);
    t[r][c] = v.x; t[r][c + 1] = v.y; t[r][c + 2] = v.z; t[r][c + 3] = v.w;
    __syncthreads();
    u16x4 o = { f2bf(t[c + 0][r]), f2bf(t[c + 1][r]),
                f2bf(t[c + 2][r]), f2bf(t[c + 3][r]) };
    *(u16x4*)(Wt + (size_t)(n0 + r) * K + k0 + c) = o;
}

// ---------------- bf16 MFMA GEMM body — depth-1 counted-vmcnt raw-barrier pipeline (round-13 proven) ----------------
// AMODE: 0 = A[r][K]; 2 = gather A rows via cidx (r = b*MAXC+slot -> mem row b*2048+cidx)
// OMODE: 0 = direct [r][N]; 1 = mem rows -> kv ctx rows (K-only, N=1024);
//        2 = local rows -> kv ctx rows (K-only); 3 = local V -> vTl transposed;
//        4 = compact V -> vTc transposed.
template<int AMODE, bool BIAS, bool GELU, bool RES, int OMODE, int RT>
__device__ __forceinline__ void gemm_body(
    unsigned short* As, unsigned short* Bs,
    const unsigned short* __restrict__ A, const int* __restrict__ gidx,
    const unsigned short* __restrict__ Wt, const float* __restrict__ bias,
    const float* __restrict__ res, float* __restrict__ Cf,
    unsigned short* __restrict__ Cb, int K, int N, int bx, int by) {
    constexpr int MF = RT / 32;
    const int tid = threadIdx.x;
    const int lane = tid & 63, wave = tid >> 6;
    const int row0 = by * RT, col0 = bx * 128;

    const int seg = tid & 3;
    const int rr0 = tid >> 2;
    const unsigned short* arow[RT / 64];
    #pragma unroll
    for (int p = 0; p < RT / 64; ++p) {
        int r = row0 + p * 64 + rr0;
        if (AMODE == 2) {
            int b = r >> 9, slot = r & (MAXC - 1);
            arow[p] = A + ((size_t)(b * 2048 + gidx[b * 2048 + slot])) * K;
        } else {
            arow[p] = A + (size_t)r * K;
        }
        arow[p] += seg * 8;
    }
    const unsigned short* brow[2];
    #pragma unroll
    for (int p = 0; p < 2; ++p)
        brow[p] = Wt + (size_t)(col0 + p * 64 + rr0) * K + seg * 8;

    char* lA = (char*)As + (tid & 192) * 16;
    char* lB = (char*)Bs + (tid & 192) * 16;

    auto stage = [&](int k0, int q) {
        char* a = lA + q * (RT * 64);
        glds16(arow[0] + k0, a);
        if (RT == 128) glds16(arow[1] + k0, a + 4096);
        char* bp = lB + q * 8192;
        glds16(brow[0] + k0, bp);
        glds16(brow[1] + k0, bp + 4096);
    };

    f32x4 acc[MF][4] = {};

    const int wr = (wave >> 1) * (RT / 2), wc = (wave & 1) * 64;
    const int fr = lane & 15;
    const int k8 = (lane >> 4) * 8;

    stage(0, 0);
    int cur = 0;
    for (int k0 = 0; k0 < K; k0 += 32) {
        if (k0 + 32 < K) {
            stage(k0 + 32, cur ^ 1);
            if (RT == 128) asm volatile("s_waitcnt vmcnt(4)" ::: "memory");
            else           asm volatile("s_waitcnt vmcnt(3)" ::: "memory");
        } else {
            asm volatile("s_waitcnt vmcnt(0)" ::: "memory");
        }
        __builtin_amdgcn_s_barrier();
        __builtin_amdgcn_sched_barrier(0);
        const unsigned short* Ar = As + cur * (RT * 32) + (size_t)(wr + fr) * 32 + k8;
        const unsigned short* Br = Bs + cur * (128 * 32) + (size_t)(wc + fr) * 32 + k8;
        short8 a[MF], b[4];
        #pragma unroll
        for (int m = 0; m < MF; ++m) a[m] = *(const short8*)(Ar + m * 16 * 32);
        #pragma unroll
        for (int n = 0; n < 4; ++n) b[n] = *(const short8*)(Br + n * 16 * 32);
        #pragma unroll
        for (int m = 0; m < MF; ++m)
            #pragma unroll
            for (int n = 0; n < 4; ++n)
                acc[m][n] = __builtin_amdgcn_mfma_f32_16x16x32_bf16(a[m], b[n], acc[m][n], 0, 0, 0);
        __builtin_amdgcn_s_barrier();
        cur ^= 1;
    }

    const int orow = row0 + wr + (lane >> 4) * 4;
    const int ocol = col0 + wc + fr;
    if (OMODE >= 3) {
        #pragma unroll
        for (int n = 0; n < 4; ++n) {
            int c = ocol + n * 16;
            #pragma unroll
            for (int m = 0; m < MF; ++m) {
                int r0 = orow + m * 16;
                int b = r0 >> 9, i = r0 & 511;
                size_t addr = (OMODE == 3)
                    ? ((size_t)(b * 1024 + c)) * 512 + i
                    : ((size_t)(b * 1024 + c)) * MAXC + i;
                u16x4 o = { f2bf(acc[m][n][0]), f2bf(acc[m][n][1]),
                            f2bf(acc[m][n][2]), f2bf(acc[m][n][3]) };
                *(u16x4*)(Cb + addr) = o;
            }
        }
        return;
    }
    #pragma unroll
    for (int n = 0; n < 4; ++n) {
        int c = ocol + n * 16;
        float bv = BIAS ? bias[c] : 0.0f;
        #pragma unroll
        for (int m = 0; m < MF; ++m) {
            #pragma unroll
            for (int i = 0; i < 4; ++i) {
                int r0 = orow + m * 16 + i;
                size_t orr = r0;
                if (OMODE == 1) orr = (size_t)r0 + (size_t)(r0 >> 11) * 512;
                if (OMODE == 2) orr = (size_t)r0 + (size_t)(r0 >> 9) * 2048 + 2048;
                size_t idx = orr * N + c;
                float v = acc[m][n][i] + bv;
                if (GELU) v = 0.5f * v * (1.0f + erff(v * 0.70710678118f));
                if (RES) v += res[idx];
                if (Cf) Cf[idx] = v;
                if (Cb) Cb[idx] = f2bf(v);
            }
        }
    }
}

// Fused: Q(128) + local-K(128) + mem-K(512) + local-V transposed(128) + compact-V transposed(256)
__global__ __launch_bounds__(256) void qkv_gemm_kernel(
    const unsigned short* __restrict__ xn_b, const unsigned short* __restrict__ mem_b,
    const unsigned short* __restrict__ wq_t, const unsigned short* __restrict__ wkv_t,
    const int* __restrict__ cidx, const int* __restrict__ cnt,
    unsigned short* __restrict__ qb, unsigned short* __restrict__ kvb,
    unsigned short* __restrict__ vTl, unsigned short* __restrict__ vTc) {
    __shared__ unsigned short As[2 * 128 * 32];
    __shared__ unsigned short Bs[2 * 128 * 32];
    int id = blockIdx.x;
    if (id < 128) {
        gemm_body<0, false, false, false, 0, 128>(As, Bs, xn_b, nullptr, wq_t,
            nullptr, nullptr, nullptr, qb, 1024, 1024, id & 7, id >> 3);
    } else if (id < 256) {
        id -= 128;  // local rows -> ctx rows, K half of wkv
        gemm_body<0, false, false, false, 2, 128>(As, Bs, xn_b, nullptr, wkv_t,
            nullptr, nullptr, nullptr, kvb, 1024, 1024, id & 7, id >> 3);
    } else if (id < 768) {
        id -= 256;  // mem rows -> ctx rows, K half of wkv
        gemm_body<0, false, false, false, 1, 128>(As, Bs, mem_b, nullptr, wkv_t,
            nullptr, nullptr, nullptr, kvb, 1024, 1024, id & 7, id >> 3);
    } else if (id < 896) {
        id -= 768;  // local V -> vTl transposed
        gemm_body<0, false, false, false, 3, 128>(As, Bs, xn_b, nullptr,
            wkv_t + (size_t)1024 * 1024, nullptr, nullptr, nullptr, vTl,
            1024, 1024, id & 7, id >> 3);
    } else {
        id -= 896;  // compact V: gather mem rows by cidx -> vTc transposed
        int by = id >> 3;
        int b = (by * 64) >> 9, slot0 = (by * 64) & (MAXC - 1);
        if (slot0 >= cnt[b] * 64) return;
        gemm_body<2, false, false, false, 4, 64>(As, Bs, mem_b, cidx,
            wkv_t + (size_t)1024 * 1024, nullptr, nullptr, nullptr, vTc,
            1024, 1024, id & 7, by);
    }
}

// RT=64 GEMM with bias+residual, N=1024 (Wo and FFN2)
__global__ __launch_bounds__(256) void gemm64_kernel(
    const unsigned short* __restrict__ A, const unsigned short* __restrict__ Wt,
    const float* __restrict__ bias, const float* __restrict__ res,
    float* __restrict__ Cf, unsigned short* __restrict__ Cb, int K) {
    __shared__ unsigned short As[2 * 64 * 32];
    __shared__ unsigned short Bs[2 * 128 * 32];
    gemm_body<0, true, false, true, 0, 64>(As, Bs, A, nullptr, Wt, bias, res,
        Cf, Cb, K, 1024, blockIdx.x, blockIdx.y);
}

// FFN1: gelu, bf16 out
__global__ __launch_bounds__(256) void ffn1_kernel(
    const unsigned short* __restrict__ A, const unsigned short* __restrict__ Wt,
    const float* __restrict__ bias, unsigned short* __restrict__ Cb) {
    __shared__ unsigned short As[2 * 128 * 32];
    __shared__ unsigned short Bs[2 * 128 * 32];
    gemm_body<0, true, true, false, 0, 128>(As, Bs, A, nullptr, Wt, bias, nullptr,
        nullptr, Cb, 1024, 4096, blockIdx.x, blockIdx.y);
}

// ---------------- logits: 256x256 tile, 512 threads, 8 waves (2x4), counted-vmcnt pipeline ----------------
__global__ __launch_bounds__(512, 2) void logits_kernel(
    const unsigned short* __restrict__ A, const unsigned short* __restrict__ Wt,
    const float* __restrict__ bias, float* __restrict__ Cf) {
    __shared__ unsigned short As[2 * 256 * 32];
    __shared__ unsigned short Bs[2 * 256 * 32];
    const int L = blockIdx.x;
    const int wid = (L & 7) * 125 + (L >> 3);
    const int ct = wid / 8, rt = wid & 7;
    const int row0 = rt * 256, col0 = ct * 256;
    const int tid = threadIdx.x;
    const int lane = tid & 63, wave = tid >> 6;

    const int seg = tid & 3;
    const int rr0 = tid >> 2;                 // 0..127
    const unsigned short* arow[2];
    const unsigned short* brow[2];
    #pragma unroll
    for (int p = 0; p < 2; ++p) {
        arow[p] = A + (size_t)(row0 + p * 128 + rr0) * 1024 + seg * 8;
        brow[p] = Wt + (size_t)(col0 + p * 128 + rr0) * 1024 + seg * 8;
    }
    char* lA = (char*)As + (tid & 448) * 16;  // wave-uniform base (8 waves)
    char* lB = (char*)Bs + (tid & 448) * 16;

    auto stage = [&](int k0, int q) {
        char* a = lA + q * 16384;
        char* bp = lB + q * 16384;
        glds16(arow[0] + k0, a);
        glds16(arow[1] + k0, a + 8192);
        glds16(brow[0] + k0, bp);
        glds16(brow[1] + k0, bp + 8192);
    };

    f32x4 acc[8][4] = {};
    const int wr = (wave >> 2) * 128, wc = (wave & 3) * 64;
    const int fr = lane & 15;
    const int k8 = (lane >> 4) * 8;

    stage(0, 0);
    int cur = 0;
    for (int k0 = 0; k0 < 1024; k0 += 32) {
        if (k0 + 32 < 1024) {
            stage(k0 + 32, cur ^ 1);
            asm volatile("s_waitcnt vmcnt(4)" ::: "memory");
        } else {
            asm volatile("s_waitcnt vmcnt(0)" ::: "memory");
        }
        __builtin_amdgcn_s_barrier();
        __builtin_amdgcn_sched_barrier(0);
        const unsigned short* Ar = As + cur * 8192 + (size_t)(wr + fr) * 32 + k8;
        const unsigned short* Br = Bs + cur * 8192 + (size_t)(wc + fr) * 32 + k8;
        short8 a[8], b[4];
        #pragma unroll
        for (int m = 0; m < 8; ++m) a[m] = *(const short8*)(Ar + m * 16 * 32);
        #pragma unroll
        for (int n = 0; n < 4; ++n) b[n] = *(const short8*)(Br + n * 16 * 32);
        #pragma unroll
        for (int m = 0; m < 8; ++m)
            #pragma unroll
            for (int n = 0; n < 4; ++n)
                acc[m][n] = __builtin_amdgcn_mfma_f32_16x16x32_bf16(a[m], b[n], acc[m][n], 0, 0, 0);
        __builtin_amdgcn_s_barrier();
        cur ^= 1;
    }

    const int orow = row0 + wr + (lane >> 4) * 4;
    const int ocol = col0 + wc + fr;
    #pragma unroll
    for (int n = 0; n < 4; ++n) {
        int c = ocol + n * 16;
        float bv = bias[c];
        #pragma unroll
        for (int m = 0; m < 8; ++m) {
            #pragma unroll
            for (int i = 0; i < 4; ++i)
                Cf[(size_t)(orow + m * 16 + i) * VOCABC + c] = acc[m][n][i] + bv;
        }
    }
}

// ---------------- 3-phase MFMA flash attention — log2-domain softmax ----------------
// grid = 512 (8 qt x 16 h x 4 b), XCD-grouped; counted-vmcnt raw-barrier pipeline.
// Softmax in base-2: p = exp2(s*CSC - m2), CSC = 0.125*log2(e). Ratio-identical to base-e.
#define CSC 0.18033688011112042f
__global__ __launch_bounds__(256) void attn_mfma_kernel(
    const unsigned short* __restrict__ qb,
    const unsigned short* __restrict__ kvb,   // K-only [b][2560][1024]
    const unsigned short* __restrict__ vTl,   // [b*1024+d][512] local V transposed
    const unsigned short* __restrict__ vTc,   // [b*1024+d][MAXC] compact V transposed
    const int* __restrict__ cidx,
    const float* __restrict__ em_c,
    const int* __restrict__ cnt,
    unsigned short* __restrict__ outb) {
    __shared__ unsigned short K_s[2][64 * 64];
    __shared__ unsigned short V_s[2][64 * 64];
    __shared__ unsigned short p_s[4][16][72];
    __shared__ float em_s[64];
    const int tid = threadIdx.x;
    const int lane = tid & 63, wave = tid >> 6;
    const int L = blockIdx.x;
    const int ix = L >> 3;
    const int qt = ix & 7;
    const int gidx = (L & 7) * 8 + (ix >> 3);   // same (h,b) group on same XCD
    const int h = gidx & 15, b = gidx >> 4;
    const int fr = lane & 15, g = lane >> 4;
    const int gq = qt * 64 + wave * 16;

    short8 aq[2];
    {
        const unsigned short* qp = qb + ((size_t)(b * SEQC + gq + fr)) * DIMC + h * DHC + g * 8;
        aq[0] = *(const short8*)qp;
        aq[1] = *(const short8*)(qp + 32);
    }

    const int sr = tid >> 3, ss = tid & 7;       // sr in [0,32)
    const int sw = (ss ^ (sr & 7)) * 8;          // same for both p (p*32 keeps r&7)
    const int wbase = (tid & 192) * 16;          // wave-uniform LDS byte base (4 waves)

    f32x4 acc_o[4] = {};
    float m_q = -1e30f, l_q = 0.0f;              // m_q, l_q live in log2 domain

    const int nt = 33 + qt;    // 32 mem tiles + qt+1 local tiles

    auto stage12 = [&](int t, int q) {
        const int jbase = t * 64;
        #pragma unroll
        for (int p = 0; p < 2; ++p) {
            int r = sr + p * 32;
            glds16(kvb + ((size_t)(b * CTXC + jbase + r)) * 1024 + h * DHC + sw,
                   (char*)K_s[q] + wbase + p * 4096);
            if (t >= 32)
                glds16(vTl + ((size_t)(b * 1024 + h * DHC + r)) * 512 + (jbase - 2048) + sw,
                       (char*)V_s[q] + wbase + p * 4096);
        }
    };

    stage12(0, 0);
    asm volatile("s_waitcnt vmcnt(0)" ::: "memory");
    __builtin_amdgcn_s_barrier();
    int cur = 0;
    for (int t = 0; t < nt; ++t) {
        if (t + 1 < nt) stage12(t + 1, cur ^ 1);
        // wait for stage(t)'s loads only; stage(t+1) stays in flight
        if (t + 1 >= nt)      asm volatile("s_waitcnt vmcnt(0)" ::: "memory");
        else if (t + 1 >= 32) asm volatile("s_waitcnt vmcnt(4)" ::: "memory");
        else                  asm volatile("s_waitcnt vmcnt(2)" ::: "memory");
        __builtin_amdgcn_s_barrier();
        __builtin_amdgcn_sched_barrier(0);

        // S^T = K @ Q : key axis lane-local
        f32x4 sT[4] = {};
        #pragma unroll
        for (int ks = 0; ks < 2; ++ks)
            #pragma unroll
            for (int mf = 0; mf < 4; ++mf) {
                int row = mf * 16 + fr, sg = (ks * 4 + g) ^ (row & 7);
                short8 kk = *(const short8*)((const char*)K_s[cur] + row * 128 + sg * 16);
                sT[mf] = __builtin_amdgcn_mfma_f32_16x16x32_bf16(kk, aq[ks], sT[mf], 0, 0, 0);
            }

        if (t < 32) {
            // denominator-only (acc_o still zero -> no rescale)
            float mx = sT[0][0];
            #pragma unroll
            for (int mf = 0; mf < 4; ++mf)
                #pragma unroll
                for (int i = 0; i < 4; ++i) mx = fmaxf(mx, sT[mf][i]);
            mx *= CSC;
            mx = fmaxf(mx, __shfl_xor(mx, 16, 64));
            mx = fmaxf(mx, __shfl_xor(mx, 32, 64));
            float mnew = fmaxf(m_q, mx);
            float fs = __builtin_amdgcn_exp2f(m_q - mnew);
            m_q = mnew;
            float ps = 0.0f;
            #pragma unroll
            for (int mf = 0; mf < 4; ++mf)
                #pragma unroll
                for (int i = 0; i < 4; ++i)
                    ps += __builtin_amdgcn_exp2f(sT[mf][i] * CSC - mnew);
            ps += __shfl_xor(ps, 16, 64);
            ps += __shfl_xor(ps, 32, 64);
            l_q = l_q * fs + ps;
        } else {
            const int lt = t - 32;
            const int kq = gq + fr - lt * 64;
            float sv[4][4];
            #pragma unroll
            for (int mf = 0; mf < 4; ++mf)
                #pragma unroll
                for (int i = 0; i < 4; ++i) {
                    int kl = mf * 16 + g * 4 + i;
                    sv[mf][i] = (kl <= kq) ? sT[mf][i] * CSC : -1e30f;
                }
            float mx = sv[0][0];
            #pragma unroll
            for (int mf = 0; mf < 4; ++mf)
                #pragma unroll
                for (int i = 0; i < 4; ++i) mx = fmaxf(mx, sv[mf][i]);
            mx = fmaxf(mx, __shfl_xor(mx, 16, 64));
            mx = fmaxf(mx, __shfl_xor(mx, 32, 64));
            float mnew = fmaxf(m_q, mx);
            float fs = __builtin_amdgcn_exp2f(m_q - mnew);
            m_q = mnew;
            float ps = 0.0f;
            #pragma unroll
            for (int mf = 0; mf < 4; ++mf)
                #pragma unroll
                for (int i = 0; i < 4; ++i) {
                    float pe = __builtin_amdgcn_exp2f(sv[mf][i] - mnew);
                    ps += pe;
                    p_s[wave][fr][mf * 16 + g * 4 + i] = f2bf(pe);
                }
            ps += __shfl_xor(ps, 16, 64);
            ps += __shfl_xor(ps, 32, 64);
            l_q = l_q * fs + ps;
            float fsr[4];
            #pragma unroll
            for (int i = 0; i < 4; ++i) fsr[i] = __shfl(fs, g * 4 + i, 64);
            #pragma unroll
            for (int n = 0; n < 4; ++n)
                #pragma unroll
                for (int i = 0; i < 4; ++i) acc_o[n][i] *= fsr[i];
            asm volatile("s_waitcnt lgkmcnt(0)" ::: "memory");
            #pragma unroll
            for (int ks = 0; ks < 2; ++ks) {
                short8 ap = *(const short8*)&p_s[wave][fr][ks * 32 + g * 8];
                #pragma unroll
                for (int n = 0; n < 4; ++n) {
                    int row = n * 16 + fr, sg = (ks * 4 + g) ^ (row & 7);
                    short8 bv = *(const short8*)((const char*)V_s[cur] + row * 128 + sg * 16);
                    acc_o[n] = __builtin_amdgcn_mfma_f32_16x16x32_bf16(ap, bv, acc_o[n], 0, 0, 0);
                }
            }
        }
        __builtin_amdgcn_s_barrier();   // protect buf[cur^1] (overwritten next iter)
        cur ^= 1;
    }

    // ---- phase 3: compact live-mem tiles (final m,l; no m/l update) ----
    const int nct = cnt[b];
    for (int ct = 0; ct < nct; ++ct) {
        __syncthreads();
        #pragma unroll
        for (int p = 0; p < 2; ++p) {
            int r = sr + p * 32;
            int row = cidx[b * 2048 + ct * 64 + r];
            glds16(kvb + ((size_t)(b * CTXC + row)) * 1024 + h * DHC + sw,
                   (char*)K_s[0] + wbase + p * 4096);
            glds16(vTc + ((size_t)(b * 1024 + h * DHC + r)) * MAXC + ct * 64 + sw,
                   (char*)V_s[0] + wbase + p * 4096);
        }
        if (tid < 64) em_s[tid] = em_c[b * 2048 + ct * 64 + tid];
        __syncthreads();
        f32x4 sT[4] = {};
        #pragma unroll
        for (int ks = 0; ks < 2; ++ks)
            #pragma unroll
            for (int mf = 0; mf < 4; ++mf) {
                int row = mf * 16 + fr, sg = (ks * 4 + g) ^ (row & 7);
                short8 kk = *(const short8*)((const char*)K_s[0] + row * 128 + sg * 16);
                sT[mf] = __builtin_amdgcn_mfma_f32_16x16x32_bf16(kk, aq[ks], sT[mf], 0, 0, 0);
            }
        #pragma unroll
        for (int mf = 0; mf < 4; ++mf)
            #pragma unroll
            for (int i = 0; i < 4; ++i) {
                int key = mf * 16 + g * 4 + i;
                float pe = __builtin_amdgcn_exp2f(sT[mf][i] * CSC - m_q) * em_s[key];
                p_s[wave][fr][key] = f2bf(pe);
            }
        asm volatile("s_waitcnt lgkmcnt(0)" ::: "memory");
        #pragma unroll
        for (int ks = 0; ks < 2; ++ks) {
            short8 ap = *(const short8*)&p_s[wave][fr][ks * 32 + g * 8];
            #pragma unroll
            for (int n = 0; n < 4; ++n) {
                int row = n * 16 + fr, sg = (ks * 4 + g) ^ (row & 7);
                short8 bv = *(const short8*)((const char*)V_s[0] + row * 128 + sg * 16);
                acc_o[n] = __builtin_amdgcn_mfma_f32_16x16x32_bf16(ap, bv, acc_o[n], 0, 0, 0);
            }
        }
    }

    float linv = 1.0f / l_q;
    float invr[4];
    #pragma unroll
    for (int i = 0; i < 4; ++i) invr[i] = __shfl(linv, g * 4 + i, 64);
    #pragma unroll
    for (int n = 0; n < 4; ++n) {
        #pragma unroll
        for (int i = 0; i < 4; ++i) {
            size_t idx = ((size_t)(b * SEQC + gq + g * 4 + i)) * DIMC + h * DHC + n * 16 + fr;
            outb[idx] = f2bf(acc_o[n][i] * invr[i]);
        }
    }
}

// ---------------- aux writeback ----------------
__global__ void aux_write_kernel(const float* __restrict__ aux, float* __restrict__ dst) {
    dst[0] = aux[0];
}

extern "C" void kernel_launch(void* const* d_in, const int* in_sizes, int n_in,
                              void* d_out, int out_size, void* d_ws, size_t ws_size,
                              hipStream_t stream) {
    const int*   tokens    = (const int*)d_in[0];
    const float* mems      = (const float*)d_in[1];
    const int*   times     = (const int*)d_in[2];
    const float* token_emb = (const float*)d_in[3];
    const float* expire_W  = (const float*)d_in[4];
    const float* expire_b  = (const float*)d_in[5];
    const float* ln1_g     = (const float*)d_in[6];
    const float* ln1_b     = (const float*)d_in[7];
    const float* Wq        = (const float*)d_in[8];
    const float* Wkv       = (const float*)d_in[9];
    const float* Wo        = (const float*)d_in[10];
    const float* bo        = (const float*)d_in[11];
    const float* ln2_g     = (const float*)d_in[12];
    const float* ln2_b     = (const float*)d_in[13];
    const float* W1        = (const float*)d_in[14];
    const float* b1        = (const float*)d_in[15];
    const float* W2        = (const float*)d_in[16];
    const float* b2        = (const float*)d_in[17];
    const float* logits_W  = (const float*)d_in[18];
    const float* logits_b  = (const float*)d_in[19];

    float* out = (float*)d_out;
    float* ws  = (float*)d_ws;

    // workspace layout (float offsets)
    float* x = ws;                                                  //  0       (2,097,152)
    unsigned short* qb_b  = (unsigned short*)(ws + 2097152);        //  1,048,576 f
    unsigned short* kv_b  = (unsigned short*)(ws + 3145728);        //  5,242,880 f (K-only)
    unsigned short* vTl   = (unsigned short*)(ws + 8388608);        //  1,048,576 f
    unsigned short* vTc   = (unsigned short*)(ws + 9437184);        //  1,048,576 f
    unsigned short* xn_b  = (unsigned short*)(ws + 10485760);       //  1,048,576 f
    unsigned short* attn_b= (unsigned short*)(ws + 11534336);       //  1,048,576 f
    unsigned short* ffn_b = (unsigned short*)(ws + 12582912);       //  4,194,304 f
    unsigned short* mem_b = (unsigned short*)(ws + 16777216);       //  4,194,304 f
    unsigned short* x_b   = (unsigned short*)(ws + 20971520);       //  1,048,576 f
    unsigned short* wq_t  = (unsigned short*)(ws + 22020096);       //    524,288 f
    unsigned short* wkv_t = (unsigned short*)(ws + 22544384);       //  1,048,576 f
    unsigned short* wo_t  = (unsigned short*)(ws + 23592960);       //    524,288 f
    unsigned short* w1_t  = (unsigned short*)(ws + 24117248);       //  2,097,152 f
    unsigned short* w2_t  = (unsigned short*)(ws + 26214400);       //  2,097,152 f
    float* exps = ws + 28311552;                                    //      8,192 f
    float* aux  = ws + 28319744;                                    //         16 f
    int*   cidx = (int*)(ws + 28319760);                            //      8,192
    float* em_c = ws + 28327952;                                    //      8,192
    int*   cnt  = (int*)(ws + 28336144);                            //          4
    // logits_W^T aliases qb_b..mem_b (all dead after last layer); ends before x_b
    unsigned short* lw_t = (unsigned short*)(ws + 2097152);         // needs 16,384,000 f

    float* out_logits = out;                // 65,536,000
    float* out_mems   = out + 65536000;     // 33,554,432
    float* out_times  = out + 99090432;     // 8,192

    embed_kernel<<<BC * SEQC, 256, 0, stream>>>(tokens, token_emb, x);
    times_init_kernel<<<32, 256, 0, stream>>>(times, out_times, aux);

    for (int d = 0; d < 4; ++d) {
        const float* mem_d = mems + (size_t)d * BC * MC * DIMC;
        prep_kernel<<<PREP_TOT, 256, 0, stream>>>(
            mem_d, x, expire_W + d * DIMC, expire_b + d, exps, aux,
            mem_b, out_mems + (size_t)d * BC * MC * DIMC,
            ln1_g + d * DIMC, ln1_b + d * DIMC, xn_b,
            Wq + (size_t)d * DIMC * DIMC, Wkv + (size_t)d * DIMC * 2 * DIMC,
            Wo + (size_t)d * DIMC * DIMC, W1 + (size_t)d * DIMC * 4 * DIMC,
            W2 + (size_t)d * 4 * DIMC * DIMC,
            wq_t, wkv_t, wo_t, w1_t, w2_t);
        compact_kernel<<<BC, 64, 0, stream>>>(exps, times + d * MC, cidx, em_c, cnt);
        qkv_gemm_kernel<<<1152, 256, 0, stream>>>(xn_b, mem_b, wq_t, wkv_t,
                                                  cidx, cnt, qb_b, kv_b, vTl, vTc);
        attn_mfma_kernel<<<512, 256, 0, stream>>>(
            qb_b, kv_b, vTl, vTc, cidx, em_c, cnt, attn_b);
        gemm64_kernel<<<dim3(8, 32), 256, 0, stream>>>(
            attn_b, wo_t, bo + d * DIMC, x, x, nullptr, DIMC);
        ln_kernel<<<BC * SEQC, 256, 0, stream>>>(x, ln2_g + d * DIMC, ln2_b + d * DIMC, xn_b);
        ffn1_kernel<<<dim3(32, 16), 256, 0, stream>>>(xn_b, w1_t, b1 + d * 4 * DIMC, ffn_b);
        if (d < 3) {
            gemm64_kernel<<<dim3(8, 32), 256, 0, stream>>>(
                ffn_b, w2_t, b2 + d * DIMC, x, x, nullptr, 4 * DIMC);
        } else {
            gemm64_kernel<<<dim3(8, 32), 256, 0, stream>>>(
                ffn_b, w2_t, b2 + d * DIMC, x, nullptr, x_b, 4 * DIMC);
        }
    }

    wt_kernel<<<dim3(1000, 32), 256, 0, stream>>>(logits_W, lw_t, DIMC, VOCABC);
    logits_kernel<<<1000, 512, 0, stream>>>(x_b, lw_t, logits_b, out_logits);
    aux_write_kernel<<<1, 1, 0, stream>>>(aux, out + 99098624);
}

// Round 16
// 1683.087 us; speedup vs baseline: 1.0335x; 1.0214x over previous
//
#include <hip/hip_runtime.h>
#include <cmath>

// Problem constants
#define DIMC   1024
#define SEQC   512
#define BC     4
#define MC     2048      // MAXMEM
#define CTXC   2560      // MC + SEQC
#define HEADSC 16
#define DHC    64
#define VOCABC 32000
#define MAXC   512       // compact-slot capacity (live keys ~64)

using short8 = __attribute__((ext_vector_type(8))) short;
using f32x4  = __attribute__((ext_vector_type(4))) float;
using u16x4  = __attribute__((ext_vector_type(4))) unsigned short;
using u16x8  = __attribute__((ext_vector_type(8))) unsigned short;

__device__ __forceinline__ unsigned short f2bf(float f) {
    unsigned u = __float_as_uint(f);
    unsigned r = (u + 0x7fffu + ((u >> 16) & 1u)) >> 16;
    return (unsigned short)r;
}

__device__ __forceinline__ void glds16(const unsigned short* g, char* l) {
    __builtin_amdgcn_global_load_lds(
        (const __attribute__((address_space(1))) void*)g,
        (__attribute__((address_space(3))) void*)l, 16, 0, 0);
}

// ---------------- embed ----------------
__global__ __launch_bounds__(256) void embed_kernel(const int* __restrict__ tokens,
                                                    const float* __restrict__ emb,
                                                    float* __restrict__ x) {
    int row = blockIdx.x;
    int tok = tokens[row];
    const float4 v = *(const float4*)(emb + (size_t)tok * DIMC + threadIdx.x * 4);
    *(float4*)(x + (size_t)row * DIMC + threadIdx.x * 4) = v;
}

// ---------------- new_times + aux zero ----------------
__global__ __launch_bounds__(256) void times_init_kernel(const int* __restrict__ times,
                                                         float* __restrict__ out_times,
                                                         float* __restrict__ aux) {
    int i = blockIdx.x * 256 + threadIdx.x;
    if (i == 0) aux[0] = 0.0f;
    if (i < 4 * MC) {
        int d = i >> 11, m = i & (MC - 1);
        out_times[i] = (m < MC - SEQC) ? (float)(times[d * MC + SEQC + m] + SEQC)
                                       : (float)(MC - 1 - m);
    }
}

// ---------------- fused per-layer prep ----------------
#define PREP_MEM 8192
#define PREP_XC  10240
#define PREP_LN  12288
#define PREP_TOT 24576
__global__ __launch_bounds__(256) void prep_kernel(
    const float* __restrict__ mem_d, const float* __restrict__ x,
    const float* __restrict__ eW, const float* __restrict__ eb,
    float* __restrict__ exps, float* __restrict__ aux,
    unsigned short* __restrict__ mem_b, float* __restrict__ out_mems_d,
    const float* __restrict__ g1, const float* __restrict__ b1v,
    unsigned short* __restrict__ xn_b,
    const float* __restrict__ Wq, const float* __restrict__ Wkv,
    const float* __restrict__ Wo, const float* __restrict__ W1,
    const float* __restrict__ W2,
    unsigned short* __restrict__ wq_t, unsigned short* __restrict__ wkv_t,
    unsigned short* __restrict__ wo_t, unsigned short* __restrict__ w1_t,
    unsigned short* __restrict__ w2_t) {
    __shared__ float sh[1056];
    const int bid = blockIdx.x, tid = threadIdx.x;
    if (bid < PREP_MEM) {
        int row = bid;                       // b*2048 + m
        int m = row & 2047, b = row >> 11;
        const float4 v = *(const float4*)(mem_d + (size_t)row * DIMC + tid * 4);
        const float4 w = *(const float4*)(eW + tid * 4);
        float s = v.x * w.x + v.y * w.y + v.z * w.z + v.w * w.w;
        for (int off = 32; off; off >>= 1) s += __shfl_down(s, off, 64);
        int wid = tid >> 6, lane = tid & 63;
        if (lane == 0) sh[wid] = s;
        u16x4 o = { f2bf(v.x), f2bf(v.y), f2bf(v.z), f2bf(v.w) };
        *(u16x4*)(mem_b + (size_t)row * DIMC + tid * 4) = o;
        if (m >= SEQC)
            *(float4*)(out_mems_d + ((size_t)(b * MC + m - SEQC)) * DIMC + tid * 4) = v;
        __syncthreads();
        if (tid == 0) {
            float z = sh[0] + sh[1] + sh[2] + sh[3] + eb[0];
            float e = (float)MC / (1.0f + expf(-z));
            exps[row] = e;
            atomicAdd(aux, e * (1e-6f / (float)SEQC));
        }
    } else if (bid < PREP_XC) {
        int r = bid - PREP_MEM;              // b*512 + i
        int b = r >> 9, i = r & 511;
        const float4 v = *(const float4*)(x + (size_t)r * DIMC + tid * 4);
        *(float4*)(out_mems_d + ((size_t)(b * MC + MC - SEQC + i)) * DIMC + tid * 4) = v;
    } else if (bid < PREP_LN) {
        int row = bid - PREP_XC;
        const float4 v = *(const float4*)(x + (size_t)row * DIMC + tid * 4);
        float s = v.x + v.y + v.z + v.w;
        float q = v.x * v.x + v.y * v.y + v.z * v.z + v.w * v.w;
        for (int off = 32; off; off >>= 1) {
            s += __shfl_down(s, off, 64);
            q += __shfl_down(q, off, 64);
        }
        int wid = tid >> 6, lane = tid & 63;
        if (lane == 0) { sh[wid] = s; sh[4 + wid] = q; }
        __syncthreads();
        if (tid == 0) {
            float S = sh[0] + sh[1] + sh[2] + sh[3];
            float Q = sh[4] + sh[5] + sh[6] + sh[7];
            float mu = S / DIMC;
            float var = Q / DIMC - mu * mu;
            sh[8] = mu;
            sh[9] = rsqrtf(var + 1e-5f);
        }
        __syncthreads();
        float mu = sh[8], rstd = sh[9];
        const float4 gg = *(const float4*)(g1 + tid * 4);
        const float4 bb = *(const float4*)(b1v + tid * 4);
        u16x4 o = { f2bf((v.x - mu) * rstd * gg.x + bb.x),
                    f2bf((v.y - mu) * rstd * gg.y + bb.y),
                    f2bf((v.z - mu) * rstd * gg.z + bb.z),
                    f2bf((v.w - mu) * rstd * gg.w + bb.w) };
        *(u16x4*)(xn_b + (size_t)row * DIMC + tid * 4) = o;
    } else {
        int t = bid - PREP_LN;
        const float* W; unsigned short* Wt; int K, N, tx, ty;
        if (t < 1024)      { W = Wq;  Wt = wq_t;  K = 1024; N = 1024; tx = t & 31;  ty = t >> 5; }
        else if (t < 3072) { int u = t - 1024; W = Wkv; Wt = wkv_t; K = 1024; N = 2048; tx = u & 63;  ty = u >> 6; }
        else if (t < 4096) { int u = t - 3072; W = Wo;  Wt = wo_t;  K = 1024; N = 1024; tx = u & 31;  ty = u >> 5; }
        else if (t < 8192) { int u = t - 4096; W = W1;  Wt = w1_t;  K = 1024; N = 4096; tx = u & 127; ty = u >> 7; }
        else               { int u = t - 8192; W = W2;  Wt = w2_t;  K = 4096; N = 1024; tx = u & 31;  ty = u >> 5; }
        int n0 = tx * 32, k0 = ty * 32;
        int r = tid >> 3, c = (tid & 7) * 4;
        const float4 v = *(const float4*)(W + (size_t)(k0 + r) * N + n0 + c);
        sh[r * 33 + c] = v.x; sh[r * 33 + c + 1] = v.y;
        sh[r * 33 + c + 2] = v.z; sh[r * 33 + c + 3] = v.w;
        __syncthreads();
        u16x4 o = { f2bf(sh[(c + 0) * 33 + r]), f2bf(sh[(c + 1) * 33 + r]),
                    f2bf(sh[(c + 2) * 33 + r]), f2bf(sh[(c + 3) * 33 + r]) };
        *(u16x4*)(Wt + (size_t)(n0 + r) * K + k0 + c) = o;
    }
}

// ---------------- compact live memory keys (deterministic ballot scan) ----------------
__global__ __launch_bounds__(64) void compact_kernel(
    const float* __restrict__ exps, const int* __restrict__ times_d,
    int* __restrict__ cidx, float* __restrict__ em_c, int* __restrict__ cnt) {
    int b = blockIdx.x, lane = threadIdx.x;
    int c = 0;
    for (int it = 0; it < 32; ++it) {
        int j = it * 64 + lane;
        float e = exps[b * MC + j];
        float rr = (e - (float)times_d[j]) * (1.0f / 128.0f) + 1.0f;
        float em = fminf(fmaxf(rr, 0.0f), 1.0f);
        unsigned long long mk = __ballot(em > 0.0f);
        int pos = c + __popcll(mk & ((1ull << lane) - 1ull));
        if (em > 0.0f) {
            cidx[b * 2048 + pos] = j;
            em_c[b * 2048 + pos] = em;
        }
        c += __popcll(mk);
    }
    int padded = (c + 63) & ~63;
    int fill_to = padded < MAXC ? MAXC : padded;
    for (int p = c + lane; p < fill_to; p += 64) {
        cidx[b * 2048 + p] = 0;     // valid row; em=0 kills contribution
        em_c[b * 2048 + p] = 0.0f;
    }
    int tiles = padded >> 6;
    if (tiles > (MAXC >> 6)) tiles = MAXC >> 6;
    if (lane == 0) cnt[b] = tiles;
}

// ---------------- LayerNorm (fp32 in, bf16 out) — LN2 ----------------
__global__ __launch_bounds__(256) void ln_kernel(const float* __restrict__ in,
                                                 const float* __restrict__ g,
                                                 const float* __restrict__ b,
                                                 unsigned short* __restrict__ outb) {
    int row = blockIdx.x;
    int tid = threadIdx.x;
    const float4 v = *(const float4*)(in + (size_t)row * DIMC + tid * 4);
    float s = v.x + v.y + v.z + v.w;
    float q = v.x * v.x + v.y * v.y + v.z * v.z + v.w * v.w;
    for (int off = 32; off; off >>= 1) {
        s += __shfl_down(s, off, 64);
        q += __shfl_down(q, off, 64);
    }
    __shared__ float ss[4], sq[4];
    int wid = tid >> 6, lane = tid & 63;
    if (lane == 0) { ss[wid] = s; sq[wid] = q; }
    __syncthreads();
    if (tid == 0) {
        float S = ss[0] + ss[1] + ss[2] + ss[3];
        float Q = sq[0] + sq[1] + sq[2] + sq[3];
        float mu = S / DIMC;
        float var = Q / DIMC - mu * mu;
        ss[0] = mu;
        sq[0] = rsqrtf(var + 1e-5f);
    }
    __syncthreads();
    float mu = ss[0], rstd = sq[0];
    const float4 gg = *(const float4*)(g + tid * 4);
    const float4 bb = *(const float4*)(b + tid * 4);
    u16x4 o = { f2bf((v.x - mu) * rstd * gg.x + bb.x),
                f2bf((v.y - mu) * rstd * gg.y + bb.y),
                f2bf((v.z - mu) * rstd * gg.z + bb.z),
                f2bf((v.w - mu) * rstd * gg.w + bb.w) };
    *(u16x4*)(outb + (size_t)row * DIMC + tid * 4) = o;
}

// ---------------- weight convert + transpose (logits_W only) ----------------
__global__ __launch_bounds__(256) void wt_kernel(const float* __restrict__ W,
                                                 unsigned short* __restrict__ Wt,
                                                 int K, int N) {
    __shared__ float t[32][33];
    int tid = threadIdx.x;
    int n0 = blockIdx.x * 32, k0 = blockIdx.y * 32;
    int r = tid >> 3, c = (tid & 7) * 4;
    const float4 v = *(const float4*)(W + (size_t)(k0 + r) * N + n0 + c);
    t[r][c] = v.x; t[r][c + 1] = v.y; t[r][c + 2] = v.z; t[r][c + 3] = v.w;
    __syncthreads();
    u16x4 o = { f2bf(t[c + 0][r]), f2bf(t[c + 1][r]),
                f2bf(t[c + 2][r]), f2bf(t[c + 3][r]) };
    *(u16x4*)(Wt + (size_t)(n0 + r) * K + k0 + c) = o;
}

// ---------------- bf16 MFMA GEMM body — depth-1 counted-vmcnt pipeline + T2 bank swizzle ----------------
// LDS rows are 64B (32 bf16): un-swizzled ds_read_b128 is an 8-way bank conflict
// (lanes 0-15 at fixed 16B slot, stride 64B). Fix (rule 21): pre-swizzle the GLOBAL
// source segment seg^((row>>1)&3) (LDS stays linear for global_load_lds) and XOR the
// same involution into the read slot. Swizzle value is invariant across fragment
// strides (+16 rows) and staging halves (+64/128 rows).
// AMODE: 0 = A[r][K]; 2 = gather A rows via cidx.
// OMODE: 0 direct; 1 mem->ctx rows; 2 local->ctx rows; 3 local V transposed; 4 compact V transposed.
template<int AMODE, bool BIAS, bool GELU, bool RES, int OMODE, int RT>
__device__ __forceinline__ void gemm_body(
    unsigned short* As, unsigned short* Bs,
    const unsigned short* __restrict__ A, const int* __restrict__ gidx,
    const unsigned short* __restrict__ Wt, const float* __restrict__ bias,
    const float* __restrict__ res, float* __restrict__ Cf,
    unsigned short* __restrict__ Cb, int K, int N, int bx, int by) {
    constexpr int MF = RT / 32;
    const int tid = threadIdx.x;
    const int lane = tid & 63, wave = tid >> 6;
    const int row0 = by * RT, col0 = bx * 128;

    const int seg = tid & 3;
    const int rr0 = tid >> 2;
    const int sseg8 = (seg ^ ((rr0 >> 1) & 3)) * 8;   // source pre-swizzle (elements)
    const unsigned short* arow[RT / 64];
    #pragma unroll
    for (int p = 0; p < RT / 64; ++p) {
        int r = row0 + p * 64 + rr0;
        if (AMODE == 2) {
            int b = r >> 9, slot = r & (MAXC - 1);
            arow[p] = A + ((size_t)(b * 2048 + gidx[b * 2048 + slot])) * K;
        } else {
            arow[p] = A + (size_t)r * K;
        }
        arow[p] += sseg8;
    }
    const unsigned short* brow[2];
    #pragma unroll
    for (int p = 0; p < 2; ++p)
        brow[p] = Wt + (size_t)(col0 + p * 64 + rr0) * K + sseg8;

    char* lA = (char*)As + (tid & 192) * 16;
    char* lB = (char*)Bs + (tid & 192) * 16;

    auto stage = [&](int k0, int q) {
        char* a = lA + q * (RT * 64);
        glds16(arow[0] + k0, a);
        if (RT == 128) glds16(arow[1] + k0, a + 4096);
        char* bp = lB + q * 8192;
        glds16(brow[0] + k0, bp);
        glds16(brow[1] + k0, bp + 4096);
    };

    f32x4 acc[MF][4] = {};

    const int wr = (wave >> 1) * (RT / 2), wc = (wave & 1) * 64;
    const int fr = lane & 15;
    const int g4 = lane >> 4;
    const int kA8 = (g4 ^ (((wr + fr) >> 1) & 3)) * 8;   // swizzled read slot (elements)
    const int kB8 = (g4 ^ (((wc + fr) >> 1) & 3)) * 8;

    stage(0, 0);
    int cur = 0;
    for (int k0 = 0; k0 < K; k0 += 32) {
        if (k0 + 32 < K) {
            stage(k0 + 32, cur ^ 1);
            if (RT == 128) asm volatile("s_waitcnt vmcnt(4)" ::: "memory");
            else           asm volatile("s_waitcnt vmcnt(3)" ::: "memory");
        } else {
            asm volatile("s_waitcnt vmcnt(0)" ::: "memory");
        }
        __builtin_amdgcn_s_barrier();
        __builtin_amdgcn_sched_barrier(0);
        const unsigned short* Ar = As + cur * (RT * 32) + (size_t)(wr + fr) * 32 + kA8;
        const unsigned short* Br = Bs + cur * (128 * 32) + (size_t)(wc + fr) * 32 + kB8;
        short8 a[MF], b[4];
        #pragma unroll
        for (int m = 0; m < MF; ++m) a[m] = *(const short8*)(Ar + m * 16 * 32);
        #pragma unroll
        for (int n = 0; n < 4; ++n) b[n] = *(const short8*)(Br + n * 16 * 32);
        #pragma unroll
        for (int m = 0; m < MF; ++m)
            #pragma unroll
            for (int n = 0; n < 4; ++n)
                acc[m][n] = __builtin_amdgcn_mfma_f32_16x16x32_bf16(a[m], b[n], acc[m][n], 0, 0, 0);
        __builtin_amdgcn_s_barrier();
        cur ^= 1;
    }

    const int orow = row0 + wr + (lane >> 4) * 4;
    const int ocol = col0 + wc + fr;
    if (OMODE >= 3) {
        #pragma unroll
        for (int n = 0; n < 4; ++n) {
            int c = ocol + n * 16;
            #pragma unroll
            for (int m = 0; m < MF; ++m) {
                int r0 = orow + m * 16;
                int b = r0 >> 9, i = r0 & 511;
                size_t addr = (OMODE == 3)
                    ? ((size_t)(b * 1024 + c)) * 512 + i
                    : ((size_t)(b * 1024 + c)) * MAXC + i;
                u16x4 o = { f2bf(acc[m][n][0]), f2bf(acc[m][n][1]),
                            f2bf(acc[m][n][2]), f2bf(acc[m][n][3]) };
                *(u16x4*)(Cb + addr) = o;
            }
        }
        return;
    }
    #pragma unroll
    for (int n = 0; n < 4; ++n) {
        int c = ocol + n * 16;
        float bv = BIAS ? bias[c] : 0.0f;
        #pragma unroll
        for (int m = 0; m < MF; ++m) {
            #pragma unroll
            for (int i = 0; i < 4; ++i) {
                int r0 = orow + m * 16 + i;
                size_t orr = r0;
                if (OMODE == 1) orr = (size_t)r0 + (size_t)(r0 >> 11) * 512;
                if (OMODE == 2) orr = (size_t)r0 + (size_t)(r0 >> 9) * 2048 + 2048;
                size_t idx = orr * N + c;
                float v = acc[m][n][i] + bv;
                if (GELU) v = 0.5f * v * (1.0f + erff(v * 0.70710678118f));
                if (RES) v += res[idx];
                if (Cf) Cf[idx] = v;
                if (Cb) Cb[idx] = f2bf(v);
            }
        }
    }
}

// Fused: Q(128) + local-K(128) + mem-K(512) + local-V transposed(128) + compact-V transposed(256)
__global__ __launch_bounds__(256) void qkv_gemm_kernel(
    const unsigned short* __restrict__ xn_b, const unsigned short* __restrict__ mem_b,
    const unsigned short* __restrict__ wq_t, const unsigned short* __restrict__ wkv_t,
    const int* __restrict__ cidx, const int* __restrict__ cnt,
    unsigned short* __restrict__ qb, unsigned short* __restrict__ kvb,
    unsigned short* __restrict__ vTl, unsigned short* __restrict__ vTc) {
    __shared__ unsigned short As[2 * 128 * 32];
    __shared__ unsigned short Bs[2 * 128 * 32];
    int id = blockIdx.x;
    if (id < 128) {
        gemm_body<0, false, false, false, 0, 128>(As, Bs, xn_b, nullptr, wq_t,
            nullptr, nullptr, nullptr, qb, 1024, 1024, id & 7, id >> 3);
    } else if (id < 256) {
        id -= 128;  // local rows -> ctx rows, K half of wkv
        gemm_body<0, false, false, false, 2, 128>(As, Bs, xn_b, nullptr, wkv_t,
            nullptr, nullptr, nullptr, kvb, 1024, 1024, id & 7, id >> 3);
    } else if (id < 768) {
        id -= 256;  // mem rows -> ctx rows, K half of wkv
        gemm_body<0, false, false, false, 1, 128>(As, Bs, mem_b, nullptr, wkv_t,
            nullptr, nullptr, nullptr, kvb, 1024, 1024, id & 7, id >> 3);
    } else if (id < 896) {
        id -= 768;  // local V -> vTl transposed
        gemm_body<0, false, false, false, 3, 128>(As, Bs, xn_b, nullptr,
            wkv_t + (size_t)1024 * 1024, nullptr, nullptr, nullptr, vTl,
            1024, 1024, id & 7, id >> 3);
    } else {
        id -= 896;  // compact V: gather mem rows by cidx -> vTc transposed
        int by = id >> 3;
        int b = (by * 64) >> 9, slot0 = (by * 64) & (MAXC - 1);
        if (slot0 >= cnt[b] * 64) return;
        gemm_body<2, false, false, false, 4, 64>(As, Bs, mem_b, cidx,
            wkv_t + (size_t)1024 * 1024, nullptr, nullptr, nullptr, vTc,
            1024, 1024, id & 7, by);
    }
}

// RT=64 GEMM with bias+residual, N=1024 (Wo and FFN2)
__global__ __launch_bounds__(256) void gemm64_kernel(
    const unsigned short* __restrict__ A, const unsigned short* __restrict__ Wt,
    const float* __restrict__ bias, const float* __restrict__ res,
    float* __restrict__ Cf, unsigned short* __restrict__ Cb, int K) {
    __shared__ unsigned short As[2 * 64 * 32];
    __shared__ unsigned short Bs[2 * 128 * 32];
    gemm_body<0, true, false, true, 0, 64>(As, Bs, A, nullptr, Wt, bias, res,
        Cf, Cb, K, 1024, blockIdx.x, blockIdx.y);
}

// FFN1: gelu, bf16 out
__global__ __launch_bounds__(256) void ffn1_kernel(
    const unsigned short* __restrict__ A, const unsigned short* __restrict__ Wt,
    const float* __restrict__ bias, unsigned short* __restrict__ Cb) {
    __shared__ unsigned short As[2 * 128 * 32];
    __shared__ unsigned short Bs[2 * 128 * 32];
    gemm_body<0, true, true, false, 0, 128>(As, Bs, A, nullptr, Wt, bias, nullptr,
        nullptr, Cb, 1024, 4096, blockIdx.x, blockIdx.y);
}

// ---------------- logits: 256x256 tile, 512 threads, 8 waves (2x4), counted-vmcnt + T2 swizzle ----------------
__global__ __launch_bounds__(512, 2) void logits_kernel(
    const unsigned short* __restrict__ A, const unsigned short* __restrict__ Wt,
    const float* __restrict__ bias, float* __restrict__ Cf) {
    __shared__ unsigned short As[2 * 256 * 32];
    __shared__ unsigned short Bs[2 * 256 * 32];
    const int L = blockIdx.x;
    const int wid = (L & 7) * 125 + (L >> 3);
    const int ct = wid / 8, rt = wid & 7;
    const int row0 = rt * 256, col0 = ct * 256;
    const int tid = threadIdx.x;
    const int lane = tid & 63, wave = tid >> 6;

    const int seg = tid & 3;
    const int rr0 = tid >> 2;                 // 0..127
    const int sseg8 = (seg ^ ((rr0 >> 1) & 3)) * 8;   // source pre-swizzle
    const unsigned short* arow[2];
    const unsigned short* brow[2];
    #pragma unroll
    for (int p = 0; p < 2; ++p) {
        arow[p] = A + (size_t)(row0 + p * 128 + rr0) * 1024 + sseg8;
        brow[p] = Wt + (size_t)(col0 + p * 128 + rr0) * 1024 + sseg8;
    }
    char* lA = (char*)As + (tid & 448) * 16;  // wave-uniform base (8 waves)
    char* lB = (char*)Bs + (tid & 448) * 16;

    auto stage = [&](int k0, int q) {
        char* a = lA + q * 16384;
        char* bp = lB + q * 16384;
        glds16(arow[0] + k0, a);
        glds16(arow[1] + k0, a + 8192);
        glds16(brow[0] + k0, bp);
        glds16(brow[1] + k0, bp + 8192);
    };

    f32x4 acc[8][4] = {};
    const int wr = (wave >> 2) * 128, wc = (wave & 3) * 64;
    const int fr = lane & 15;
    const int g4 = lane >> 4;
    const int kA8 = (g4 ^ (((wr + fr) >> 1) & 3)) * 8;
    const int kB8 = (g4 ^ (((wc + fr) >> 1) & 3)) * 8;

    stage(0, 0);
    int cur = 0;
    for (int k0 = 0; k0 < 1024; k0 += 32) {
        if (k0 + 32 < 1024) {
            stage(k0 + 32, cur ^ 1);
            asm volatile("s_waitcnt vmcnt(4)" ::: "memory");
        } else {
            asm volatile("s_waitcnt vmcnt(0)" ::: "memory");
        }
        __builtin_amdgcn_s_barrier();
        __builtin_amdgcn_sched_barrier(0);
        const unsigned short* Ar = As + cur * 8192 + (size_t)(wr + fr) * 32 + kA8;
        const unsigned short* Br = Bs + cur * 8192 + (size_t)(wc + fr) * 32 + kB8;
        short8 a[8], b[4];
        #pragma unroll
        for (int m = 0; m < 8; ++m) a[m] = *(const short8*)(Ar + m * 16 * 32);
        #pragma unroll
        for (int n = 0; n < 4; ++n) b[n] = *(const short8*)(Br + n * 16 * 32);
        #pragma unroll
        for (int m = 0; m < 8; ++m)
            #pragma unroll
            for (int n = 0; n < 4; ++n)
                acc[m][n] = __builtin_amdgcn_mfma_f32_16x16x32_bf16(a[m], b[n], acc[m][n], 0, 0, 0);
        __builtin_amdgcn_s_barrier();
        cur ^= 1;
    }

    const int orow = row0 + wr + (lane >> 4) * 4;
    const int ocol = col0 + wc + fr;
    #pragma unroll
    for (int n = 0; n < 4; ++n) {
        int c = ocol + n * 16;
        float bv = bias[c];
        #pragma unroll
        for (int m = 0; m < 8; ++m) {
            #pragma unroll
            for (int i = 0; i < 4; ++i)
                Cf[(size_t)(orow + m * 16 + i) * VOCABC + c] = acc[m][n][i] + bv;
        }
    }
}

// ---------------- 3-phase MFMA flash attention — log2-domain softmax ----------------
// grid = 512 (8 qt x 16 h x 4 b), XCD-grouped; counted-vmcnt raw-barrier pipeline.
// Softmax in base-2: p = exp2(s*CSC - m2), CSC = 0.125*log2(e). Ratio-identical to base-e.
#define CSC 0.18033688011112042f
__global__ __launch_bounds__(256) void attn_mfma_kernel(
    const unsigned short* __restrict__ qb,
    const unsigned short* __restrict__ kvb,   // K-only [b][2560][1024]
    const unsigned short* __restrict__ vTl,   // [b*1024+d][512] local V transposed
    const unsigned short* __restrict__ vTc,   // [b*1024+d][MAXC] compact V transposed
    const int* __restrict__ cidx,
    const float* __restrict__ em_c,
    const int* __restrict__ cnt,
    unsigned short* __restrict__ outb) {
    __shared__ unsigned short K_s[2][64 * 64];
    __shared__ unsigned short V_s[2][64 * 64];
    __shared__ unsigned short p_s[4][16][72];
    __shared__ float em_s[64];
    const int tid = threadIdx.x;
    const int lane = tid & 63, wave = tid >> 6;
    const int L = blockIdx.x;
    const int ix = L >> 3;
    const int qt = ix & 7;
    const int gidx = (L & 7) * 8 + (ix >> 3);   // same (h,b) group on same XCD
    const int h = gidx & 15, b = gidx >> 4;
    const int fr = lane & 15, g = lane >> 4;
    const int gq = qt * 64 + wave * 16;

    short8 aq[2];
    {
        const unsigned short* qp = qb + ((size_t)(b * SEQC + gq + fr)) * DIMC + h * DHC + g * 8;
        aq[0] = *(const short8*)qp;
        aq[1] = *(const short8*)(qp + 32);
    }

    const int sr = tid >> 3, ss = tid & 7;       // sr in [0,32)
    const int sw = (ss ^ (sr & 7)) * 8;          // same for both p (p*32 keeps r&7)
    const int wbase = (tid & 192) * 16;          // wave-uniform LDS byte base (4 waves)

    f32x4 acc_o[4] = {};
    float m_q = -1e30f, l_q = 0.0f;              // m_q, l_q live in log2 domain

    const int nt = 33 + qt;    // 32 mem tiles + qt+1 local tiles

    auto stage12 = [&](int t, int q) {
        const int jbase = t * 64;
        #pragma unroll
        for (int p = 0; p < 2; ++p) {
            int r = sr + p * 32;
            glds16(kvb + ((size_t)(b * CTXC + jbase + r)) * 1024 + h * DHC + sw,
                   (char*)K_s[q] + wbase + p * 4096);
            if (t >= 32)
                glds16(vTl + ((size_t)(b * 1024 + h * DHC + r)) * 512 + (jbase - 2048) + sw,
                       (char*)V_s[q] + wbase + p * 4096);
        }
    };

    stage12(0, 0);
    asm volatile("s_waitcnt vmcnt(0)" ::: "memory");
    __builtin_amdgcn_s_barrier();
    int cur = 0;
    for (int t = 0; t < nt; ++t) {
        if (t + 1 < nt) stage12(t + 1, cur ^ 1);
        // wait for stage(t)'s loads only; stage(t+1) stays in flight
        if (t + 1 >= nt)      asm volatile("s_waitcnt vmcnt(0)" ::: "memory");
        else if (t + 1 >= 32) asm volatile("s_waitcnt vmcnt(4)" ::: "memory");
        else                  asm volatile("s_waitcnt vmcnt(2)" ::: "memory");
        __builtin_amdgcn_s_barrier();
        __builtin_amdgcn_sched_barrier(0);

        // S^T = K @ Q : key axis lane-local
        f32x4 sT[4] = {};
        #pragma unroll
        for (int ks = 0; ks < 2; ++ks)
            #pragma unroll
            for (int mf = 0; mf < 4; ++mf) {
                int row = mf * 16 + fr, sg = (ks * 4 + g) ^ (row & 7);
                short8 kk = *(const short8*)((const char*)K_s[cur] + row * 128 + sg * 16);
                sT[mf] = __builtin_amdgcn_mfma_f32_16x16x32_bf16(kk, aq[ks], sT[mf], 0, 0, 0);
            }

        if (t < 32) {
            // denominator-only (acc_o still zero -> no rescale)
            float mx = sT[0][0];
            #pragma unroll
            for (int mf = 0; mf < 4; ++mf)
                #pragma unroll
                for (int i = 0; i < 4; ++i) mx = fmaxf(mx, sT[mf][i]);
            mx *= CSC;
            mx = fmaxf(mx, __shfl_xor(mx, 16, 64));
            mx = fmaxf(mx, __shfl_xor(mx, 32, 64));
            float mnew = fmaxf(m_q, mx);
            float fs = __builtin_amdgcn_exp2f(m_q - mnew);
            m_q = mnew;
            float ps = 0.0f;
            #pragma unroll
            for (int mf = 0; mf < 4; ++mf)
                #pragma unroll
                for (int i = 0; i < 4; ++i)
                    ps += __builtin_amdgcn_exp2f(sT[mf][i] * CSC - mnew);
            ps += __shfl_xor(ps, 16, 64);
            ps += __shfl_xor(ps, 32, 64);
            l_q = l_q * fs + ps;
        } else {
            const int lt = t - 32;
            const int kq = gq + fr - lt * 64;
            float sv[4][4];
            #pragma unroll
            for (int mf = 0; mf < 4; ++mf)
                #pragma unroll
                for (int i = 0; i < 4; ++i) {
                    int kl = mf * 16 + g * 4 + i;
                    sv[mf][i] = (kl <= kq) ? sT[mf][i] * CSC : -1e30f;
                }
            float mx = sv[0][0];
            #pragma unroll
            for (int mf = 0; mf < 4; ++mf)
                #pragma unroll
                for (int i = 0; i < 4; ++i) mx = fmaxf(mx, sv[mf][i]);
            mx = fmaxf(mx, __shfl_xor(mx, 16, 64));
            mx = fmaxf(mx, __shfl_xor(mx, 32, 64));
            float mnew = fmaxf(m_q, mx);
            float fs = __builtin_amdgcn_exp2f(m_q - mnew);
            m_q = mnew;
            float ps = 0.0f;
            #pragma unroll
            for (int mf = 0; mf < 4; ++mf)
                #pragma unroll
                for (int i = 0; i < 4; ++i) {
                    float pe = __builtin_amdgcn_exp2f(sv[mf][i] - mnew);
                    ps += pe;
                    p_s[wave][fr][mf * 16 + g * 4 + i] = f2bf(pe);
                }
            ps += __shfl_xor(ps, 16, 64);
            ps += __shfl_xor(ps, 32, 64);
            l_q = l_q * fs + ps;
            float fsr[4];
            #pragma unroll
            for (int i = 0; i < 4; ++i) fsr[i] = __shfl(fs, g * 4 + i, 64);
            #pragma unroll
            for (int n = 0; n < 4; ++n)
                #pragma unroll
                for (int i = 0; i < 4; ++i) acc_o[n][i] *= fsr[i];
            asm volatile("s_waitcnt lgkmcnt(0)" ::: "memory");
            #pragma unroll
            for (int ks = 0; ks < 2; ++ks) {
                short8 ap = *(const short8*)&p_s[wave][fr][ks * 32 + g * 8];
                #pragma unroll
                for (int n = 0; n < 4; ++n) {
                    int row = n * 16 + fr, sg = (ks * 4 + g) ^ (row & 7);
                    short8 bv = *(const short8*)((const char*)V_s[cur] + row * 128 + sg * 16);
                    acc_o[n] = __builtin_amdgcn_mfma_f32_16x16x32_bf16(ap, bv, acc_o[n], 0, 0, 0);
                }
            }
        }
        __builtin_amdgcn_s_barrier();   // protect buf[cur^1] (overwritten next iter)
        cur ^= 1;
    }

    // ---- phase 3: compact live-mem tiles (final m,l; no m/l update) ----
    const int nct = cnt[b];
    for (int ct = 0; ct < nct; ++ct) {
        __syncthreads();
        #pragma unroll
        for (int p = 0; p < 2; ++p) {
            int r = sr + p * 32;
            int row = cidx[b * 2048 + ct * 64 + r];
            glds16(kvb + ((size_t)(b * CTXC + row)) * 1024 + h * DHC + sw,
                   (char*)K_s[0] + wbase + p * 4096);
            glds16(vTc + ((size_t)(b * 1024 + h * DHC + r)) * MAXC + ct * 64 + sw,
                   (char*)V_s[0] + wbase + p * 4096);
        }
        if (tid < 64) em_s[tid] = em_c[b * 2048 + ct * 64 + tid];
        __syncthreads();
        f32x4 sT[4] = {};
        #pragma unroll
        for (int ks = 0; ks < 2; ++ks)
            #pragma unroll
            for (int mf = 0; mf < 4; ++mf) {
                int row = mf * 16 + fr, sg = (ks * 4 + g) ^ (row & 7);
                short8 kk = *(const short8*)((const char*)K_s[0] + row * 128 + sg * 16);
                sT[mf] = __builtin_amdgcn_mfma_f32_16x16x32_bf16(kk, aq[ks], sT[mf], 0, 0, 0);
            }
        #pragma unroll
        for (int mf = 0; mf < 4; ++mf)
            #pragma unroll
            for (int i = 0; i < 4; ++i) {
                int key = mf * 16 + g * 4 + i;
                float pe = __builtin_amdgcn_exp2f(sT[mf][i] * CSC - m_q) * em_s[key];
                p_s[wave][fr][key] = f2bf(pe);
            }
        asm volatile("s_waitcnt lgkmcnt(0)" ::: "memory");
        #pragma unroll
        for (int ks = 0; ks < 2; ++ks) {
            short8 ap = *(const short8*)&p_s[wave][fr][ks * 32 + g * 8];
            #pragma unroll
            for (int n = 0; n < 4; ++n) {
                int row = n * 16 + fr, sg = (ks * 4 + g) ^ (row & 7);
                short8 bv = *(const short8*)((const char*)V_s[0] + row * 128 + sg * 16);
                acc_o[n] = __builtin_amdgcn_mfma_f32_16x16x32_bf16(ap, bv, acc_o[n], 0, 0, 0);
            }
        }
    }

    float linv = 1.0f / l_q;
    float invr[4];
    #pragma unroll
    for (int i = 0; i < 4; ++i) invr[i] = __shfl(linv, g * 4 + i, 64);
    #pragma unroll
    for (int n = 0; n < 4; ++n) {
        #pragma unroll
        for (int i = 0; i < 4; ++i) {
            size_t idx = ((size_t)(b * SEQC + gq + g * 4 + i)) * DIMC + h * DHC + n * 16 + fr;
            outb[idx] = f2bf(acc_o[n][i] * invr[i]);
        }
    }
}

// ---------------- aux writeback ----------------
__global__ void aux_write_kernel(const float* __restrict__ aux, float* __restrict__ dst) {
    dst[0] = aux[0];
}

extern "C" void kernel_launch(void* const* d_in, const int* in_sizes, int n_in,
                              void* d_out, int out_size, void* d_ws, size_t ws_size,
                              hipStream_t stream) {
    const int*   tokens    = (const int*)d_in[0];
    const float* mems      = (const float*)d_in[1];
    const int*   times     = (const int*)d_in[2];
    const float* token_emb = (const float*)d_in[3];
    const float* expire_W  = (const float*)d_in[4];
    const float* expire_b  = (const float*)d_in[5];
    const float* ln1_g     = (const float*)d_in[6];
    const float* ln1_b     = (const float*)d_in[7];
    const float* Wq        = (const float*)d_in[8];
    const float* Wkv       = (const float*)d_in[9];
    const float* Wo        = (const float*)d_in[10];
    const float* bo        = (const float*)d_in[11];
    const float* ln2_g     = (const float*)d_in[12];
    const float* ln2_b     = (const float*)d_in[13];
    const float* W1        = (const float*)d_in[14];
    const float* b1        = (const float*)d_in[15];
    const float* W2        = (const float*)d_in[16];
    const float* b2        = (const float*)d_in[17];
    const float* logits_W  = (const float*)d_in[18];
    const float* logits_b  = (const float*)d_in[19];

    float* out = (float*)d_out;
    float* ws  = (float*)d_ws;

    // workspace layout (float offsets)
    float* x = ws;                                                  //  0       (2,097,152)
    unsigned short* qb_b  = (unsigned short*)(ws + 2097152);        //  1,048,576 f
    unsigned short* kv_b  = (unsigned short*)(ws + 3145728);        //  5,242,880 f (K-only)
    unsigned short* vTl   = (unsigned short*)(ws + 8388608);        //  1,048,576 f
    unsigned short* vTc   = (unsigned short*)(ws + 9437184);        //  1,048,576 f
    unsigned short* xn_b  = (unsigned short*)(ws + 10485760);       //  1,048,576 f
    unsigned short* attn_b= (unsigned short*)(ws + 11534336);       //  1,048,576 f
    unsigned short* ffn_b = (unsigned short*)(ws + 12582912);       //  4,194,304 f
    unsigned short* mem_b = (unsigned short*)(ws + 16777216);       //  4,194,304 f
    unsigned short* x_b   = (unsigned short*)(ws + 20971520);       //  1,048,576 f
    unsigned short* wq_t  = (unsigned short*)(ws + 22020096);       //    524,288 f
    unsigned short* wkv_t = (unsigned short*)(ws + 22544384);       //  1,048,576 f
    unsigned short* wo_t  = (unsigned short*)(ws + 23592960);       //    524,288 f
    unsigned short* w1_t  = (unsigned short*)(ws + 24117248);       //  2,097,152 f
    unsigned short* w2_t  = (unsigned short*)(ws + 26214400);       //  2,097,152 f
    float* exps = ws + 28311552;                                    //      8,192 f
    float* aux  = ws + 28319744;                                    //         16 f
    int*   cidx = (int*)(ws + 28319760);                            //      8,192
    float* em_c = ws + 28327952;                                    //      8,192
    int*   cnt  = (int*)(ws + 28336144);                            //          4
    // logits_W^T aliases qb_b..mem_b (all dead after last layer); ends before x_b
    unsigned short* lw_t = (unsigned short*)(ws + 2097152);         // needs 16,384,000 f

    float* out_logits = out;                // 65,536,000
    float* out_mems   = out + 65536000;     // 33,554,432
    float* out_times  = out + 99090432;     // 8,192

    embed_kernel<<<BC * SEQC, 256, 0, stream>>>(tokens, token_emb, x);
    times_init_kernel<<<32, 256, 0, stream>>>(times, out_times, aux);

    for (int d = 0; d < 4; ++d) {
        const float* mem_d = mems + (size_t)d * BC * MC * DIMC;
        prep_kernel<<<PREP_TOT, 256, 0, stream>>>(
            mem_d, x, expire_W + d * DIMC, expire_b + d, exps, aux,
            mem_b, out_mems + (size_t)d * BC * MC * DIMC,
            ln1_g + d * DIMC, ln1_b + d * DIMC, xn_b,
            Wq + (size_t)d * DIMC * DIMC, Wkv + (size_t)d * DIMC * 2 * DIMC,
            Wo + (size_t)d * DIMC * DIMC, W1 + (size_t)d * DIMC * 4 * DIMC,
            W2 + (size_t)d * 4 * DIMC * DIMC,
            wq_t, wkv_t, wo_t, w1_t, w2_t);
        compact_kernel<<<BC, 64, 0, stream>>>(exps, times + d * MC, cidx, em_c, cnt);
        qkv_gemm_kernel<<<1152, 256, 0, stream>>>(xn_b, mem_b, wq_t, wkv_t,
                                                  cidx, cnt, qb_b, kv_b, vTl, vTc);
        attn_mfma_kernel<<<512, 256, 0, stream>>>(
            qb_b, kv_b, vTl, vTc, cidx, em_c, cnt, attn_b);
        gemm64_kernel<<<dim3(8, 32), 256, 0, stream>>>(
            attn_b, wo_t, bo + d * DIMC, x, x, nullptr, DIMC);
        ln_kernel<<<BC * SEQC, 256, 0, stream>>>(x, ln2_g + d * DIMC, ln2_b + d * DIMC, xn_b);
        ffn1_kernel<<<dim3(32, 16), 256, 0, stream>>>(xn_b, w1_t, b1 + d * 4 * DIMC, ffn_b);
        if (d < 3) {
            gemm64_kernel<<<dim3(8, 32), 256, 0, stream>>>(
                ffn_b, w2_t, b2 + d * DIMC, x, x, nullptr, 4 * DIMC);
        } else {
            gemm64_kernel<<<dim3(8, 32), 256, 0, stream>>>(
                ffn_b, w2_t, b2 + d * DIMC, x, nullptr, x_b, 4 * DIMC);
        }
    }

    wt_kernel<<<dim3(1000, 32), 256, 0, stream>>>(logits_W, lw_t, DIMC, VOCABC);
    logits_kernel<<<1000, 512, 0, stream>>>(x_b, lw_t, logits_b, out_logits);
    aux_write_kernel<<<1, 1, 0, stream>>>(aux, out + 99098624);
}

// Round 17
// 1632.514 us; speedup vs baseline: 1.0655x; 1.0310x over previous
//
#include <hip/hip_runtime.h>
#include <cmath>

// Problem constants
#define DIMC   1024
#define SEQC   512
#define BC     4
#define MC     2048      // MAXMEM
#define CTXC   2560      // MC + SEQC
#define HEADSC 16
#define DHC    64
#define VOCABC 32000
#define MAXC   512       // compact-slot capacity (live keys ~64)

using short8 = __attribute__((ext_vector_type(8))) short;
using f32x4  = __attribute__((ext_vector_type(4))) float;
using u16x4  = __attribute__((ext_vector_type(4))) unsigned short;
using u16x8  = __attribute__((ext_vector_type(8))) unsigned short;

__device__ __forceinline__ unsigned short f2bf(float f) {
    unsigned u = __float_as_uint(f);
    unsigned r = (u + 0x7fffu + ((u >> 16) & 1u)) >> 16;
    return (unsigned short)r;
}

__device__ __forceinline__ void glds16(const unsigned short* g, char* l) {
    __builtin_amdgcn_global_load_lds(
        (const __attribute__((address_space(1))) void*)g,
        (__attribute__((address_space(3))) void*)l, 16, 0, 0);
}

// ---------------- embed ----------------
__global__ __launch_bounds__(256) void embed_kernel(const int* __restrict__ tokens,
                                                    const float* __restrict__ emb,
                                                    float* __restrict__ x) {
    int row = blockIdx.x;
    int tok = tokens[row];
    const float4 v = *(const float4*)(emb + (size_t)tok * DIMC + threadIdx.x * 4);
    *(float4*)(x + (size_t)row * DIMC + threadIdx.x * 4) = v;
}

// ---------------- new_times + aux zero ----------------
__global__ __launch_bounds__(256) void times_init_kernel(const int* __restrict__ times,
                                                         float* __restrict__ out_times,
                                                         float* __restrict__ aux) {
    int i = blockIdx.x * 256 + threadIdx.x;
    if (i == 0) aux[0] = 0.0f;
    if (i < 4 * MC) {
        int d = i >> 11, m = i & (MC - 1);
        out_times[i] = (m < MC - SEQC) ? (float)(times[d * MC + SEQC + m] + SEQC)
                                       : (float)(MC - 1 - m);
    }
}

// ---------------- fused per-layer prep ----------------
#define PREP_MEM 8192
#define PREP_XC  10240
#define PREP_LN  12288
#define PREP_TOT 24576
__global__ __launch_bounds__(256) void prep_kernel(
    const float* __restrict__ mem_d, const float* __restrict__ x,
    const float* __restrict__ eW, const float* __restrict__ eb,
    float* __restrict__ exps, float* __restrict__ aux,
    unsigned short* __restrict__ mem_b, float* __restrict__ out_mems_d,
    const float* __restrict__ g1, const float* __restrict__ b1v,
    unsigned short* __restrict__ xn_b,
    const float* __restrict__ Wq, const float* __restrict__ Wkv,
    const float* __restrict__ Wo, const float* __restrict__ W1,
    const float* __restrict__ W2,
    unsigned short* __restrict__ wq_t, unsigned short* __restrict__ wkv_t,
    unsigned short* __restrict__ wo_t, unsigned short* __restrict__ w1_t,
    unsigned short* __restrict__ w2_t) {
    __shared__ float sh[1056];
    const int bid = blockIdx.x, tid = threadIdx.x;
    if (bid < PREP_MEM) {
        int row = bid;                       // b*2048 + m
        int m = row & 2047, b = row >> 11;
        const float4 v = *(const float4*)(mem_d + (size_t)row * DIMC + tid * 4);
        const float4 w = *(const float4*)(eW + tid * 4);
        float s = v.x * w.x + v.y * w.y + v.z * w.z + v.w * w.w;
        for (int off = 32; off; off >>= 1) s += __shfl_down(s, off, 64);
        int wid = tid >> 6, lane = tid & 63;
        if (lane == 0) sh[wid] = s;
        u16x4 o = { f2bf(v.x), f2bf(v.y), f2bf(v.z), f2bf(v.w) };
        *(u16x4*)(mem_b + (size_t)row * DIMC + tid * 4) = o;
        if (m >= SEQC)
            *(float4*)(out_mems_d + ((size_t)(b * MC + m - SEQC)) * DIMC + tid * 4) = v;
        __syncthreads();
        if (tid == 0) {
            float z = sh[0] + sh[1] + sh[2] + sh[3] + eb[0];
            float e = (float)MC / (1.0f + expf(-z));
            exps[row] = e;
            atomicAdd(aux, e * (1e-6f / (float)SEQC));
        }
    } else if (bid < PREP_XC) {
        int r = bid - PREP_MEM;              // b*512 + i
        int b = r >> 9, i = r & 511;
        const float4 v = *(const float4*)(x + (size_t)r * DIMC + tid * 4);
        *(float4*)(out_mems_d + ((size_t)(b * MC + MC - SEQC + i)) * DIMC + tid * 4) = v;
    } else if (bid < PREP_LN) {
        int row = bid - PREP_XC;
        const float4 v = *(const float4*)(x + (size_t)row * DIMC + tid * 4);
        float s = v.x + v.y + v.z + v.w;
        float q = v.x * v.x + v.y * v.y + v.z * v.z + v.w * v.w;
        for (int off = 32; off; off >>= 1) {
            s += __shfl_down(s, off, 64);
            q += __shfl_down(q, off, 64);
        }
        int wid = tid >> 6, lane = tid & 63;
        if (lane == 0) { sh[wid] = s; sh[4 + wid] = q; }
        __syncthreads();
        if (tid == 0) {
            float S = sh[0] + sh[1] + sh[2] + sh[3];
            float Q = sh[4] + sh[5] + sh[6] + sh[7];
            float mu = S / DIMC;
            float var = Q / DIMC - mu * mu;
            sh[8] = mu;
            sh[9] = rsqrtf(var + 1e-5f);
        }
        __syncthreads();
        float mu = sh[8], rstd = sh[9];
        const float4 gg = *(const float4*)(g1 + tid * 4);
        const float4 bb = *(const float4*)(b1v + tid * 4);
        u16x4 o = { f2bf((v.x - mu) * rstd * gg.x + bb.x),
                    f2bf((v.y - mu) * rstd * gg.y + bb.y),
                    f2bf((v.z - mu) * rstd * gg.z + bb.z),
                    f2bf((v.w - mu) * rstd * gg.w + bb.w) };
        *(u16x4*)(xn_b + (size_t)row * DIMC + tid * 4) = o;
    } else {
        int t = bid - PREP_LN;
        const float* W; unsigned short* Wt; int K, N, tx, ty;
        if (t < 1024)      { W = Wq;  Wt = wq_t;  K = 1024; N = 1024; tx = t & 31;  ty = t >> 5; }
        else if (t < 3072) { int u = t - 1024; W = Wkv; Wt = wkv_t; K = 1024; N = 2048; tx = u & 63;  ty = u >> 6; }
        else if (t < 4096) { int u = t - 3072; W = Wo;  Wt = wo_t;  K = 1024; N = 1024; tx = u & 31;  ty = u >> 5; }
        else if (t < 8192) { int u = t - 4096; W = W1;  Wt = w1_t;  K = 1024; N = 4096; tx = u & 127; ty = u >> 7; }
        else               { int u = t - 8192; W = W2;  Wt = w2_t;  K = 4096; N = 1024; tx = u & 31;  ty = u >> 5; }
        int n0 = tx * 32, k0 = ty * 32;
        int r = tid >> 3, c = (tid & 7) * 4;
        const float4 v = *(const float4*)(W + (size_t)(k0 + r) * N + n0 + c);
        sh[r * 33 + c] = v.x; sh[r * 33 + c + 1] = v.y;
        sh[r * 33 + c + 2] = v.z; sh[r * 33 + c + 3] = v.w;
        __syncthreads();
        u16x4 o = { f2bf(sh[(c + 0) * 33 + r]), f2bf(sh[(c + 1) * 33 + r]),
                    f2bf(sh[(c + 2) * 33 + r]), f2bf(sh[(c + 3) * 33 + r]) };
        *(u16x4*)(Wt + (size_t)(n0 + r) * K + k0 + c) = o;
    }
}

// ---------------- compact live memory keys (deterministic ballot scan) ----------------
__global__ __launch_bounds__(64) void compact_kernel(
    const float* __restrict__ exps, const int* __restrict__ times_d,
    int* __restrict__ cidx, float* __restrict__ em_c, int* __restrict__ cnt) {
    int b = blockIdx.x, lane = threadIdx.x;
    int c = 0;
    for (int it = 0; it < 32; ++it) {
        int j = it * 64 + lane;
        float e = exps[b * MC + j];
        float rr = (e - (float)times_d[j]) * (1.0f / 128.0f) + 1.0f;
        float em = fminf(fmaxf(rr, 0.0f), 1.0f);
        unsigned long long mk = __ballot(em > 0.0f);
        int pos = c + __popcll(mk & ((1ull << lane) - 1ull));
        if (em > 0.0f) {
            cidx[b * 2048 + pos] = j;
            em_c[b * 2048 + pos] = em;
        }
        c += __popcll(mk);
    }
    int padded = (c + 63) & ~63;
    int fill_to = padded < MAXC ? MAXC : padded;
    for (int p = c + lane; p < fill_to; p += 64) {
        cidx[b * 2048 + p] = 0;     // valid row; em=0 kills contribution
        em_c[b * 2048 + p] = 0.0f;
    }
    int tiles = padded >> 6;
    if (tiles > (MAXC >> 6)) tiles = MAXC >> 6;
    if (lane == 0) cnt[b] = tiles;
}

// ---------------- LayerNorm (fp32 in, bf16 out) — LN2 ----------------
__global__ __launch_bounds__(256) void ln_kernel(const float* __restrict__ in,
                                                 const float* __restrict__ g,
                                                 const float* __restrict__ b,
                                                 unsigned short* __restrict__ outb) {
    int row = blockIdx.x;
    int tid = threadIdx.x;
    const float4 v = *(const float4*)(in + (size_t)row * DIMC + tid * 4);
    float s = v.x + v.y + v.z + v.w;
    float q = v.x * v.x + v.y * v.y + v.z * v.z + v.w * v.w;
    for (int off = 32; off; off >>= 1) {
        s += __shfl_down(s, off, 64);
        q += __shfl_down(q, off, 64);
    }
    __shared__ float ss[4], sq[4];
    int wid = tid >> 6, lane = tid & 63;
    if (lane == 0) { ss[wid] = s; sq[wid] = q; }
    __syncthreads();
    if (tid == 0) {
        float S = ss[0] + ss[1] + ss[2] + ss[3];
        float Q = sq[0] + sq[1] + sq[2] + sq[3];
        float mu = S / DIMC;
        float var = Q / DIMC - mu * mu;
        ss[0] = mu;
        sq[0] = rsqrtf(var + 1e-5f);
    }
    __syncthreads();
    float mu = ss[0], rstd = sq[0];
    const float4 gg = *(const float4*)(g + tid * 4);
    const float4 bb = *(const float4*)(b + tid * 4);
    u16x4 o = { f2bf((v.x - mu) * rstd * gg.x + bb.x),
                f2bf((v.y - mu) * rstd * gg.y + bb.y),
                f2bf((v.z - mu) * rstd * gg.z + bb.z),
                f2bf((v.w - mu) * rstd * gg.w + bb.w) };
    *(u16x4*)(outb + (size_t)row * DIMC + tid * 4) = o;
}

// ---------------- weight convert + transpose (logits_W only) ----------------
__global__ __launch_bounds__(256) void wt_kernel(const float* __restrict__ W,
                                                 unsigned short* __restrict__ Wt,
                                                 int K, int N) {
    __shared__ float t[32][33];
    int tid = threadIdx.x;
    int n0 = blockIdx.x * 32, k0 = blockIdx.y * 32;
    int r = tid >> 3, c = (tid & 7) * 4;
    const float4 v = *(const float4*)(W + (size_t)(k0 + r) * N + n0 + c);
    t[r][c] = v.x; t[r][c + 1] = v.y; t[r][c + 2] = v.z; t[r][c + 3] = v.w;
    __syncthreads();
    u16x4 o = { f2bf(t[c + 0][r]), f2bf(t[c + 1][r]),
                f2bf(t[c + 2][r]), f2bf(t[c + 3][r]) };
    *(u16x4*)(Wt + (size_t)(n0 + r) * K + k0 + c) = o;
}

// ---------------- bf16 MFMA GEMM body — depth-1 counted-vmcnt pipeline + T2 bank swizzle ----------------
template<int AMODE, bool BIAS, bool GELU, bool RES, int OMODE, int RT>
__device__ __forceinline__ void gemm_body(
    unsigned short* As, unsigned short* Bs,
    const unsigned short* __restrict__ A, const int* __restrict__ gidx,
    const unsigned short* __restrict__ Wt, const float* __restrict__ bias,
    const float* __restrict__ res, float* __restrict__ Cf,
    unsigned short* __restrict__ Cb, int K, int N, int bx, int by) {
    constexpr int MF = RT / 32;
    const int tid = threadIdx.x;
    const int lane = tid & 63, wave = tid >> 6;
    const int row0 = by * RT, col0 = bx * 128;

    const int seg = tid & 3;
    const int rr0 = tid >> 2;
    const int sseg8 = (seg ^ ((rr0 >> 1) & 3)) * 8;   // source pre-swizzle (elements)
    const unsigned short* arow[RT / 64];
    #pragma unroll
    for (int p = 0; p < RT / 64; ++p) {
        int r = row0 + p * 64 + rr0;
        if (AMODE == 2) {
            int b = r >> 9, slot = r & (MAXC - 1);
            arow[p] = A + ((size_t)(b * 2048 + gidx[b * 2048 + slot])) * K;
        } else {
            arow[p] = A + (size_t)r * K;
        }
        arow[p] += sseg8;
    }
    const unsigned short* brow[2];
    #pragma unroll
    for (int p = 0; p < 2; ++p)
        brow[p] = Wt + (size_t)(col0 + p * 64 + rr0) * K + sseg8;

    char* lA = (char*)As + (tid & 192) * 16;
    char* lB = (char*)Bs + (tid & 192) * 16;

    auto stage = [&](int k0, int q) {
        char* a = lA + q * (RT * 64);
        glds16(arow[0] + k0, a);
        if (RT == 128) glds16(arow[1] + k0, a + 4096);
        char* bp = lB + q * 8192;
        glds16(brow[0] + k0, bp);
        glds16(brow[1] + k0, bp + 4096);
    };

    f32x4 acc[MF][4] = {};

    const int wr = (wave >> 1) * (RT / 2), wc = (wave & 1) * 64;
    const int fr = lane & 15;
    const int g4 = lane >> 4;
    const int kA8 = (g4 ^ (((wr + fr) >> 1) & 3)) * 8;   // swizzled read slot (elements)
    const int kB8 = (g4 ^ (((wc + fr) >> 1) & 3)) * 8;

    stage(0, 0);
    int cur = 0;
    for (int k0 = 0; k0 < K; k0 += 32) {
        if (k0 + 32 < K) {
            stage(k0 + 32, cur ^ 1);
            if (RT == 128) asm volatile("s_waitcnt vmcnt(4)" ::: "memory");
            else           asm volatile("s_waitcnt vmcnt(3)" ::: "memory");
        } else {
            asm volatile("s_waitcnt vmcnt(0)" ::: "memory");
        }
        __builtin_amdgcn_s_barrier();
        __builtin_amdgcn_sched_barrier(0);
        const unsigned short* Ar = As + cur * (RT * 32) + (size_t)(wr + fr) * 32 + kA8;
        const unsigned short* Br = Bs + cur * (128 * 32) + (size_t)(wc + fr) * 32 + kB8;
        short8 a[MF], b[4];
        #pragma unroll
        for (int m = 0; m < MF; ++m) a[m] = *(const short8*)(Ar + m * 16 * 32);
        #pragma unroll
        for (int n = 0; n < 4; ++n) b[n] = *(const short8*)(Br + n * 16 * 32);
        #pragma unroll
        for (int m = 0; m < MF; ++m)
            #pragma unroll
            for (int n = 0; n < 4; ++n)
                acc[m][n] = __builtin_amdgcn_mfma_f32_16x16x32_bf16(a[m], b[n], acc[m][n], 0, 0, 0);
        __builtin_amdgcn_s_barrier();
        cur ^= 1;
    }

    const int orow = row0 + wr + (lane >> 4) * 4;
    const int ocol = col0 + wc + fr;
    if (OMODE >= 3) {
        #pragma unroll
        for (int n = 0; n < 4; ++n) {
            int c = ocol + n * 16;
            #pragma unroll
            for (int m = 0; m < MF; ++m) {
                int r0 = orow + m * 16;
                int b = r0 >> 9, i = r0 & 511;
                size_t addr = (OMODE == 3)
                    ? ((size_t)(b * 1024 + c)) * 512 + i
                    : ((size_t)(b * 1024 + c)) * MAXC + i;
                u16x4 o = { f2bf(acc[m][n][0]), f2bf(acc[m][n][1]),
                            f2bf(acc[m][n][2]), f2bf(acc[m][n][3]) };
                *(u16x4*)(Cb + addr) = o;
            }
        }
        return;
    }
    #pragma unroll
    for (int n = 0; n < 4; ++n) {
        int c = ocol + n * 16;
        float bv = BIAS ? bias[c] : 0.0f;
        #pragma unroll
        for (int m = 0; m < MF; ++m) {
            #pragma unroll
            for (int i = 0; i < 4; ++i) {
                int r0 = orow + m * 16 + i;
                size_t orr = r0;
                if (OMODE == 1) orr = (size_t)r0 + (size_t)(r0 >> 11) * 512;
                if (OMODE == 2) orr = (size_t)r0 + (size_t)(r0 >> 9) * 2048 + 2048;
                size_t idx = orr * N + c;
                float v = acc[m][n][i] + bv;
                if (GELU) v = 0.5f * v * (1.0f + erff(v * 0.70710678118f));
                if (RES) v += res[idx];
                if (Cf) Cf[idx] = v;
                if (Cb) Cb[idx] = f2bf(v);
            }
        }
    }
}

// Fused: Q(128) + local-K(128) + mem-K(512) + local-V transposed(128) + compact-V transposed(256)
__global__ __launch_bounds__(256) void qkv_gemm_kernel(
    const unsigned short* __restrict__ xn_b, const unsigned short* __restrict__ mem_b,
    const unsigned short* __restrict__ wq_t, const unsigned short* __restrict__ wkv_t,
    const int* __restrict__ cidx, const int* __restrict__ cnt,
    unsigned short* __restrict__ qb, unsigned short* __restrict__ kvb,
    unsigned short* __restrict__ vTl, unsigned short* __restrict__ vTc) {
    __shared__ unsigned short As[2 * 128 * 32];
    __shared__ unsigned short Bs[2 * 128 * 32];
    int id = blockIdx.x;
    if (id < 128) {
        gemm_body<0, false, false, false, 0, 128>(As, Bs, xn_b, nullptr, wq_t,
            nullptr, nullptr, nullptr, qb, 1024, 1024, id & 7, id >> 3);
    } else if (id < 256) {
        id -= 128;  // local rows -> ctx rows, K half of wkv
        gemm_body<0, false, false, false, 2, 128>(As, Bs, xn_b, nullptr, wkv_t,
            nullptr, nullptr, nullptr, kvb, 1024, 1024, id & 7, id >> 3);
    } else if (id < 768) {
        id -= 256;  // mem rows -> ctx rows, K half of wkv
        gemm_body<0, false, false, false, 1, 128>(As, Bs, mem_b, nullptr, wkv_t,
            nullptr, nullptr, nullptr, kvb, 1024, 1024, id & 7, id >> 3);
    } else if (id < 896) {
        id -= 768;  // local V -> vTl transposed
        gemm_body<0, false, false, false, 3, 128>(As, Bs, xn_b, nullptr,
            wkv_t + (size_t)1024 * 1024, nullptr, nullptr, nullptr, vTl,
            1024, 1024, id & 7, id >> 3);
    } else {
        id -= 896;  // compact V: gather mem rows by cidx -> vTc transposed
        int by = id >> 3;
        int b = (by * 64) >> 9, slot0 = (by * 64) & (MAXC - 1);
        if (slot0 >= cnt[b] * 64) return;
        gemm_body<2, false, false, false, 4, 64>(As, Bs, mem_b, cidx,
            wkv_t + (size_t)1024 * 1024, nullptr, nullptr, nullptr, vTc,
            1024, 1024, id & 7, by);
    }
}

// RT=64 GEMM with bias+residual, N=1024 (Wo and FFN2)
__global__ __launch_bounds__(256) void gemm64_kernel(
    const unsigned short* __restrict__ A, const unsigned short* __restrict__ Wt,
    const float* __restrict__ bias, const float* __restrict__ res,
    float* __restrict__ Cf, unsigned short* __restrict__ Cb, int K) {
    __shared__ unsigned short As[2 * 64 * 32];
    __shared__ unsigned short Bs[2 * 128 * 32];
    gemm_body<0, true, false, true, 0, 64>(As, Bs, A, nullptr, Wt, bias, res,
        Cf, Cb, K, 1024, blockIdx.x, blockIdx.y);
}

// FFN1: gelu, bf16 out
__global__ __launch_bounds__(256) void ffn1_kernel(
    const unsigned short* __restrict__ A, const unsigned short* __restrict__ Wt,
    const float* __restrict__ bias, unsigned short* __restrict__ Cb) {
    __shared__ unsigned short As[2 * 128 * 32];
    __shared__ unsigned short Bs[2 * 128 * 32];
    gemm_body<0, true, true, false, 0, 128>(As, Bs, A, nullptr, Wt, bias, nullptr,
        nullptr, Cb, 1024, 4096, blockIdx.x, blockIdx.y);
}

// ---------------- logits: 256x256 tile, 512 threads, 8 waves (2x4), counted-vmcnt + T2 swizzle ----------------
__global__ __launch_bounds__(512, 2) void logits_kernel(
    const unsigned short* __restrict__ A, const unsigned short* __restrict__ Wt,
    const float* __restrict__ bias, float* __restrict__ Cf) {
    __shared__ unsigned short As[2 * 256 * 32];
    __shared__ unsigned short Bs[2 * 256 * 32];
    const int L = blockIdx.x;
    const int wid = (L & 7) * 125 + (L >> 3);
    const int ct = wid / 8, rt = wid & 7;
    const int row0 = rt * 256, col0 = ct * 256;
    const int tid = threadIdx.x;
    const int lane = tid & 63, wave = tid >> 6;

    const int seg = tid & 3;
    const int rr0 = tid >> 2;                 // 0..127
    const int sseg8 = (seg ^ ((rr0 >> 1) & 3)) * 8;   // source pre-swizzle
    const unsigned short* arow[2];
    const unsigned short* brow[2];
    #pragma unroll
    for (int p = 0; p < 2; ++p) {
        arow[p] = A + (size_t)(row0 + p * 128 + rr0) * 1024 + sseg8;
        brow[p] = Wt + (size_t)(col0 + p * 128 + rr0) * 1024 + sseg8;
    }
    char* lA = (char*)As + (tid & 448) * 16;  // wave-uniform base (8 waves)
    char* lB = (char*)Bs + (tid & 448) * 16;

    auto stage = [&](int k0, int q) {
        char* a = lA + q * 16384;
        char* bp = lB + q * 16384;
        glds16(arow[0] + k0, a);
        glds16(arow[1] + k0, a + 8192);
        glds16(brow[0] + k0, bp);
        glds16(brow[1] + k0, bp + 8192);
    };

    f32x4 acc[8][4] = {};
    const int wr = (wave >> 2) * 128, wc = (wave & 3) * 64;
    const int fr = lane & 15;
    const int g4 = lane >> 4;
    const int kA8 = (g4 ^ (((wr + fr) >> 1) & 3)) * 8;
    const int kB8 = (g4 ^ (((wc + fr) >> 1) & 3)) * 8;

    stage(0, 0);
    int cur = 0;
    for (int k0 = 0; k0 < 1024; k0 += 32) {
        if (k0 + 32 < 1024) {
            stage(k0 + 32, cur ^ 1);
            asm volatile("s_waitcnt vmcnt(4)" ::: "memory");
        } else {
            asm volatile("s_waitcnt vmcnt(0)" ::: "memory");
        }
        __builtin_amdgcn_s_barrier();
        __builtin_amdgcn_sched_barrier(0);
        const unsigned short* Ar = As + cur * 8192 + (size_t)(wr + fr) * 32 + kA8;
        const unsigned short* Br = Bs + cur * 8192 + (size_t)(wc + fr) * 32 + kB8;
        short8 a[8], b[4];
        #pragma unroll
        for (int m = 0; m < 8; ++m) a[m] = *(const short8*)(Ar + m * 16 * 32);
        #pragma unroll
        for (int n = 0; n < 4; ++n) b[n] = *(const short8*)(Br + n * 16 * 32);
        #pragma unroll
        for (int m = 0; m < 8; ++m)
            #pragma unroll
            for (int n = 0; n < 4; ++n)
                acc[m][n] = __builtin_amdgcn_mfma_f32_16x16x32_bf16(a[m], b[n], acc[m][n], 0, 0, 0);
        __builtin_amdgcn_s_barrier();
        cur ^= 1;
    }

    const int orow = row0 + wr + (lane >> 4) * 4;
    const int ocol = col0 + wc + fr;
    #pragma unroll
    for (int n = 0; n < 4; ++n) {
        int c = ocol + n * 16;
        float bv = bias[c];
        #pragma unroll
        for (int m = 0; m < 8; ++m) {
            #pragma unroll
            for (int i = 0; i < 4; ++i)
                Cf[(size_t)(orow + m * 16 + i) * VOCABC + c] = acc[m][n][i] + bv;
        }
    }
}

// ---------------- 3-phase MFMA flash attention — 128-wide mem double-tiles ----------------
// grid = 512 (8 qt x 16 h x 4 b), XCD-grouped; counted-vmcnt raw-barrier pipelines.
// Phase 1: 16 double-tiles of 128 mem keys (denominator only) — half the barrier pairs,
// one combined 32-value max/exp2/sum per iteration. Phase 2: 64-wide causal local tiles
// with V. Phase 3: compact live-mem tiles. Softmax in base-2 (CSC = 0.125*log2 e).
#define CSC 0.18033688011112042f
__global__ __launch_bounds__(256) void attn_mfma_kernel(
    const unsigned short* __restrict__ qb,
    const unsigned short* __restrict__ kvb,   // K-only [b][2560][1024]
    const unsigned short* __restrict__ vTl,   // [b*1024+d][512] local V transposed
    const unsigned short* __restrict__ vTc,   // [b*1024+d][MAXC] compact V transposed
    const int* __restrict__ cidx,
    const float* __restrict__ em_c,
    const int* __restrict__ cnt,
    unsigned short* __restrict__ outb) {
    __shared__ unsigned short K_s[2][128 * 64];
    __shared__ unsigned short V_s[2][64 * 64];
    __shared__ unsigned short p_s[4][16][72];
    __shared__ float em_s[64];
    const int tid = threadIdx.x;
    const int lane = tid & 63, wave = tid >> 6;
    const int L = blockIdx.x;
    const int ix = L >> 3;
    const int qt = ix & 7;
    const int gidx = (L & 7) * 8 + (ix >> 3);   // same (h,b) group on same XCD
    const int h = gidx & 15, b = gidx >> 4;
    const int fr = lane & 15, g = lane >> 4;
    const int gq = qt * 64 + wave * 16;

    short8 aq[2];
    {
        const unsigned short* qp = qb + ((size_t)(b * SEQC + gq + fr)) * DIMC + h * DHC + g * 8;
        aq[0] = *(const short8*)qp;
        aq[1] = *(const short8*)(qp + 32);
    }

    const int sr = tid >> 3, ss = tid & 7;       // sr in [0,32)
    const int sw = (ss ^ (sr & 7)) * 8;          // source pre-swizzle (p*32 keeps r&7)
    const int wbase = (tid & 192) * 16;          // wave-uniform LDS byte base (4 waves)

    f32x4 acc_o[4] = {};
    float m_q = -1e30f, l_q = 0.0f;              // log2 domain

    // ---- phase 1: 16 double-tiles of 128 mem keys, denominator only ----
    auto stageM = [&](int t, int q) {
        const int jbase = t * 128;
        #pragma unroll
        for (int p = 0; p < 4; ++p) {
            int r = sr + p * 32;
            glds16(kvb + ((size_t)(b * CTXC + jbase + r)) * 1024 + h * DHC + sw,
                   (char*)K_s[q] + wbase + p * 4096);
        }
    };

    stageM(0, 0);
    asm volatile("s_waitcnt vmcnt(0)" ::: "memory");
    __builtin_amdgcn_s_barrier();
    int cur = 0;
    for (int t = 0; t < 16; ++t) {
        if (t + 1 < 16) {
            stageM(t + 1, cur ^ 1);
            asm volatile("s_waitcnt vmcnt(4)" ::: "memory");
        } else {
            asm volatile("s_waitcnt vmcnt(0)" ::: "memory");
        }
        __builtin_amdgcn_s_barrier();
        __builtin_amdgcn_sched_barrier(0);

        f32x4 sT[2][4] = {};
        #pragma unroll
        for (int c = 0; c < 2; ++c)
            #pragma unroll
            for (int ks = 0; ks < 2; ++ks)
                #pragma unroll
                for (int mf = 0; mf < 4; ++mf) {
                    int row = c * 64 + mf * 16 + fr, sg = (ks * 4 + g) ^ (row & 7);
                    short8 kk = *(const short8*)((const char*)K_s[cur] + row * 128 + sg * 16);
                    sT[c][mf] = __builtin_amdgcn_mfma_f32_16x16x32_bf16(kk, aq[ks], sT[c][mf], 0, 0, 0);
                }

        float mx = sT[0][0][0];
        #pragma unroll
        for (int c = 0; c < 2; ++c)
            #pragma unroll
            for (int mf = 0; mf < 4; ++mf)
                #pragma unroll
                for (int i = 0; i < 4; ++i) mx = fmaxf(mx, sT[c][mf][i]);
        mx *= CSC;
        mx = fmaxf(mx, __shfl_xor(mx, 16, 64));
        mx = fmaxf(mx, __shfl_xor(mx, 32, 64));
        float mnew = fmaxf(m_q, mx);
        float fs = __builtin_amdgcn_exp2f(m_q - mnew);
        m_q = mnew;
        float ps = 0.0f;
        #pragma unroll
        for (int c = 0; c < 2; ++c)
            #pragma unroll
            for (int mf = 0; mf < 4; ++mf)
                #pragma unroll
                for (int i = 0; i < 4; ++i)
                    ps += __builtin_amdgcn_exp2f(sT[c][mf][i] * CSC - mnew);
        ps += __shfl_xor(ps, 16, 64);
        ps += __shfl_xor(ps, 32, 64);
        l_q = l_q * fs + ps;

        __builtin_amdgcn_s_barrier();
        cur ^= 1;
    }

    // ---- phase 2: local causal tiles (64-wide, with V) ----
    auto stageL = [&](int lt, int q) {
        const int jbase = MC + lt * 64;
        #pragma unroll
        for (int p = 0; p < 2; ++p) {
            int r = sr + p * 32;
            glds16(kvb + ((size_t)(b * CTXC + jbase + r)) * 1024 + h * DHC + sw,
                   (char*)K_s[q] + wbase + p * 4096);
            glds16(vTl + ((size_t)(b * 1024 + h * DHC + r)) * 512 + lt * 64 + sw,
                   (char*)V_s[q] + wbase + p * 4096);
        }
    };

    const int nlt = qt + 1;
    stageL(0, 0);
    asm volatile("s_waitcnt vmcnt(0)" ::: "memory");
    __builtin_amdgcn_s_barrier();
    cur = 0;
    for (int lt = 0; lt < nlt; ++lt) {
        if (lt + 1 < nlt) {
            stageL(lt + 1, cur ^ 1);
            asm volatile("s_waitcnt vmcnt(4)" ::: "memory");
        } else {
            asm volatile("s_waitcnt vmcnt(0)" ::: "memory");
        }
        __builtin_amdgcn_s_barrier();
        __builtin_amdgcn_sched_barrier(0);

        f32x4 sT[4] = {};
        #pragma unroll
        for (int ks = 0; ks < 2; ++ks)
            #pragma unroll
            for (int mf = 0; mf < 4; ++mf) {
                int row = mf * 16 + fr, sg = (ks * 4 + g) ^ (row & 7);
                short8 kk = *(const short8*)((const char*)K_s[cur] + row * 128 + sg * 16);
                sT[mf] = __builtin_amdgcn_mfma_f32_16x16x32_bf16(kk, aq[ks], sT[mf], 0, 0, 0);
            }

        const int kq = gq + fr - lt * 64;
        float sv[4][4];
        #pragma unroll
        for (int mf = 0; mf < 4; ++mf)
            #pragma unroll
            for (int i = 0; i < 4; ++i) {
                int kl = mf * 16 + g * 4 + i;
                sv[mf][i] = (kl <= kq) ? sT[mf][i] * CSC : -1e30f;
            }
        float mx = sv[0][0];
        #pragma unroll
        for (int mf = 0; mf < 4; ++mf)
            #pragma unroll
            for (int i = 0; i < 4; ++i) mx = fmaxf(mx, sv[mf][i]);
        mx = fmaxf(mx, __shfl_xor(mx, 16, 64));
        mx = fmaxf(mx, __shfl_xor(mx, 32, 64));
        float mnew = fmaxf(m_q, mx);
        float fs = __builtin_amdgcn_exp2f(m_q - mnew);
        m_q = mnew;
        float ps = 0.0f;
        #pragma unroll
        for (int mf = 0; mf < 4; ++mf)
            #pragma unroll
            for (int i = 0; i < 4; ++i) {
                float pe = __builtin_amdgcn_exp2f(sv[mf][i] - mnew);
                ps += pe;
                p_s[wave][fr][mf * 16 + g * 4 + i] = f2bf(pe);
            }
        ps += __shfl_xor(ps, 16, 64);
        ps += __shfl_xor(ps, 32, 64);
        l_q = l_q * fs + ps;
        float fsr[4];
        #pragma unroll
        for (int i = 0; i < 4; ++i) fsr[i] = __shfl(fs, g * 4 + i, 64);
        #pragma unroll
        for (int n = 0; n < 4; ++n)
            #pragma unroll
            for (int i = 0; i < 4; ++i) acc_o[n][i] *= fsr[i];
        asm volatile("s_waitcnt lgkmcnt(0)" ::: "memory");
        #pragma unroll
        for (int ks = 0; ks < 2; ++ks) {
            short8 ap = *(const short8*)&p_s[wave][fr][ks * 32 + g * 8];
            #pragma unroll
            for (int n = 0; n < 4; ++n) {
                int row = n * 16 + fr, sg = (ks * 4 + g) ^ (row & 7);
                short8 bv = *(const short8*)((const char*)V_s[cur] + row * 128 + sg * 16);
                acc_o[n] = __builtin_amdgcn_mfma_f32_16x16x32_bf16(ap, bv, acc_o[n], 0, 0, 0);
            }
        }
        __builtin_amdgcn_s_barrier();
        cur ^= 1;
    }

    // ---- phase 3: compact live-mem tiles (final m,l; no m/l update) ----
    const int nct = cnt[b];
    for (int ct = 0; ct < nct; ++ct) {
        __syncthreads();
        #pragma unroll
        for (int p = 0; p < 2; ++p) {
            int r = sr + p * 32;
            int row = cidx[b * 2048 + ct * 64 + r];
            glds16(kvb + ((size_t)(b * CTXC + row)) * 1024 + h * DHC + sw,
                   (char*)K_s[0] + wbase + p * 4096);
            glds16(vTc + ((size_t)(b * 1024 + h * DHC + r)) * MAXC + ct * 64 + sw,
                   (char*)V_s[0] + wbase + p * 4096);
        }
        if (tid < 64) em_s[tid] = em_c[b * 2048 + ct * 64 + tid];
        __syncthreads();
        f32x4 sT[4] = {};
        #pragma unroll
        for (int ks = 0; ks < 2; ++ks)
            #pragma unroll
            for (int mf = 0; mf < 4; ++mf) {
                int row = mf * 16 + fr, sg = (ks * 4 + g) ^ (row & 7);
                short8 kk = *(const short8*)((const char*)K_s[0] + row * 128 + sg * 16);
                sT[mf] = __builtin_amdgcn_mfma_f32_16x16x32_bf16(kk, aq[ks], sT[mf], 0, 0, 0);
            }
        #pragma unroll
        for (int mf = 0; mf < 4; ++mf)
            #pragma unroll
            for (int i = 0; i < 4; ++i) {
                int key = mf * 16 + g * 4 + i;
                float pe = __builtin_amdgcn_exp2f(sT[mf][i] * CSC - m_q) * em_s[key];
                p_s[wave][fr][key] = f2bf(pe);
            }
        asm volatile("s_waitcnt lgkmcnt(0)" ::: "memory");
        #pragma unroll
        for (int ks = 0; ks < 2; ++ks) {
            short8 ap = *(const short8*)&p_s[wave][fr][ks * 32 + g * 8];
            #pragma unroll
            for (int n = 0; n < 4; ++n) {
                int row = n * 16 + fr, sg = (ks * 4 + g) ^ (row & 7);
                short8 bv = *(const short8*)((const char*)V_s[0] + row * 128 + sg * 16);
                acc_o[n] = __builtin_amdgcn_mfma_f32_16x16x32_bf16(ap, bv, acc_o[n], 0, 0, 0);
            }
        }
    }

    float linv = 1.0f / l_q;
    float invr[4];
    #pragma unroll
    for (int i = 0; i < 4; ++i) invr[i] = __shfl(linv, g * 4 + i, 64);
    #pragma unroll
    for (int n = 0; n < 4; ++n) {
        #pragma unroll
        for (int i = 0; i < 4; ++i) {
            size_t idx = ((size_t)(b * SEQC + gq + g * 4 + i)) * DIMC + h * DHC + n * 16 + fr;
            outb[idx] = f2bf(acc_o[n][i] * invr[i]);
        }
    }
}

// ---------------- aux writeback ----------------
__global__ void aux_write_kernel(const float* __restrict__ aux, float* __restrict__ dst) {
    dst[0] = aux[0];
}

extern "C" void kernel_launch(void* const* d_in, const int* in_sizes, int n_in,
                              void* d_out, int out_size, void* d_ws, size_t ws_size,
                              hipStream_t stream) {
    const int*   tokens    = (const int*)d_in[0];
    const float* mems      = (const float*)d_in[1];
    const int*   times     = (const int*)d_in[2];
    const float* token_emb = (const float*)d_in[3];
    const float* expire_W  = (const float*)d_in[4];
    const float* expire_b  = (const float*)d_in[5];
    const float* ln1_g     = (const float*)d_in[6];
    const float* ln1_b     = (const float*)d_in[7];
    const float* Wq        = (const float*)d_in[8];
    const float* Wkv       = (const float*)d_in[9];
    const float* Wo        = (const float*)d_in[10];
    const float* bo        = (const float*)d_in[11];
    const float* ln2_g     = (const float*)d_in[12];
    const float* ln2_b     = (const float*)d_in[13];
    const float* W1        = (const float*)d_in[14];
    const float* b1        = (const float*)d_in[15];
    const float* W2        = (const float*)d_in[16];
    const float* b2        = (const float*)d_in[17];
    const float* logits_W  = (const float*)d_in[18];
    const float* logits_b  = (const float*)d_in[19];

    float* out = (float*)d_out;
    float* ws  = (float*)d_ws;

    // workspace layout (float offsets)
    float* x = ws;                                                  //  0       (2,097,152)
    unsigned short* qb_b  = (unsigned short*)(ws + 2097152);        //  1,048,576 f
    unsigned short* kv_b  = (unsigned short*)(ws + 3145728);        //  5,242,880 f (K-only)
    unsigned short* vTl   = (unsigned short*)(ws + 8388608);        //  1,048,576 f
    unsigned short* vTc   = (unsigned short*)(ws + 9437184);        //  1,048,576 f
    unsigned short* xn_b  = (unsigned short*)(ws + 10485760);       //  1,048,576 f
    unsigned short* attn_b= (unsigned short*)(ws + 11534336);       //  1,048,576 f
    unsigned short* ffn_b = (unsigned short*)(ws + 12582912);       //  4,194,304 f
    unsigned short* mem_b = (unsigned short*)(ws + 16777216);       //  4,194,304 f
    unsigned short* x_b   = (unsigned short*)(ws + 20971520);       //  1,048,576 f
    unsigned short* wq_t  = (unsigned short*)(ws + 22020096);       //    524,288 f
    unsigned short* wkv_t = (unsigned short*)(ws + 22544384);       //  1,048,576 f
    unsigned short* wo_t  = (unsigned short*)(ws + 23592960);       //    524,288 f
    unsigned short* w1_t  = (unsigned short*)(ws + 24117248);       //  2,097,152 f
    unsigned short* w2_t  = (unsigned short*)(ws + 26214400);       //  2,097,152 f
    float* exps = ws + 28311552;                                    //      8,192 f
    float* aux  = ws + 28319744;                                    //         16 f
    int*   cidx = (int*)(ws + 28319760);                            //      8,192
    float* em_c = ws + 28327952;                                    //      8,192
    int*   cnt  = (int*)(ws + 28336144);                            //          4
    // logits_W^T aliases qb_b..mem_b (all dead after last layer); ends before x_b
    unsigned short* lw_t = (unsigned short*)(ws + 2097152);         // needs 16,384,000 f

    float* out_logits = out;                // 65,536,000
    float* out_mems   = out + 65536000;     // 33,554,432
    float* out_times  = out + 99090432;     // 8,192

    embed_kernel<<<BC * SEQC, 256, 0, stream>>>(tokens, token_emb, x);
    times_init_kernel<<<32, 256, 0, stream>>>(times, out_times, aux);

    for (int d = 0; d < 4; ++d) {
        const float* mem_d = mems + (size_t)d * BC * MC * DIMC;
        prep_kernel<<<PREP_TOT, 256, 0, stream>>>(
            mem_d, x, expire_W + d * DIMC, expire_b + d, exps, aux,
            mem_b, out_mems + (size_t)d * BC * MC * DIMC,
            ln1_g + d * DIMC, ln1_b + d * DIMC, xn_b,
            Wq + (size_t)d * DIMC * DIMC, Wkv + (size_t)d * DIMC * 2 * DIMC,
            Wo + (size_t)d * DIMC * DIMC, W1 + (size_t)d * DIMC * 4 * DIMC,
            W2 + (size_t)d * 4 * DIMC * DIMC,
            wq_t, wkv_t, wo_t, w1_t, w2_t);
        compact_kernel<<<BC, 64, 0, stream>>>(exps, times + d * MC, cidx, em_c, cnt);
        qkv_gemm_kernel<<<1152, 256, 0, stream>>>(xn_b, mem_b, wq_t, wkv_t,
                                                  cidx, cnt, qb_b, kv_b, vTl, vTc);
        attn_mfma_kernel<<<512, 256, 0, stream>>>(
            qb_b, kv_b, vTl, vTc, cidx, em_c, cnt, attn_b);
        gemm64_kernel<<<dim3(8, 32), 256, 0, stream>>>(
            attn_b, wo_t, bo + d * DIMC, x, x, nullptr, DIMC);
        ln_kernel<<<BC * SEQC, 256, 0, stream>>>(x, ln2_g + d * DIMC, ln2_b + d * DIMC, xn_b);
        ffn1_kernel<<<dim3(32, 16), 256, 0, stream>>>(xn_b, w1_t, b1 + d * 4 * DIMC, ffn_b);
        if (d < 3) {
            gemm64_kernel<<<dim3(8, 32), 256, 0, stream>>>(
                ffn_b, w2_t, b2 + d * DIMC, x, x, nullptr, 4 * DIMC);
        } else {
            gemm64_kernel<<<dim3(8, 32), 256, 0, stream>>>(
                ffn_b, w2_t, b2 + d * DIMC, x, nullptr, x_b, 4 * DIMC);
        }
    }

    wt_kernel<<<dim3(1000, 32), 256, 0, stream>>>(logits_W, lw_t, DIMC, VOCABC);
    logits_kernel<<<1000, 512, 0, stream>>>(x_b, lw_t, logits_b, out_logits);
    aux_write_kernel<<<1, 1, 0, stream>>>(aux, out + 99098624);
}

// Round 18
// 1570.881 us; speedup vs baseline: 1.1073x; 1.0392x over previous
//
#include <hip/hip_runtime.h>
#include <cmath>

// Problem constants
#define DIMC   1024
#define SEQC   512
#define BC     4
#define MC     2048      // MAXMEM
#define CTXC   2560      // MC + SEQC
#define HEADSC 16
#define DHC    64
#define VOCABC 32000
#define MAXC   512       // compact-slot capacity (live keys ~64)

using short8 = __attribute__((ext_vector_type(8))) short;
using f32x4  = __attribute__((ext_vector_type(4))) float;
using u16x4  = __attribute__((ext_vector_type(4))) unsigned short;
using u16x8  = __attribute__((ext_vector_type(8))) unsigned short;

__device__ __forceinline__ unsigned short f2bf(float f) {
    unsigned u = __float_as_uint(f);
    unsigned r = (u + 0x7fffu + ((u >> 16) & 1u)) >> 16;
    return (unsigned short)r;
}

__device__ __forceinline__ void glds16(const unsigned short* g, char* l) {
    __builtin_amdgcn_global_load_lds(
        (const __attribute__((address_space(1))) void*)g,
        (__attribute__((address_space(3))) void*)l, 16, 0, 0);
}

// ---------------- embed ----------------
__global__ __launch_bounds__(256) void embed_kernel(const int* __restrict__ tokens,
                                                    const float* __restrict__ emb,
                                                    float* __restrict__ x) {
    int row = blockIdx.x;
    int tok = tokens[row];
    const float4 v = *(const float4*)(emb + (size_t)tok * DIMC + threadIdx.x * 4);
    *(float4*)(x + (size_t)row * DIMC + threadIdx.x * 4) = v;
}

// ---------------- new_times + aux zero ----------------
__global__ __launch_bounds__(256) void times_init_kernel(const int* __restrict__ times,
                                                         float* __restrict__ out_times,
                                                         float* __restrict__ aux) {
    int i = blockIdx.x * 256 + threadIdx.x;
    if (i == 0) aux[0] = 0.0f;
    if (i < 4 * MC) {
        int d = i >> 11, m = i & (MC - 1);
        out_times[i] = (m < MC - SEQC) ? (float)(times[d * MC + SEQC + m] + SEQC)
                                       : (float)(MC - 1 - m);
    }
}

// ---------------- fused per-layer prep ----------------
#define PREP_MEM 8192
#define PREP_XC  10240
#define PREP_LN  12288
#define PREP_TOT 24576
__global__ __launch_bounds__(256) void prep_kernel(
    const float* __restrict__ mem_d, const float* __restrict__ x,
    const float* __restrict__ eW, const float* __restrict__ eb,
    float* __restrict__ exps, float* __restrict__ aux,
    unsigned short* __restrict__ mem_b, float* __restrict__ out_mems_d,
    const float* __restrict__ g1, const float* __restrict__ b1v,
    unsigned short* __restrict__ xn_b,
    const float* __restrict__ Wq, const float* __restrict__ Wkv,
    const float* __restrict__ Wo, const float* __restrict__ W1,
    const float* __restrict__ W2,
    unsigned short* __restrict__ wq_t, unsigned short* __restrict__ wkv_t,
    unsigned short* __restrict__ wo_t, unsigned short* __restrict__ w1_t,
    unsigned short* __restrict__ w2_t) {
    __shared__ float sh[1056];
    const int bid = blockIdx.x, tid = threadIdx.x;
    if (bid < PREP_MEM) {
        int row = bid;                       // b*2048 + m
        int m = row & 2047, b = row >> 11;
        const float4 v = *(const float4*)(mem_d + (size_t)row * DIMC + tid * 4);
        const float4 w = *(const float4*)(eW + tid * 4);
        float s = v.x * w.x + v.y * w.y + v.z * w.z + v.w * w.w;
        for (int off = 32; off; off >>= 1) s += __shfl_down(s, off, 64);
        int wid = tid >> 6, lane = tid & 63;
        if (lane == 0) sh[wid] = s;
        u16x4 o = { f2bf(v.x), f2bf(v.y), f2bf(v.z), f2bf(v.w) };
        *(u16x4*)(mem_b + (size_t)row * DIMC + tid * 4) = o;
        if (m >= SEQC)
            *(float4*)(out_mems_d + ((size_t)(b * MC + m - SEQC)) * DIMC + tid * 4) = v;
        __syncthreads();
        if (tid == 0) {
            float z = sh[0] + sh[1] + sh[2] + sh[3] + eb[0];
            float e = (float)MC / (1.0f + expf(-z));
            exps[row] = e;
            atomicAdd(aux, e * (1e-6f / (float)SEQC));
        }
    } else if (bid < PREP_XC) {
        int r = bid - PREP_MEM;              // b*512 + i
        int b = r >> 9, i = r & 511;
        const float4 v = *(const float4*)(x + (size_t)r * DIMC + tid * 4);
        *(float4*)(out_mems_d + ((size_t)(b * MC + MC - SEQC + i)) * DIMC + tid * 4) = v;
    } else if (bid < PREP_LN) {
        int row = bid - PREP_XC;
        const float4 v = *(const float4*)(x + (size_t)row * DIMC + tid * 4);
        float s = v.x + v.y + v.z + v.w;
        float q = v.x * v.x + v.y * v.y + v.z * v.z + v.w * v.w;
        for (int off = 32; off; off >>= 1) {
            s += __shfl_down(s, off, 64);
            q += __shfl_down(q, off, 64);
        }
        int wid = tid >> 6, lane = tid & 63;
        if (lane == 0) { sh[wid] = s; sh[4 + wid] = q; }
        __syncthreads();
        if (tid == 0) {
            float S = sh[0] + sh[1] + sh[2] + sh[3];
            float Q = sh[4] + sh[5] + sh[6] + sh[7];
            float mu = S / DIMC;
            float var = Q / DIMC - mu * mu;
            sh[8] = mu;
            sh[9] = rsqrtf(var + 1e-5f);
        }
        __syncthreads();
        float mu = sh[8], rstd = sh[9];
        const float4 gg = *(const float4*)(g1 + tid * 4);
        const float4 bb = *(const float4*)(b1v + tid * 4);
        u16x4 o = { f2bf((v.x - mu) * rstd * gg.x + bb.x),
                    f2bf((v.y - mu) * rstd * gg.y + bb.y),
                    f2bf((v.z - mu) * rstd * gg.z + bb.z),
                    f2bf((v.w - mu) * rstd * gg.w + bb.w) };
        *(u16x4*)(xn_b + (size_t)row * DIMC + tid * 4) = o;
    } else {
        int t = bid - PREP_LN;
        const float* W; unsigned short* Wt; int K, N, tx, ty;
        if (t < 1024)      { W = Wq;  Wt = wq_t;  K = 1024; N = 1024; tx = t & 31;  ty = t >> 5; }
        else if (t < 3072) { int u = t - 1024; W = Wkv; Wt = wkv_t; K = 1024; N = 2048; tx = u & 63;  ty = u >> 6; }
        else if (t < 4096) { int u = t - 3072; W = Wo;  Wt = wo_t;  K = 1024; N = 1024; tx = u & 31;  ty = u >> 5; }
        else if (t < 8192) { int u = t - 4096; W = W1;  Wt = w1_t;  K = 1024; N = 4096; tx = u & 127; ty = u >> 7; }
        else               { int u = t - 8192; W = W2;  Wt = w2_t;  K = 4096; N = 1024; tx = u & 31;  ty = u >> 5; }
        int n0 = tx * 32, k0 = ty * 32;
        int r = tid >> 3, c = (tid & 7) * 4;
        const float4 v = *(const float4*)(W + (size_t)(k0 + r) * N + n0 + c);
        sh[r * 33 + c] = v.x; sh[r * 33 + c + 1] = v.y;
        sh[r * 33 + c + 2] = v.z; sh[r * 33 + c + 3] = v.w;
        __syncthreads();
        u16x4 o = { f2bf(sh[(c + 0) * 33 + r]), f2bf(sh[(c + 1) * 33 + r]),
                    f2bf(sh[(c + 2) * 33 + r]), f2bf(sh[(c + 3) * 33 + r]) };
        *(u16x4*)(Wt + (size_t)(n0 + r) * K + k0 + c) = o;
    }
}

// ---------------- compact live memory keys (deterministic ballot scan) ----------------
__global__ __launch_bounds__(64) void compact_kernel(
    const float* __restrict__ exps, const int* __restrict__ times_d,
    int* __restrict__ cidx, float* __restrict__ em_c, int* __restrict__ cnt) {
    int b = blockIdx.x, lane = threadIdx.x;
    int c = 0;
    for (int it = 0; it < 32; ++it) {
        int j = it * 64 + lane;
        float e = exps[b * MC + j];
        float rr = (e - (float)times_d[j]) * (1.0f / 128.0f) + 1.0f;
        float em = fminf(fmaxf(rr, 0.0f), 1.0f);
        unsigned long long mk = __ballot(em > 0.0f);
        int pos = c + __popcll(mk & ((1ull << lane) - 1ull));
        if (em > 0.0f) {
            cidx[b * 2048 + pos] = j;
            em_c[b * 2048 + pos] = em;
        }
        c += __popcll(mk);
    }
    int padded = (c + 63) & ~63;
    int fill_to = padded < MAXC ? MAXC : padded;
    for (int p = c + lane; p < fill_to; p += 64) {
        cidx[b * 2048 + p] = 0;     // valid row; em=0 kills contribution
        em_c[b * 2048 + p] = 0.0f;
    }
    int tiles = padded >> 6;
    if (tiles > (MAXC >> 6)) tiles = MAXC >> 6;
    if (lane == 0) cnt[b] = tiles;
}

// ---------------- LayerNorm (fp32 in, bf16 out) — LN2 ----------------
__global__ __launch_bounds__(256) void ln_kernel(const float* __restrict__ in,
                                                 const float* __restrict__ g,
                                                 const float* __restrict__ b,
                                                 unsigned short* __restrict__ outb) {
    int row = blockIdx.x;
    int tid = threadIdx.x;
    const float4 v = *(const float4*)(in + (size_t)row * DIMC + tid * 4);
    float s = v.x + v.y + v.z + v.w;
    float q = v.x * v.x + v.y * v.y + v.z * v.z + v.w * v.w;
    for (int off = 32; off; off >>= 1) {
        s += __shfl_down(s, off, 64);
        q += __shfl_down(q, off, 64);
    }
    __shared__ float ss[4], sq[4];
    int wid = tid >> 6, lane = tid & 63;
    if (lane == 0) { ss[wid] = s; sq[wid] = q; }
    __syncthreads();
    if (tid == 0) {
        float S = ss[0] + ss[1] + ss[2] + ss[3];
        float Q = sq[0] + sq[1] + sq[2] + sq[3];
        float mu = S / DIMC;
        float var = Q / DIMC - mu * mu;
        ss[0] = mu;
        sq[0] = rsqrtf(var + 1e-5f);
    }
    __syncthreads();
    float mu = ss[0], rstd = sq[0];
    const float4 gg = *(const float4*)(g + tid * 4);
    const float4 bb = *(const float4*)(b + tid * 4);
    u16x4 o = { f2bf((v.x - mu) * rstd * gg.x + bb.x),
                f2bf((v.y - mu) * rstd * gg.y + bb.y),
                f2bf((v.z - mu) * rstd * gg.z + bb.z),
                f2bf((v.w - mu) * rstd * gg.w + bb.w) };
    *(u16x4*)(outb + (size_t)row * DIMC + tid * 4) = o;
}

// ---------------- weight convert + transpose (logits_W only) ----------------
__global__ __launch_bounds__(256) void wt_kernel(const float* __restrict__ W,
                                                 unsigned short* __restrict__ Wt,
                                                 int K, int N) {
    __shared__ float t[32][33];
    int tid = threadIdx.x;
    int n0 = blockIdx.x * 32, k0 = blockIdx.y * 32;
    int r = tid >> 3, c = (tid & 7) * 4;
    const float4 v = *(const float4*)(W + (size_t)(k0 + r) * N + n0 + c);
    t[r][c] = v.x; t[r][c + 1] = v.y; t[r][c + 2] = v.z; t[r][c + 3] = v.w;
    __syncthreads();
    u16x4 o = { f2bf(t[c + 0][r]), f2bf(t[c + 1][r]),
                f2bf(t[c + 2][r]), f2bf(t[c + 3][r]) };
    *(u16x4*)(Wt + (size_t)(n0 + r) * K + k0 + c) = o;
}

// ---------------- bf16 MFMA GEMM body — BK=64 (two 32-K planes/buffer), counted-vmcnt + T2 swizzle ----------------
// Each buffer = 2 planes of [RT][32] u16 (linear per plane -> global_load_lds mapping and
// T2 swizzle unchanged; planes are base offsets). Per iteration: stage 64 K-elems of the
// next buffer (8 loads RT=128 / 6 RT=64), counted vmcnt, one barrier pair, 2x MFMA sub-rounds.
// Requires K % 64 == 0 (all K here are 1024 or 4096). MFMA order unchanged -> identical numerics.
template<int AMODE, bool BIAS, bool GELU, bool RES, int OMODE, int RT>
__device__ __forceinline__ void gemm_body(
    unsigned short* As, unsigned short* Bs,
    const unsigned short* __restrict__ A, const int* __restrict__ gidx,
    const unsigned short* __restrict__ Wt, const float* __restrict__ bias,
    const float* __restrict__ res, float* __restrict__ Cf,
    unsigned short* __restrict__ Cb, int K, int N, int bx, int by) {
    constexpr int MF = RT / 32;
    const int tid = threadIdx.x;
    const int lane = tid & 63, wave = tid >> 6;
    const int row0 = by * RT, col0 = bx * 128;

    const int seg = tid & 3;
    const int rr0 = tid >> 2;
    const int sseg8 = (seg ^ ((rr0 >> 1) & 3)) * 8;   // source pre-swizzle (elements)
    const unsigned short* arow[RT / 64];
    #pragma unroll
    for (int p = 0; p < RT / 64; ++p) {
        int r = row0 + p * 64 + rr0;
        if (AMODE == 2) {
            int b = r >> 9, slot = r & (MAXC - 1);
            arow[p] = A + ((size_t)(b * 2048 + gidx[b * 2048 + slot])) * K;
        } else {
            arow[p] = A + (size_t)r * K;
        }
        arow[p] += sseg8;
    }
    const unsigned short* brow[2];
    #pragma unroll
    for (int p = 0; p < 2; ++p)
        brow[p] = Wt + (size_t)(col0 + p * 64 + rr0) * K + sseg8;

    char* lA = (char*)As + (tid & 192) * 16;
    char* lB = (char*)Bs + (tid & 192) * 16;

    // buffer q = planes {q*2, q*2+1}; A plane = RT*64 bytes, B plane = 8192 bytes
    auto stage = [&](int k0, int q) {
        #pragma unroll
        for (int kk = 0; kk < 2; ++kk) {
            char* a = lA + (q * 2 + kk) * (RT * 64);
            glds16(arow[0] + k0 + kk * 32, a);
            if (RT == 128) glds16(arow[1] + k0 + kk * 32, a + 4096);
            char* bp = lB + (q * 2 + kk) * 8192;
            glds16(brow[0] + k0 + kk * 32, bp);
            glds16(brow[1] + k0 + kk * 32, bp + 4096);
        }
    };

    f32x4 acc[MF][4] = {};

    const int wr = (wave >> 1) * (RT / 2), wc = (wave & 1) * 64;
    const int fr = lane & 15;
    const int g4 = lane >> 4;
    const int kA8 = (g4 ^ (((wr + fr) >> 1) & 3)) * 8;   // swizzled read slot (elements)
    const int kB8 = (g4 ^ (((wc + fr) >> 1) & 3)) * 8;

    stage(0, 0);
    int cur = 0;
    for (int k0 = 0; k0 < K; k0 += 64) {
        if (k0 + 64 < K) {
            stage(k0 + 64, cur ^ 1);
            if (RT == 128) asm volatile("s_waitcnt vmcnt(8)" ::: "memory");
            else           asm volatile("s_waitcnt vmcnt(6)" ::: "memory");
        } else {
            asm volatile("s_waitcnt vmcnt(0)" ::: "memory");
        }
        __builtin_amdgcn_s_barrier();
        __builtin_amdgcn_sched_barrier(0);
        #pragma unroll
        for (int kk = 0; kk < 2; ++kk) {
            const unsigned short* Ar = As + (cur * 2 + kk) * (RT * 32)
                                       + (size_t)(wr + fr) * 32 + kA8;
            const unsigned short* Br = Bs + (cur * 2 + kk) * (128 * 32)
                                       + (size_t)(wc + fr) * 32 + kB8;
            short8 a[MF], b[4];
            #pragma unroll
            for (int m = 0; m < MF; ++m) a[m] = *(const short8*)(Ar + m * 16 * 32);
            #pragma unroll
            for (int n = 0; n < 4; ++n) b[n] = *(const short8*)(Br + n * 16 * 32);
            #pragma unroll
            for (int m = 0; m < MF; ++m)
                #pragma unroll
                for (int n = 0; n < 4; ++n)
                    acc[m][n] = __builtin_amdgcn_mfma_f32_16x16x32_bf16(a[m], b[n], acc[m][n], 0, 0, 0);
        }
        __builtin_amdgcn_s_barrier();
        cur ^= 1;
    }

    const int orow = row0 + wr + (lane >> 4) * 4;
    const int ocol = col0 + wc + fr;
    if (OMODE >= 3) {
        #pragma unroll
        for (int n = 0; n < 4; ++n) {
            int c = ocol + n * 16;
            #pragma unroll
            for (int m = 0; m < MF; ++m) {
                int r0 = orow + m * 16;
                int b = r0 >> 9, i = r0 & 511;
                size_t addr = (OMODE == 3)
                    ? ((size_t)(b * 1024 + c)) * 512 + i
                    : ((size_t)(b * 1024 + c)) * MAXC + i;
                u16x4 o = { f2bf(acc[m][n][0]), f2bf(acc[m][n][1]),
                            f2bf(acc[m][n][2]), f2bf(acc[m][n][3]) };
                *(u16x4*)(Cb + addr) = o;
            }
        }
        return;
    }
    #pragma unroll
    for (int n = 0; n < 4; ++n) {
        int c = ocol + n * 16;
        float bv = BIAS ? bias[c] : 0.0f;
        #pragma unroll
        for (int m = 0; m < MF; ++m) {
            #pragma unroll
            for (int i = 0; i < 4; ++i) {
                int r0 = orow + m * 16 + i;
                size_t orr = r0;
                if (OMODE == 1) orr = (size_t)r0 + (size_t)(r0 >> 11) * 512;
                if (OMODE == 2) orr = (size_t)r0 + (size_t)(r0 >> 9) * 2048 + 2048;
                size_t idx = orr * N + c;
                float v = acc[m][n][i] + bv;
                if (GELU) v = 0.5f * v * (1.0f + erff(v * 0.70710678118f));
                if (RES) v += res[idx];
                if (Cf) Cf[idx] = v;
                if (Cb) Cb[idx] = f2bf(v);
            }
        }
    }
}

// Fused: Q(128) + local-K(128) + mem-K(512) + local-V transposed(128) + compact-V transposed(256)
__global__ __launch_bounds__(256) void qkv_gemm_kernel(
    const unsigned short* __restrict__ xn_b, const unsigned short* __restrict__ mem_b,
    const unsigned short* __restrict__ wq_t, const unsigned short* __restrict__ wkv_t,
    const int* __restrict__ cidx, const int* __restrict__ cnt,
    unsigned short* __restrict__ qb, unsigned short* __restrict__ kvb,
    unsigned short* __restrict__ vTl, unsigned short* __restrict__ vTc) {
    __shared__ unsigned short As[4 * 128 * 32];
    __shared__ unsigned short Bs[4 * 128 * 32];
    int id = blockIdx.x;
    if (id < 128) {
        gemm_body<0, false, false, false, 0, 128>(As, Bs, xn_b, nullptr, wq_t,
            nullptr, nullptr, nullptr, qb, 1024, 1024, id & 7, id >> 3);
    } else if (id < 256) {
        id -= 128;  // local rows -> ctx rows, K half of wkv
        gemm_body<0, false, false, false, 2, 128>(As, Bs, xn_b, nullptr, wkv_t,
            nullptr, nullptr, nullptr, kvb, 1024, 1024, id & 7, id >> 3);
    } else if (id < 768) {
        id -= 256;  // mem rows -> ctx rows, K half of wkv
        gemm_body<0, false, false, false, 1, 128>(As, Bs, mem_b, nullptr, wkv_t,
            nullptr, nullptr, nullptr, kvb, 1024, 1024, id & 7, id >> 3);
    } else if (id < 896) {
        id -= 768;  // local V -> vTl transposed
        gemm_body<0, false, false, false, 3, 128>(As, Bs, xn_b, nullptr,
            wkv_t + (size_t)1024 * 1024, nullptr, nullptr, nullptr, vTl,
            1024, 1024, id & 7, id >> 3);
    } else {
        id -= 896;  // compact V: gather mem rows by cidx -> vTc transposed
        int by = id >> 3;
        int b = (by * 64) >> 9, slot0 = (by * 64) & (MAXC - 1);
        if (slot0 >= cnt[b] * 64) return;
        gemm_body<2, false, false, false, 4, 64>(As, Bs, mem_b, cidx,
            wkv_t + (size_t)1024 * 1024, nullptr, nullptr, nullptr, vTc,
            1024, 1024, id & 7, by);
    }
}

// RT=64 GEMM with bias+residual, N=1024 (Wo and FFN2)
__global__ __launch_bounds__(256) void gemm64_kernel(
    const unsigned short* __restrict__ A, const unsigned short* __restrict__ Wt,
    const float* __restrict__ bias, const float* __restrict__ res,
    float* __restrict__ Cf, unsigned short* __restrict__ Cb, int K) {
    __shared__ unsigned short As[4 * 64 * 32];
    __shared__ unsigned short Bs[4 * 128 * 32];
    gemm_body<0, true, false, true, 0, 64>(As, Bs, A, nullptr, Wt, bias, res,
        Cf, Cb, K, 1024, blockIdx.x, blockIdx.y);
}

// FFN1: gelu, bf16 out
__global__ __launch_bounds__(256) void ffn1_kernel(
    const unsigned short* __restrict__ A, const unsigned short* __restrict__ Wt,
    const float* __restrict__ bias, unsigned short* __restrict__ Cb) {
    __shared__ unsigned short As[4 * 128 * 32];
    __shared__ unsigned short Bs[4 * 128 * 32];
    gemm_body<0, true, true, false, 0, 128>(As, Bs, A, nullptr, Wt, bias, nullptr,
        nullptr, Cb, 1024, 4096, blockIdx.x, blockIdx.y);
}

// ---------------- logits: 256x256 tile, 512 threads, 8 waves (2x4), counted-vmcnt + T2 swizzle ----------------
__global__ __launch_bounds__(512, 2) void logits_kernel(
    const unsigned short* __restrict__ A, const unsigned short* __restrict__ Wt,
    const float* __restrict__ bias, float* __restrict__ Cf) {
    __shared__ unsigned short As[2 * 256 * 32];
    __shared__ unsigned short Bs[2 * 256 * 32];
    const int L = blockIdx.x;
    const int wid = (L & 7) * 125 + (L >> 3);
    const int ct = wid / 8, rt = wid & 7;
    const int row0 = rt * 256, col0 = ct * 256;
    const int tid = threadIdx.x;
    const int lane = tid & 63, wave = tid >> 6;

    const int seg = tid & 3;
    const int rr0 = tid >> 2;                 // 0..127
    const int sseg8 = (seg ^ ((rr0 >> 1) & 3)) * 8;   // source pre-swizzle
    const unsigned short* arow[2];
    const unsigned short* brow[2];
    #pragma unroll
    for (int p = 0; p < 2; ++p) {
        arow[p] = A + (size_t)(row0 + p * 128 + rr0) * 1024 + sseg8;
        brow[p] = Wt + (size_t)(col0 + p * 128 + rr0) * 1024 + sseg8;
    }
    char* lA = (char*)As + (tid & 448) * 16;  // wave-uniform base (8 waves)
    char* lB = (char*)Bs + (tid & 448) * 16;

    auto stage = [&](int k0, int q) {
        char* a = lA + q * 16384;
        char* bp = lB + q * 16384;
        glds16(arow[0] + k0, a);
        glds16(arow[1] + k0, a + 8192);
        glds16(brow[0] + k0, bp);
        glds16(brow[1] + k0, bp + 8192);
    };

    f32x4 acc[8][4] = {};
    const int wr = (wave >> 2) * 128, wc = (wave & 3) * 64;
    const int fr = lane & 15;
    const int g4 = lane >> 4;
    const int kA8 = (g4 ^ (((wr + fr) >> 1) & 3)) * 8;
    const int kB8 = (g4 ^ (((wc + fr) >> 1) & 3)) * 8;

    stage(0, 0);
    int cur = 0;
    for (int k0 = 0; k0 < 1024; k0 += 32) {
        if (k0 + 32 < 1024) {
            stage(k0 + 32, cur ^ 1);
            asm volatile("s_waitcnt vmcnt(4)" ::: "memory");
        } else {
            asm volatile("s_waitcnt vmcnt(0)" ::: "memory");
        }
        __builtin_amdgcn_s_barrier();
        __builtin_amdgcn_sched_barrier(0);
        const unsigned short* Ar = As + cur * 8192 + (size_t)(wr + fr) * 32 + kA8;
        const unsigned short* Br = Bs + cur * 8192 + (size_t)(wc + fr) * 32 + kB8;
        short8 a[8], b[4];
        #pragma unroll
        for (int m = 0; m < 8; ++m) a[m] = *(const short8*)(Ar + m * 16 * 32);
        #pragma unroll
        for (int n = 0; n < 4; ++n) b[n] = *(const short8*)(Br + n * 16 * 32);
        #pragma unroll
        for (int m = 0; m < 8; ++m)
            #pragma unroll
            for (int n = 0; n < 4; ++n)
                acc[m][n] = __builtin_amdgcn_mfma_f32_16x16x32_bf16(a[m], b[n], acc[m][n], 0, 0, 0);
        __builtin_amdgcn_s_barrier();
        cur ^= 1;
    }

    const int orow = row0 + wr + (lane >> 4) * 4;
    const int ocol = col0 + wc + fr;
    #pragma unroll
    for (int n = 0; n < 4; ++n) {
        int c = ocol + n * 16;
        float bv = bias[c];
        #pragma unroll
        for (int m = 0; m < 8; ++m) {
            #pragma unroll
            for (int i = 0; i < 4; ++i)
                Cf[(size_t)(orow + m * 16 + i) * VOCABC + c] = acc[m][n][i] + bv;
        }
    }
}

// ---------------- 3-phase MFMA flash attention — 128-wide mem double-tiles ----------------
// grid = 512 (8 qt x 16 h x 4 b), XCD-grouped; counted-vmcnt raw-barrier pipelines.
// Phase 1: 16 double-tiles of 128 mem keys (denominator only). Phase 2: 64-wide causal
// local tiles with V. Phase 3: compact live-mem tiles. Softmax in base-2.
#define CSC 0.18033688011112042f
__global__ __launch_bounds__(256) void attn_mfma_kernel(
    const unsigned short* __restrict__ qb,
    const unsigned short* __restrict__ kvb,   // K-only [b][2560][1024]
    const unsigned short* __restrict__ vTl,   // [b*1024+d][512] local V transposed
    const unsigned short* __restrict__ vTc,   // [b*1024+d][MAXC] compact V transposed
    const int* __restrict__ cidx,
    const float* __restrict__ em_c,
    const int* __restrict__ cnt,
    unsigned short* __restrict__ outb) {
    __shared__ unsigned short K_s[2][128 * 64];
    __shared__ unsigned short V_s[2][64 * 64];
    __shared__ unsigned short p_s[4][16][72];
    __shared__ float em_s[64];
    const int tid = threadIdx.x;
    const int lane = tid & 63, wave = tid >> 6;
    const int L = blockIdx.x;
    const int ix = L >> 3;
    const int qt = ix & 7;
    const int gidx = (L & 7) * 8 + (ix >> 3);   // same (h,b) group on same XCD
    const int h = gidx & 15, b = gidx >> 4;
    const int fr = lane & 15, g = lane >> 4;
    const int gq = qt * 64 + wave * 16;

    short8 aq[2];
    {
        const unsigned short* qp = qb + ((size_t)(b * SEQC + gq + fr)) * DIMC + h * DHC + g * 8;
        aq[0] = *(const short8*)qp;
        aq[1] = *(const short8*)(qp + 32);
    }

    const int sr = tid >> 3, ss = tid & 7;       // sr in [0,32)
    const int sw = (ss ^ (sr & 7)) * 8;          // source pre-swizzle (p*32 keeps r&7)
    const int wbase = (tid & 192) * 16;          // wave-uniform LDS byte base (4 waves)

    f32x4 acc_o[4] = {};
    float m_q = -1e30f, l_q = 0.0f;              // log2 domain

    // ---- phase 1: 16 double-tiles of 128 mem keys, denominator only ----
    auto stageM = [&](int t, int q) {
        const int jbase = t * 128;
        #pragma unroll
        for (int p = 0; p < 4; ++p) {
            int r = sr + p * 32;
            glds16(kvb + ((size_t)(b * CTXC + jbase + r)) * 1024 + h * DHC + sw,
                   (char*)K_s[q] + wbase + p * 4096);
        }
    };

    stageM(0, 0);
    asm volatile("s_waitcnt vmcnt(0)" ::: "memory");
    __builtin_amdgcn_s_barrier();
    int cur = 0;
    for (int t = 0; t < 16; ++t) {
        if (t + 1 < 16) {
            stageM(t + 1, cur ^ 1);
            asm volatile("s_waitcnt vmcnt(4)" ::: "memory");
        } else {
            asm volatile("s_waitcnt vmcnt(0)" ::: "memory");
        }
        __builtin_amdgcn_s_barrier();
        __builtin_amdgcn_sched_barrier(0);

        f32x4 sT[2][4] = {};
        #pragma unroll
        for (int c = 0; c < 2; ++c)
            #pragma unroll
            for (int ks = 0; ks < 2; ++ks)
                #pragma unroll
                for (int mf = 0; mf < 4; ++mf) {
                    int row = c * 64 + mf * 16 + fr, sg = (ks * 4 + g) ^ (row & 7);
                    short8 kk = *(const short8*)((const char*)K_s[cur] + row * 128 + sg * 16);
                    sT[c][mf] = __builtin_amdgcn_mfma_f32_16x16x32_bf16(kk, aq[ks], sT[c][mf], 0, 0, 0);
                }

        float mx = sT[0][0][0];
        #pragma unroll
        for (int c = 0; c < 2; ++c)
            #pragma unroll
            for (int mf = 0; mf < 4; ++mf)
                #pragma unroll
                for (int i = 0; i < 4; ++i) mx = fmaxf(mx, sT[c][mf][i]);
        mx *= CSC;
        mx = fmaxf(mx, __shfl_xor(mx, 16, 64));
        mx = fmaxf(mx, __shfl_xor(mx, 32, 64));
        float mnew = fmaxf(m_q, mx);
        float fs = __builtin_amdgcn_exp2f(m_q - mnew);
        m_q = mnew;
        float ps = 0.0f;
        #pragma unroll
        for (int c = 0; c < 2; ++c)
            #pragma unroll
            for (int mf = 0; mf < 4; ++mf)
                #pragma unroll
                for (int i = 0; i < 4; ++i)
                    ps += __builtin_amdgcn_exp2f(sT[c][mf][i] * CSC - mnew);
        ps += __shfl_xor(ps, 16, 64);
        ps += __shfl_xor(ps, 32, 64);
        l_q = l_q * fs + ps;

        __builtin_amdgcn_s_barrier();
        cur ^= 1;
    }

    // ---- phase 2: local causal tiles (64-wide, with V) ----
    auto stageL = [&](int lt, int q) {
        const int jbase = MC + lt * 64;
        #pragma unroll
        for (int p = 0; p < 2; ++p) {
            int r = sr + p * 32;
            glds16(kvb + ((size_t)(b * CTXC + jbase + r)) * 1024 + h * DHC + sw,
                   (char*)K_s[q] + wbase + p * 4096);
            glds16(vTl + ((size_t)(b * 1024 + h * DHC + r)) * 512 + lt * 64 + sw,
                   (char*)V_s[q] + wbase + p * 4096);
        }
    };

    const int nlt = qt + 1;
    stageL(0, 0);
    asm volatile("s_waitcnt vmcnt(0)" ::: "memory");
    __builtin_amdgcn_s_barrier();
    cur = 0;
    for (int lt = 0; lt < nlt; ++lt) {
        if (lt + 1 < nlt) {
            stageL(lt + 1, cur ^ 1);
            asm volatile("s_waitcnt vmcnt(4)" ::: "memory");
        } else {
            asm volatile("s_waitcnt vmcnt(0)" ::: "memory");
        }
        __builtin_amdgcn_s_barrier();
        __builtin_amdgcn_sched_barrier(0);

        f32x4 sT[4] = {};
        #pragma unroll
        for (int ks = 0; ks < 2; ++ks)
            #pragma unroll
            for (int mf = 0; mf < 4; ++mf) {
                int row = mf * 16 + fr, sg = (ks * 4 + g) ^ (row & 7);
                short8 kk = *(const short8*)((const char*)K_s[cur] + row * 128 + sg * 16);
                sT[mf] = __builtin_amdgcn_mfma_f32_16x16x32_bf16(kk, aq[ks], sT[mf], 0, 0, 0);
            }

        const int kq = gq + fr - lt * 64;
        float sv[4][4];
        #pragma unroll
        for (int mf = 0; mf < 4; ++mf)
            #pragma unroll
            for (int i = 0; i < 4; ++i) {
                int kl = mf * 16 + g * 4 + i;
                sv[mf][i] = (kl <= kq) ? sT[mf][i] * CSC : -1e30f;
            }
        float mx = sv[0][0];
        #pragma unroll
        for (int mf = 0; mf < 4; ++mf)
            #pragma unroll
            for (int i = 0; i < 4; ++i) mx = fmaxf(mx, sv[mf][i]);
        mx = fmaxf(mx, __shfl_xor(mx, 16, 64));
        mx = fmaxf(mx, __shfl_xor(mx, 32, 64));
        float mnew = fmaxf(m_q, mx);
        float fs = __builtin_amdgcn_exp2f(m_q - mnew);
        m_q = mnew;
        float ps = 0.0f;
        #pragma unroll
        for (int mf = 0; mf < 4; ++mf)
            #pragma unroll
            for (int i = 0; i < 4; ++i) {
                float pe = __builtin_amdgcn_exp2f(sv[mf][i] - mnew);
                ps += pe;
                p_s[wave][fr][mf * 16 + g * 4 + i] = f2bf(pe);
            }
        ps += __shfl_xor(ps, 16, 64);
        ps += __shfl_xor(ps, 32, 64);
        l_q = l_q * fs + ps;
        float fsr[4];
        #pragma unroll
        for (int i = 0; i < 4; ++i) fsr[i] = __shfl(fs, g * 4 + i, 64);
        #pragma unroll
        for (int n = 0; n < 4; ++n)
            #pragma unroll
            for (int i = 0; i < 4; ++i) acc_o[n][i] *= fsr[i];
        asm volatile("s_waitcnt lgkmcnt(0)" ::: "memory");
        #pragma unroll
        for (int ks = 0; ks < 2; ++ks) {
            short8 ap = *(const short8*)&p_s[wave][fr][ks * 32 + g * 8];
            #pragma unroll
            for (int n = 0; n < 4; ++n) {
                int row = n * 16 + fr, sg = (ks * 4 + g) ^ (row & 7);
                short8 bv = *(const short8*)((const char*)V_s[cur] + row * 128 + sg * 16);
                acc_o[n] = __builtin_amdgcn_mfma_f32_16x16x32_bf16(ap, bv, acc_o[n], 0, 0, 0);
            }
        }
        __builtin_amdgcn_s_barrier();
        cur ^= 1;
    }

    // ---- phase 3: compact live-mem tiles (final m,l; no m/l update) ----
    const int nct = cnt[b];
    for (int ct = 0; ct < nct; ++ct) {
        __syncthreads();
        #pragma unroll
        for (int p = 0; p < 2; ++p) {
            int r = sr + p * 32;
            int row = cidx[b * 2048 + ct * 64 + r];
            glds16(kvb + ((size_t)(b * CTXC + row)) * 1024 + h * DHC + sw,
                   (char*)K_s[0] + wbase + p * 4096);
            glds16(vTc + ((size_t)(b * 1024 + h * DHC + r)) * MAXC + ct * 64 + sw,
                   (char*)V_s[0] + wbase + p * 4096);
        }
        if (tid < 64) em_s[tid] = em_c[b * 2048 + ct * 64 + tid];
        __syncthreads();
        f32x4 sT[4] = {};
        #pragma unroll
        for (int ks = 0; ks < 2; ++ks)
            #pragma unroll
            for (int mf = 0; mf < 4; ++mf) {
                int row = mf * 16 + fr, sg = (ks * 4 + g) ^ (row & 7);
                short8 kk = *(const short8*)((const char*)K_s[0] + row * 128 + sg * 16);
                sT[mf] = __builtin_amdgcn_mfma_f32_16x16x32_bf16(kk, aq[ks], sT[mf], 0, 0, 0);
            }
        #pragma unroll
        for (int mf = 0; mf < 4; ++mf)
            #pragma unroll
            for (int i = 0; i < 4; ++i) {
                int key = mf * 16 + g * 4 + i;
                float pe = __builtin_amdgcn_exp2f(sT[mf][i] * CSC - m_q) * em_s[key];
                p_s[wave][fr][key] = f2bf(pe);
            }
        asm volatile("s_waitcnt lgkmcnt(0)" ::: "memory");
        #pragma unroll
        for (int ks = 0; ks < 2; ++ks) {
            short8 ap = *(const short8*)&p_s[wave][fr][ks * 32 + g * 8];
            #pragma unroll
            for (int n = 0; n < 4; ++n) {
                int row = n * 16 + fr, sg = (ks * 4 + g) ^ (row & 7);
                short8 bv = *(const short8*)((const char*)V_s[0] + row * 128 + sg * 16);
                acc_o[n] = __builtin_amdgcn_mfma_f32_16x16x32_bf16(ap, bv, acc_o[n], 0, 0, 0);
            }
        }
    }

    float linv = 1.0f / l_q;
    float invr[4];
    #pragma unroll
    for (int i = 0; i < 4; ++i) invr[i] = __shfl(linv, g * 4 + i, 64);
    #pragma unroll
    for (int n = 0; n < 4; ++n) {
        #pragma unroll
        for (int i = 0; i < 4; ++i) {
            size_t idx = ((size_t)(b * SEQC + gq + g * 4 + i)) * DIMC + h * DHC + n * 16 + fr;
            outb[idx] = f2bf(acc_o[n][i] * invr[i]);
        }
    }
}

// ---------------- aux writeback ----------------
__global__ void aux_write_kernel(const float* __restrict__ aux, float* __restrict__ dst) {
    dst[0] = aux[0];
}

extern "C" void kernel_launch(void* const* d_in, const int* in_sizes, int n_in,
                              void* d_out, int out_size, void* d_ws, size_t ws_size,
                              hipStream_t stream) {
    const int*   tokens    = (const int*)d_in[0];
    const float* mems      = (const float*)d_in[1];
    const int*   times     = (const int*)d_in[2];
    const float* token_emb = (const float*)d_in[3];
    const float* expire_W  = (const float*)d_in[4];
    const float* expire_b  = (const float*)d_in[5];
    const float* ln1_g     = (const float*)d_in[6];
    const float* ln1_b     = (const float*)d_in[7];
    const float* Wq        = (const float*)d_in[8];
    const float* Wkv       = (const float*)d_in[9];
    const float* Wo        = (const float*)d_in[10];
    const float* bo        = (const float*)d_in[11];
    const float* ln2_g     = (const float*)d_in[12];
    const float* ln2_b     = (const float*)d_in[13];
    const float* W1        = (const float*)d_in[14];
    const float* b1        = (const float*)d_in[15];
    const float* W2        = (const float*)d_in[16];
    const float* b2        = (const float*)d_in[17];
    const float* logits_W  = (const float*)d_in[18];
    const float* logits_b  = (const float*)d_in[19];

    float* out = (float*)d_out;
    float* ws  = (float*)d_ws;

    // workspace layout (float offsets)
    float* x = ws;                                                  //  0       (2,097,152)
    unsigned short* qb_b  = (unsigned short*)(ws + 2097152);        //  1,048,576 f
    unsigned short* kv_b  = (unsigned short*)(ws + 3145728);        //  5,242,880 f (K-only)
    unsigned short* vTl   = (unsigned short*)(ws + 8388608);        //  1,048,576 f
    unsigned short* vTc   = (unsigned short*)(ws + 9437184);        //  1,048,576 f
    unsigned short* xn_b  = (unsigned short*)(ws + 10485760);       //  1,048,576 f
    unsigned short* attn_b= (unsigned short*)(ws + 11534336);       //  1,048,576 f
    unsigned short* ffn_b = (unsigned short*)(ws + 12582912);       //  4,194,304 f
    unsigned short* mem_b = (unsigned short*)(ws + 16777216);       //  4,194,304 f
    unsigned short* x_b   = (unsigned short*)(ws + 20971520);       //  1,048,576 f
    unsigned short* wq_t  = (unsigned short*)(ws + 22020096);       //    524,288 f
    unsigned short* wkv_t = (unsigned short*)(ws + 22544384);       //  1,048,576 f
    unsigned short* wo_t  = (unsigned short*)(ws + 23592960);       //    524,288 f
    unsigned short* w1_t  = (unsigned short*)(ws + 24117248);       //  2,097,152 f
    unsigned short* w2_t  = (unsigned short*)(ws + 26214400);       //  2,097,152 f
    float* exps = ws + 28311552;                                    //      8,192 f
    float* aux  = ws + 28319744;                                    //         16 f
    int*   cidx = (int*)(ws + 28319760);                            //      8,192
    float* em_c = ws + 28327952;                                    //      8,192
    int*   cnt  = (int*)(ws + 28336144);                            //          4
    // logits_W^T aliases qb_b..mem_b (all dead after last layer); ends before x_b
    unsigned short* lw_t = (unsigned short*)(ws + 2097152);         // needs 16,384,000 f

    float* out_logits = out;                // 65,536,000
    float* out_mems   = out + 65536000;     // 33,554,432
    float* out_times  = out + 99090432;     // 8,192

    embed_kernel<<<BC * SEQC, 256, 0, stream>>>(tokens, token_emb, x);
    times_init_kernel<<<32, 256, 0, stream>>>(times, out_times, aux);

    for (int d = 0; d < 4; ++d) {
        const float* mem_d = mems + (size_t)d * BC * MC * DIMC;
        prep_kernel<<<PREP_TOT, 256, 0, stream>>>(
            mem_d, x, expire_W + d * DIMC, expire_b + d, exps, aux,
            mem_b, out_mems + (size_t)d * BC * MC * DIMC,
            ln1_g + d * DIMC, ln1_b + d * DIMC, xn_b,
            Wq + (size_t)d * DIMC * DIMC, Wkv + (size_t)d * DIMC * 2 * DIMC,
            Wo + (size_t)d * DIMC * DIMC, W1 + (size_t)d * DIMC * 4 * DIMC,
            W2 + (size_t)d * 4 * DIMC * DIMC,
            wq_t, wkv_t, wo_t, w1_t, w2_t);
        compact_kernel<<<BC, 64, 0, stream>>>(exps, times + d * MC, cidx, em_c, cnt);
        qkv_gemm_kernel<<<1152, 256, 0, stream>>>(xn_b, mem_b, wq_t, wkv_t,
                                                  cidx, cnt, qb_b, kv_b, vTl, vTc);
        attn_mfma_kernel<<<512, 256, 0, stream>>>(
            qb_b, kv_b, vTl, vTc, cidx, em_c, cnt, attn_b);
        gemm64_kernel<<<dim3(8, 32), 256, 0, stream>>>(
            attn_b, wo_t, bo + d * DIMC, x, x, nullptr, DIMC);
        ln_kernel<<<BC * SEQC, 256, 0, stream>>>(x, ln2_g + d * DIMC, ln2_b + d * DIMC, xn_b);
        ffn1_kernel<<<dim3(32, 16), 256, 0, stream>>>(xn_b, w1_t, b1 + d * 4 * DIMC, ffn_b);
        if (d < 3) {
            gemm64_kernel<<<dim3(8, 32), 256, 0, stream>>>(
                ffn_b, w2_t, b2 + d * DIMC, x, x, nullptr, 4 * DIMC);
        } else {
            gemm64_kernel<<<dim3(8, 32), 256, 0, stream>>>(
                ffn_b, w2_t, b2 + d * DIMC, x, nullptr, x_b, 4 * DIMC);
        }
    }

    wt_kernel<<<dim3(1000, 32), 256, 0, stream>>>(logits_W, lw_t, DIMC, VOCABC);
    logits_kernel<<<1000, 512, 0, stream>>>(x_b, lw_t, logits_b, out_logits);
    aux_write_kernel<<<1, 1, 0, stream>>>(aux, out + 99098624);
}

// Round 19
// 1491.212 us; speedup vs baseline: 1.1665x; 1.0534x over previous
//
#include <hip/hip_runtime.h>
#include <cmath>

// Problem constants
#define DIMC   1024
#define SEQC   512
#define BC     4
#define MC     2048      // MAXMEM
#define CTXC   2560      // MC + SEQC
#define HEADSC 16
#define DHC    64
#define VOCABC 32000
#define MAXC   512       // compact-slot capacity (live keys ~64)

using short8 = __attribute__((ext_vector_type(8))) short;
using f32x4  = __attribute__((ext_vector_type(4))) float;
using u16x4  = __attribute__((ext_vector_type(4))) unsigned short;
using u16x8  = __attribute__((ext_vector_type(8))) unsigned short;

__device__ __forceinline__ unsigned short f2bf(float f) {
    unsigned u = __float_as_uint(f);
    unsigned r = (u + 0x7fffu + ((u >> 16) & 1u)) >> 16;
    return (unsigned short)r;
}

__device__ __forceinline__ void glds16(const unsigned short* g, char* l) {
    __builtin_amdgcn_global_load_lds(
        (const __attribute__((address_space(1))) void*)g,
        (__attribute__((address_space(3))) void*)l, 16, 0, 0);
}

// ---------------- embed ----------------
__global__ __launch_bounds__(256) void embed_kernel(const int* __restrict__ tokens,
                                                    const float* __restrict__ emb,
                                                    float* __restrict__ x) {
    int row = blockIdx.x;
    int tok = tokens[row];
    const float4 v = *(const float4*)(emb + (size_t)tok * DIMC + threadIdx.x * 4);
    *(float4*)(x + (size_t)row * DIMC + threadIdx.x * 4) = v;
}

// ---------------- new_times + aux zero ----------------
__global__ __launch_bounds__(256) void times_init_kernel(const int* __restrict__ times,
                                                         float* __restrict__ out_times,
                                                         float* __restrict__ aux) {
    int i = blockIdx.x * 256 + threadIdx.x;
    if (i == 0) aux[0] = 0.0f;
    if (i < 4 * MC) {
        int d = i >> 11, m = i & (MC - 1);
        out_times[i] = (m < MC - SEQC) ? (float)(times[d * MC + SEQC + m] + SEQC)
                                       : (float)(MC - 1 - m);
    }
}

// ---------------- fused per-layer prep ----------------
#define PREP_MEM 8192
#define PREP_XC  10240
#define PREP_LN  12288
#define PREP_TOT 24576
__global__ __launch_bounds__(256) void prep_kernel(
    const float* __restrict__ mem_d, const float* __restrict__ x,
    const float* __restrict__ eW, const float* __restrict__ eb,
    float* __restrict__ exps, float* __restrict__ aux,
    unsigned short* __restrict__ mem_b, float* __restrict__ out_mems_d,
    const float* __restrict__ g1, const float* __restrict__ b1v,
    unsigned short* __restrict__ xn_b,
    const float* __restrict__ Wq, const float* __restrict__ Wkv,
    const float* __restrict__ Wo, const float* __restrict__ W1,
    const float* __restrict__ W2,
    unsigned short* __restrict__ wq_t, unsigned short* __restrict__ wkv_t,
    unsigned short* __restrict__ wo_t, unsigned short* __restrict__ w1_t,
    unsigned short* __restrict__ w2_t) {
    __shared__ float sh[1056];
    const int bid = blockIdx.x, tid = threadIdx.x;
    if (bid < PREP_MEM) {
        int row = bid;                       // b*2048 + m
        int m = row & 2047, b = row >> 11;
        const float4 v = *(const float4*)(mem_d + (size_t)row * DIMC + tid * 4);
        const float4 w = *(const float4*)(eW + tid * 4);
        float s = v.x * w.x + v.y * w.y + v.z * w.z + v.w * w.w;
        for (int off = 32; off; off >>= 1) s += __shfl_down(s, off, 64);
        int wid = tid >> 6, lane = tid & 63;
        if (lane == 0) sh[wid] = s;
        u16x4 o = { f2bf(v.x), f2bf(v.y), f2bf(v.z), f2bf(v.w) };
        *(u16x4*)(mem_b + (size_t)row * DIMC + tid * 4) = o;
        if (m >= SEQC)
            *(float4*)(out_mems_d + ((size_t)(b * MC + m - SEQC)) * DIMC + tid * 4) = v;
        __syncthreads();
        if (tid == 0) {
            float z = sh[0] + sh[1] + sh[2] + sh[3] + eb[0];
            float e = (float)MC / (1.0f + expf(-z));
            exps[row] = e;
            atomicAdd(aux, e * (1e-6f / (float)SEQC));
        }
    } else if (bid < PREP_XC) {
        int r = bid - PREP_MEM;              // b*512 + i
        int b = r >> 9, i = r & 511;
        const float4 v = *(const float4*)(x + (size_t)r * DIMC + tid * 4);
        *(float4*)(out_mems_d + ((size_t)(b * MC + MC - SEQC + i)) * DIMC + tid * 4) = v;
    } else if (bid < PREP_LN) {
        int row = bid - PREP_XC;
        const float4 v = *(const float4*)(x + (size_t)row * DIMC + tid * 4);
        float s = v.x + v.y + v.z + v.w;
        float q = v.x * v.x + v.y * v.y + v.z * v.z + v.w * v.w;
        for (int off = 32; off; off >>= 1) {
            s += __shfl_down(s, off, 64);
            q += __shfl_down(q, off, 64);
        }
        int wid = tid >> 6, lane = tid & 63;
        if (lane == 0) { sh[wid] = s; sh[4 + wid] = q; }
        __syncthreads();
        if (tid == 0) {
            float S = sh[0] + sh[1] + sh[2] + sh[3];
            float Q = sh[4] + sh[5] + sh[6] + sh[7];
            float mu = S / DIMC;
            float var = Q / DIMC - mu * mu;
            sh[8] = mu;
            sh[9] = rsqrtf(var + 1e-5f);
        }
        __syncthreads();
        float mu = sh[8], rstd = sh[9];
        const float4 gg = *(const float4*)(g1 + tid * 4);
        const float4 bb = *(const float4*)(b1v + tid * 4);
        u16x4 o = { f2bf((v.x - mu) * rstd * gg.x + bb.x),
                    f2bf((v.y - mu) * rstd * gg.y + bb.y),
                    f2bf((v.z - mu) * rstd * gg.z + bb.z),
                    f2bf((v.w - mu) * rstd * gg.w + bb.w) };
        *(u16x4*)(xn_b + (size_t)row * DIMC + tid * 4) = o;
    } else {
        int t = bid - PREP_LN;
        const float* W; unsigned short* Wt; int K, N, tx, ty;
        if (t < 1024)      { W = Wq;  Wt = wq_t;  K = 1024; N = 1024; tx = t & 31;  ty = t >> 5; }
        else if (t < 3072) { int u = t - 1024; W = Wkv; Wt = wkv_t; K = 1024; N = 2048; tx = u & 63;  ty = u >> 6; }
        else if (t < 4096) { int u = t - 3072; W = Wo;  Wt = wo_t;  K = 1024; N = 1024; tx = u & 31;  ty = u >> 5; }
        else if (t < 8192) { int u = t - 4096; W = W1;  Wt = w1_t;  K = 1024; N = 4096; tx = u & 127; ty = u >> 7; }
        else               { int u = t - 8192; W = W2;  Wt = w2_t;  K = 4096; N = 1024; tx = u & 31;  ty = u >> 5; }
        int n0 = tx * 32, k0 = ty * 32;
        int r = tid >> 3, c = (tid & 7) * 4;
        const float4 v = *(const float4*)(W + (size_t)(k0 + r) * N + n0 + c);
        sh[r * 33 + c] = v.x; sh[r * 33 + c + 1] = v.y;
        sh[r * 33 + c + 2] = v.z; sh[r * 33 + c + 3] = v.w;
        __syncthreads();
        u16x4 o = { f2bf(sh[(c + 0) * 33 + r]), f2bf(sh[(c + 1) * 33 + r]),
                    f2bf(sh[(c + 2) * 33 + r]), f2bf(sh[(c + 3) * 33 + r]) };
        *(u16x4*)(Wt + (size_t)(n0 + r) * K + k0 + c) = o;
    }
}

// ---------------- compact live memory keys (deterministic ballot scan) ----------------
__global__ __launch_bounds__(64) void compact_kernel(
    const float* __restrict__ exps, const int* __restrict__ times_d,
    int* __restrict__ cidx, float* __restrict__ em_c, int* __restrict__ cnt) {
    int b = blockIdx.x, lane = threadIdx.x;
    int c = 0;
    for (int it = 0; it < 32; ++it) {
        int j = it * 64 + lane;
        float e = exps[b * MC + j];
        float rr = (e - (float)times_d[j]) * (1.0f / 128.0f) + 1.0f;
        float em = fminf(fmaxf(rr, 0.0f), 1.0f);
        unsigned long long mk = __ballot(em > 0.0f);
        int pos = c + __popcll(mk & ((1ull << lane) - 1ull));
        if (em > 0.0f) {
            cidx[b * 2048 + pos] = j;
            em_c[b * 2048 + pos] = em;
        }
        c += __popcll(mk);
    }
    int padded = (c + 63) & ~63;
    int fill_to = padded < MAXC ? MAXC : padded;
    for (int p = c + lane; p < fill_to; p += 64) {
        cidx[b * 2048 + p] = 0;     // valid row; em=0 kills contribution
        em_c[b * 2048 + p] = 0.0f;
    }
    int tiles = padded >> 6;
    if (tiles > (MAXC >> 6)) tiles = MAXC >> 6;
    if (lane == 0) cnt[b] = tiles;
}

// ---------------- LayerNorm (fp32 in, bf16 out) — LN2 ----------------
__global__ __launch_bounds__(256) void ln_kernel(const float* __restrict__ in,
                                                 const float* __restrict__ g,
                                                 const float* __restrict__ b,
                                                 unsigned short* __restrict__ outb) {
    int row = blockIdx.x;
    int tid = threadIdx.x;
    const float4 v = *(const float4*)(in + (size_t)row * DIMC + tid * 4);
    float s = v.x + v.y + v.z + v.w;
    float q = v.x * v.x + v.y * v.y + v.z * v.z + v.w * v.w;
    for (int off = 32; off; off >>= 1) {
        s += __shfl_down(s, off, 64);
        q += __shfl_down(q, off, 64);
    }
    __shared__ float ss[4], sq[4];
    int wid = tid >> 6, lane = tid & 63;
    if (lane == 0) { ss[wid] = s; sq[wid] = q; }
    __syncthreads();
    if (tid == 0) {
        float S = ss[0] + ss[1] + ss[2] + ss[3];
        float Q = sq[0] + sq[1] + sq[2] + sq[3];
        float mu = S / DIMC;
        float var = Q / DIMC - mu * mu;
        ss[0] = mu;
        sq[0] = rsqrtf(var + 1e-5f);
    }
    __syncthreads();
    float mu = ss[0], rstd = sq[0];
    const float4 gg = *(const float4*)(g + tid * 4);
    const float4 bb = *(const float4*)(b + tid * 4);
    u16x4 o = { f2bf((v.x - mu) * rstd * gg.x + bb.x),
                f2bf((v.y - mu) * rstd * gg.y + bb.y),
                f2bf((v.z - mu) * rstd * gg.z + bb.z),
                f2bf((v.w - mu) * rstd * gg.w + bb.w) };
    *(u16x4*)(outb + (size_t)row * DIMC + tid * 4) = o;
}

// ---------------- weight convert + transpose (logits_W only) ----------------
__global__ __launch_bounds__(256) void wt_kernel(const float* __restrict__ W,
                                                 unsigned short* __restrict__ Wt,
                                                 int K, int N) {
    __shared__ float t[32][33];
    int tid = threadIdx.x;
    int n0 = blockIdx.x * 32, k0 = blockIdx.y * 32;
    int r = tid >> 3, c = (tid & 7) * 4;
    const float4 v = *(const float4*)(W + (size_t)(k0 + r) * N + n0 + c);
    t[r][c] = v.x; t[r][c + 1] = v.y; t[r][c + 2] = v.z; t[r][c + 3] = v.w;
    __syncthreads();
    u16x4 o = { f2bf(t[c + 0][r]), f2bf(t[c + 1][r]),
                f2bf(t[c + 2][r]), f2bf(t[c + 3][r]) };
    *(u16x4*)(Wt + (size_t)(n0 + r) * K + k0 + c) = o;
}

// ---------------- bf16 MFMA GEMM body — BK=64, counted-vmcnt + T2 swizzle ----------------
// KS = row stride of A and Wt in elements (decoupled from K loop bound -> split-K).
template<int AMODE, bool BIAS, bool GELU, bool RES, int OMODE, int RT>
__device__ __forceinline__ void gemm_body(
    unsigned short* As, unsigned short* Bs,
    const unsigned short* __restrict__ A, const int* __restrict__ gidx,
    const unsigned short* __restrict__ Wt, const float* __restrict__ bias,
    const float* __restrict__ res, float* __restrict__ Cf,
    unsigned short* __restrict__ Cb, int K, int N, int bx, int by, int KS) {
    constexpr int MF = RT / 32;
    const int tid = threadIdx.x;
    const int lane = tid & 63, wave = tid >> 6;
    const int row0 = by * RT, col0 = bx * 128;

    const int seg = tid & 3;
    const int rr0 = tid >> 2;
    const int sseg8 = (seg ^ ((rr0 >> 1) & 3)) * 8;   // source pre-swizzle (elements)
    const unsigned short* arow[RT / 64];
    #pragma unroll
    for (int p = 0; p < RT / 64; ++p) {
        int r = row0 + p * 64 + rr0;
        if (AMODE == 2) {
            int b = r >> 9, slot = r & (MAXC - 1);
            arow[p] = A + ((size_t)(b * 2048 + gidx[b * 2048 + slot])) * KS;
        } else {
            arow[p] = A + (size_t)r * KS;
        }
        arow[p] += sseg8;
    }
    const unsigned short* brow[2];
    #pragma unroll
    for (int p = 0; p < 2; ++p)
        brow[p] = Wt + (size_t)(col0 + p * 64 + rr0) * KS + sseg8;

    char* lA = (char*)As + (tid & 192) * 16;
    char* lB = (char*)Bs + (tid & 192) * 16;

    // buffer q = planes {q*2, q*2+1}; A plane = RT*64 bytes, B plane = 8192 bytes
    auto stage = [&](int k0, int q) {
        #pragma unroll
        for (int kk = 0; kk < 2; ++kk) {
            char* a = lA + (q * 2 + kk) * (RT * 64);
            glds16(arow[0] + k0 + kk * 32, a);
            if (RT == 128) glds16(arow[1] + k0 + kk * 32, a + 4096);
            char* bp = lB + (q * 2 + kk) * 8192;
            glds16(brow[0] + k0 + kk * 32, bp);
            glds16(brow[1] + k0 + kk * 32, bp + 4096);
        }
    };

    f32x4 acc[MF][4] = {};

    const int wr = (wave >> 1) * (RT / 2), wc = (wave & 1) * 64;
    const int fr = lane & 15;
    const int g4 = lane >> 4;
    const int kA8 = (g4 ^ (((wr + fr) >> 1) & 3)) * 8;   // swizzled read slot (elements)
    const int kB8 = (g4 ^ (((wc + fr) >> 1) & 3)) * 8;

    stage(0, 0);
    int cur = 0;
    for (int k0 = 0; k0 < K; k0 += 64) {
        if (k0 + 64 < K) {
            stage(k0 + 64, cur ^ 1);
            if (RT == 128) asm volatile("s_waitcnt vmcnt(8)" ::: "memory");
            else           asm volatile("s_waitcnt vmcnt(6)" ::: "memory");
        } else {
            asm volatile("s_waitcnt vmcnt(0)" ::: "memory");
        }
        __builtin_amdgcn_s_barrier();
        __builtin_amdgcn_sched_barrier(0);
        #pragma unroll
        for (int kk = 0; kk < 2; ++kk) {
            const unsigned short* Ar = As + (cur * 2 + kk) * (RT * 32)
                                       + (size_t)(wr + fr) * 32 + kA8;
            const unsigned short* Br = Bs + (cur * 2 + kk) * (128 * 32)
                                       + (size_t)(wc + fr) * 32 + kB8;
            short8 a[MF], b[4];
            #pragma unroll
            for (int m = 0; m < MF; ++m) a[m] = *(const short8*)(Ar + m * 16 * 32);
            #pragma unroll
            for (int n = 0; n < 4; ++n) b[n] = *(const short8*)(Br + n * 16 * 32);
            #pragma unroll
            for (int m = 0; m < MF; ++m)
                #pragma unroll
                for (int n = 0; n < 4; ++n)
                    acc[m][n] = __builtin_amdgcn_mfma_f32_16x16x32_bf16(a[m], b[n], acc[m][n], 0, 0, 0);
        }
        __builtin_amdgcn_s_barrier();
        cur ^= 1;
    }

    const int orow = row0 + wr + (lane >> 4) * 4;
    const int ocol = col0 + wc + fr;
    if (OMODE >= 3) {
        #pragma unroll
        for (int n = 0; n < 4; ++n) {
            int c = ocol + n * 16;
            #pragma unroll
            for (int m = 0; m < MF; ++m) {
                int r0 = orow + m * 16;
                int b = r0 >> 9, i = r0 & 511;
                size_t addr = (OMODE == 3)
                    ? ((size_t)(b * 1024 + c)) * 512 + i
                    : ((size_t)(b * 1024 + c)) * MAXC + i;
                u16x4 o = { f2bf(acc[m][n][0]), f2bf(acc[m][n][1]),
                            f2bf(acc[m][n][2]), f2bf(acc[m][n][3]) };
                *(u16x4*)(Cb + addr) = o;
            }
        }
        return;
    }
    #pragma unroll
    for (int n = 0; n < 4; ++n) {
        int c = ocol + n * 16;
        float bv = BIAS ? bias[c] : 0.0f;
        #pragma unroll
        for (int m = 0; m < MF; ++m) {
            #pragma unroll
            for (int i = 0; i < 4; ++i) {
                int r0 = orow + m * 16 + i;
                size_t orr = r0;
                if (OMODE == 1) orr = (size_t)r0 + (size_t)(r0 >> 11) * 512;
                if (OMODE == 2) orr = (size_t)r0 + (size_t)(r0 >> 9) * 2048 + 2048;
                size_t idx = orr * N + c;
                float v = acc[m][n][i] + bv;
                if (GELU) v = 0.5f * v * (1.0f + erff(v * 0.70710678118f));
                if (RES) v += res[idx];
                if (Cf) Cf[idx] = v;
                if (Cb) Cb[idx] = f2bf(v);
            }
        }
    }
}

// Fused: Q(128) + local-K(128) + mem-K(512) + local-V transposed(128) + compact-V transposed(256)
__global__ __launch_bounds__(256) void qkv_gemm_kernel(
    const unsigned short* __restrict__ xn_b, const unsigned short* __restrict__ mem_b,
    const unsigned short* __restrict__ wq_t, const unsigned short* __restrict__ wkv_t,
    const int* __restrict__ cidx, const int* __restrict__ cnt,
    unsigned short* __restrict__ qb, unsigned short* __restrict__ kvb,
    unsigned short* __restrict__ vTl, unsigned short* __restrict__ vTc) {
    __shared__ unsigned short As[4 * 128 * 32];
    __shared__ unsigned short Bs[4 * 128 * 32];
    int id = blockIdx.x;
    if (id < 128) {
        gemm_body<0, false, false, false, 0, 128>(As, Bs, xn_b, nullptr, wq_t,
            nullptr, nullptr, nullptr, qb, 1024, 1024, id & 7, id >> 3, 1024);
    } else if (id < 256) {
        id -= 128;  // local rows -> ctx rows, K half of wkv
        gemm_body<0, false, false, false, 2, 128>(As, Bs, xn_b, nullptr, wkv_t,
            nullptr, nullptr, nullptr, kvb, 1024, 1024, id & 7, id >> 3, 1024);
    } else if (id < 768) {
        id -= 256;  // mem rows -> ctx rows, K half of wkv
        gemm_body<0, false, false, false, 1, 128>(As, Bs, mem_b, nullptr, wkv_t,
            nullptr, nullptr, nullptr, kvb, 1024, 1024, id & 7, id >> 3, 1024);
    } else if (id < 896) {
        id -= 768;  // local V -> vTl transposed
        gemm_body<0, false, false, false, 3, 128>(As, Bs, xn_b, nullptr,
            wkv_t + (size_t)1024 * 1024, nullptr, nullptr, nullptr, vTl,
            1024, 1024, id & 7, id >> 3, 1024);
    } else {
        id -= 896;  // compact V: gather mem rows by cidx -> vTc transposed
        int by = id >> 3;
        int b = (by * 64) >> 9, slot0 = (by * 64) & (MAXC - 1);
        if (slot0 >= cnt[b] * 64) return;
        gemm_body<2, false, false, false, 4, 64>(As, Bs, mem_b, cidx,
            wkv_t + (size_t)1024 * 1024, nullptr, nullptr, nullptr, vTc,
            1024, 1024, id & 7, by, 1024);
    }
}

// RT=64 GEMM with bias+residual, N=1024 (Wo)
__global__ __launch_bounds__(256) void gemm64_kernel(
    const unsigned short* __restrict__ A, const unsigned short* __restrict__ Wt,
    const float* __restrict__ bias, const float* __restrict__ res,
    float* __restrict__ Cf, unsigned short* __restrict__ Cb, int K) {
    __shared__ unsigned short As[4 * 64 * 32];
    __shared__ unsigned short Bs[4 * 128 * 32];
    gemm_body<0, true, false, true, 0, 64>(As, Bs, A, nullptr, Wt, bias, res,
        Cf, Cb, K, 1024, blockIdx.x, blockIdx.y, K);
}

// FFN2 split-K partial: z-half computes K=2048 slice (stride 4096), fp32 partials
__global__ __launch_bounds__(256) void ffn2_part_kernel(
    const unsigned short* __restrict__ A, const unsigned short* __restrict__ Wt,
    float* __restrict__ Cp) {
    __shared__ unsigned short As[4 * 64 * 32];
    __shared__ unsigned short Bs[4 * 128 * 32];
    const int z = blockIdx.z;
    gemm_body<0, false, false, false, 0, 64>(As, Bs, A + z * 2048, nullptr,
        Wt + z * 2048, nullptr, nullptr, Cp + (size_t)z * 2097152, nullptr,
        2048, 1024, blockIdx.x, blockIdx.y, 4096);
}

// FFN2 reduce: v = p0 + p1 + bias + res; write x fp32 (d<3) or x_b bf16 (d==3)
__global__ __launch_bounds__(256) void ffn2_red_kernel(
    const float* __restrict__ p0, const float* __restrict__ p1,
    const float* __restrict__ bias, const float* __restrict__ res,
    float* __restrict__ xo, unsigned short* __restrict__ xb) {
    size_t i = (size_t)blockIdx.x * 256 + threadIdx.x;   // float4 index
    float4 a = *(const float4*)(p0 + i * 4);
    float4 b = *(const float4*)(p1 + i * 4);
    float4 r = *(const float4*)(res + i * 4);
    const float4 bv = *(const float4*)(bias + (i & 255) * 4);
    float4 v = { a.x + b.x + bv.x + r.x, a.y + b.y + bv.y + r.y,
                 a.z + b.z + bv.z + r.z, a.w + b.w + bv.w + r.w };
    if (xo) *(float4*)(xo + i * 4) = v;
    if (xb) {
        u16x4 o = { f2bf(v.x), f2bf(v.y), f2bf(v.z), f2bf(v.w) };
        *(u16x4*)(xb + i * 4) = o;
    }
}

// FFN1: gelu, bf16 out
__global__ __launch_bounds__(256) void ffn1_kernel(
    const unsigned short* __restrict__ A, const unsigned short* __restrict__ Wt,
    const float* __restrict__ bias, unsigned short* __restrict__ Cb) {
    __shared__ unsigned short As[4 * 128 * 32];
    __shared__ unsigned short Bs[4 * 128 * 32];
    gemm_body<0, true, true, false, 0, 128>(As, Bs, A, nullptr, Wt, bias, nullptr,
        nullptr, Cb, 1024, 4096, blockIdx.x, blockIdx.y, 1024);
}

// ---------------- logits: 256x256 tile, 512 threads, 8 waves (2x4), counted-vmcnt + T2 swizzle ----------------
__global__ __launch_bounds__(512, 2) void logits_kernel(
    const unsigned short* __restrict__ A, const unsigned short* __restrict__ Wt,
    const float* __restrict__ bias, float* __restrict__ Cf) {
    __shared__ unsigned short As[2 * 256 * 32];
    __shared__ unsigned short Bs[2 * 256 * 32];
    const int L = blockIdx.x;
    const int wid = (L & 7) * 125 + (L >> 3);
    const int ct = wid / 8, rt = wid & 7;
    const int row0 = rt * 256, col0 = ct * 256;
    const int tid = threadIdx.x;
    const int lane = tid & 63, wave = tid >> 6;

    const int seg = tid & 3;
    const int rr0 = tid >> 2;                 // 0..127
    const int sseg8 = (seg ^ ((rr0 >> 1) & 3)) * 8;   // source pre-swizzle
    const unsigned short* arow[2];
    const unsigned short* brow[2];
    #pragma unroll
    for (int p = 0; p < 2; ++p) {
        arow[p] = A + (size_t)(row0 + p * 128 + rr0) * 1024 + sseg8;
        brow[p] = Wt + (size_t)(col0 + p * 128 + rr0) * 1024 + sseg8;
    }
    char* lA = (char*)As + (tid & 448) * 16;  // wave-uniform base (8 waves)
    char* lB = (char*)Bs + (tid & 448) * 16;

    auto stage = [&](int k0, int q) {
        char* a = lA + q * 16384;
        char* bp = lB + q * 16384;
        glds16(arow[0] + k0, a);
        glds16(arow[1] + k0, a + 8192);
        glds16(brow[0] + k0, bp);
        glds16(brow[1] + k0, bp + 8192);
    };

    f32x4 acc[8][4] = {};
    const int wr = (wave >> 2) * 128, wc = (wave & 3) * 64;
    const int fr = lane & 15;
    const int g4 = lane >> 4;
    const int kA8 = (g4 ^ (((wr + fr) >> 1) & 3)) * 8;
    const int kB8 = (g4 ^ (((wc + fr) >> 1) & 3)) * 8;

    stage(0, 0);
    int cur = 0;
    for (int k0 = 0; k0 < 1024; k0 += 32) {
        if (k0 + 32 < 1024) {
            stage(k0 + 32, cur ^ 1);
            asm volatile("s_waitcnt vmcnt(4)" ::: "memory");
        } else {
            asm volatile("s_waitcnt vmcnt(0)" ::: "memory");
        }
        __builtin_amdgcn_s_barrier();
        __builtin_amdgcn_sched_barrier(0);
        const unsigned short* Ar = As + cur * 8192 + (size_t)(wr + fr) * 32 + kA8;
        const unsigned short* Br = Bs + cur * 8192 + (size_t)(wc + fr) * 32 + kB8;
        short8 a[8], b[4];
        #pragma unroll
        for (int m = 0; m < 8; ++m) a[m] = *(const short8*)(Ar + m * 16 * 32);
        #pragma unroll
        for (int n = 0; n < 4; ++n) b[n] = *(const short8*)(Br + n * 16 * 32);
        #pragma unroll
        for (int m = 0; m < 8; ++m)
            #pragma unroll
            for (int n = 0; n < 4; ++n)
                acc[m][n] = __builtin_amdgcn_mfma_f32_16x16x32_bf16(a[m], b[n], acc[m][n], 0, 0, 0);
        __builtin_amdgcn_s_barrier();
        cur ^= 1;
    }

    const int orow = row0 + wr + (lane >> 4) * 4;
    const int ocol = col0 + wc + fr;
    #pragma unroll
    for (int n = 0; n < 4; ++n) {
        int c = ocol + n * 16;
        float bv = bias[c];
        #pragma unroll
        for (int m = 0; m < 8; ++m) {
            #pragma unroll
            for (int i = 0; i < 4; ++i)
                Cf[(size_t)(orow + m * 16 + i) * VOCABC + c] = acc[m][n][i] + bv;
        }
    }
}

// ---------------- 3-phase MFMA flash attention — 128-wide mem double-tiles ----------------
// grid = 512 (8 qt x 16 h x 4 b), XCD-grouped; counted-vmcnt raw-barrier pipelines.
// Phase 1: 16 double-tiles of 128 mem keys (denominator only). Phase 2: 64-wide causal
// local tiles with V. Phase 3: compact live-mem tiles. Softmax in base-2.
#define CSC 0.18033688011112042f
__global__ __launch_bounds__(256) void attn_mfma_kernel(
    const unsigned short* __restrict__ qb,
    const unsigned short* __restrict__ kvb,   // K-only [b][2560][1024]
    const unsigned short* __restrict__ vTl,   // [b*1024+d][512] local V transposed
    const unsigned short* __restrict__ vTc,   // [b*1024+d][MAXC] compact V transposed
    const int* __restrict__ cidx,
    const float* __restrict__ em_c,
    const int* __restrict__ cnt,
    unsigned short* __restrict__ outb) {
    __shared__ unsigned short K_s[2][128 * 64];
    __shared__ unsigned short V_s[2][64 * 64];
    __shared__ unsigned short p_s[4][16][72];
    __shared__ float em_s[64];
    const int tid = threadIdx.x;
    const int lane = tid & 63, wave = tid >> 6;
    const int L = blockIdx.x;
    const int ix = L >> 3;
    const int qt = ix & 7;
    const int gidx = (L & 7) * 8 + (ix >> 3);   // same (h,b) group on same XCD
    const int h = gidx & 15, b = gidx >> 4;
    const int fr = lane & 15, g = lane >> 4;
    const int gq = qt * 64 + wave * 16;

    short8 aq[2];
    {
        const unsigned short* qp = qb + ((size_t)(b * SEQC + gq + fr)) * DIMC + h * DHC + g * 8;
        aq[0] = *(const short8*)qp;
        aq[1] = *(const short8*)(qp + 32);
    }

    const int sr = tid >> 3, ss = tid & 7;       // sr in [0,32)
    const int sw = (ss ^ (sr & 7)) * 8;          // source pre-swizzle (p*32 keeps r&7)
    const int wbase = (tid & 192) * 16;          // wave-uniform LDS byte base (4 waves)

    f32x4 acc_o[4] = {};
    float m_q = -1e30f, l_q = 0.0f;              // log2 domain

    // ---- phase 1: 16 double-tiles of 128 mem keys, denominator only ----
    auto stageM = [&](int t, int q) {
        const int jbase = t * 128;
        #pragma unroll
        for (int p = 0; p < 4; ++p) {
            int r = sr + p * 32;
            glds16(kvb + ((size_t)(b * CTXC + jbase + r)) * 1024 + h * DHC + sw,
                   (char*)K_s[q] + wbase + p * 4096);
        }
    };

    stageM(0, 0);
    asm volatile("s_waitcnt vmcnt(0)" ::: "memory");
    __builtin_amdgcn_s_barrier();
    int cur = 0;
    for (int t = 0; t < 16; ++t) {
        if (t + 1 < 16) {
            stageM(t + 1, cur ^ 1);
            asm volatile("s_waitcnt vmcnt(4)" ::: "memory");
        } else {
            asm volatile("s_waitcnt vmcnt(0)" ::: "memory");
        }
        __builtin_amdgcn_s_barrier();
        __builtin_amdgcn_sched_barrier(0);

        f32x4 sT[2][4] = {};
        #pragma unroll
        for (int c = 0; c < 2; ++c)
            #pragma unroll
            for (int ks = 0; ks < 2; ++ks)
                #pragma unroll
                for (int mf = 0; mf < 4; ++mf) {
                    int row = c * 64 + mf * 16 + fr, sg = (ks * 4 + g) ^ (row & 7);
                    short8 kk = *(const short8*)((const char*)K_s[cur] + row * 128 + sg * 16);
                    sT[c][mf] = __builtin_amdgcn_mfma_f32_16x16x32_bf16(kk, aq[ks], sT[c][mf], 0, 0, 0);
                }

        float mx = sT[0][0][0];
        #pragma unroll
        for (int c = 0; c < 2; ++c)
            #pragma unroll
            for (int mf = 0; mf < 4; ++mf)
                #pragma unroll
                for (int i = 0; i < 4; ++i) mx = fmaxf(mx, sT[c][mf][i]);
        mx *= CSC;
        mx = fmaxf(mx, __shfl_xor(mx, 16, 64));
        mx = fmaxf(mx, __shfl_xor(mx, 32, 64));
        float mnew = fmaxf(m_q, mx);
        float fs = __builtin_amdgcn_exp2f(m_q - mnew);
        m_q = mnew;
        float ps = 0.0f;
        #pragma unroll
        for (int c = 0; c < 2; ++c)
            #pragma unroll
            for (int mf = 0; mf < 4; ++mf)
                #pragma unroll
                for (int i = 0; i < 4; ++i)
                    ps += __builtin_amdgcn_exp2f(sT[c][mf][i] * CSC - mnew);
        ps += __shfl_xor(ps, 16, 64);
        ps += __shfl_xor(ps, 32, 64);
        l_q = l_q * fs + ps;

        __builtin_amdgcn_s_barrier();
        cur ^= 1;
    }

    // ---- phase 2: local causal tiles (64-wide, with V) ----
    auto stageL = [&](int lt, int q) {
        const int jbase = MC + lt * 64;
        #pragma unroll
        for (int p = 0; p < 2; ++p) {
            int r = sr + p * 32;
            glds16(kvb + ((size_t)(b * CTXC + jbase + r)) * 1024 + h * DHC + sw,
                   (char*)K_s[q] + wbase + p * 4096);
            glds16(vTl + ((size_t)(b * 1024 + h * DHC + r)) * 512 + lt * 64 + sw,
                   (char*)V_s[q] + wbase + p * 4096);
        }
    };

    const int nlt = qt + 1;
    stageL(0, 0);
    asm volatile("s_waitcnt vmcnt(0)" ::: "memory");
    __builtin_amdgcn_s_barrier();
    cur = 0;
    for (int lt = 0; lt < nlt; ++lt) {
        if (lt + 1 < nlt) {
            stageL(lt + 1, cur ^ 1);
            asm volatile("s_waitcnt vmcnt(4)" ::: "memory");
        } else {
            asm volatile("s_waitcnt vmcnt(0)" ::: "memory");
        }
        __builtin_amdgcn_s_barrier();
        __builtin_amdgcn_sched_barrier(0);

        f32x4 sT[4] = {};
        #pragma unroll
        for (int ks = 0; ks < 2; ++ks)
            #pragma unroll
            for (int mf = 0; mf < 4; ++mf) {
                int row = mf * 16 + fr, sg = (ks * 4 + g) ^ (row & 7);
                short8 kk = *(const short8*)((const char*)K_s[cur] + row * 128 + sg * 16);
                sT[mf] = __builtin_amdgcn_mfma_f32_16x16x32_bf16(kk, aq[ks], sT[mf], 0, 0, 0);
            }

        const int kq = gq + fr - lt * 64;
        float sv[4][4];
        #pragma unroll
        for (int mf = 0; mf < 4; ++mf)
            #pragma unroll
            for (int i = 0; i < 4; ++i) {
                int kl = mf * 16 + g * 4 + i;
                sv[mf][i] = (kl <= kq) ? sT[mf][i] * CSC : -1e30f;
            }
        float mx = sv[0][0];
        #pragma unroll
        for (int mf = 0; mf < 4; ++mf)
            #pragma unroll
            for (int i = 0; i < 4; ++i) mx = fmaxf(mx, sv[mf][i]);
        mx = fmaxf(mx, __shfl_xor(mx, 16, 64));
        mx = fmaxf(mx, __shfl_xor(mx, 32, 64));
        float mnew = fmaxf(m_q, mx);
        float fs = __builtin_amdgcn_exp2f(m_q - mnew);
        m_q = mnew;
        float ps = 0.0f;
        #pragma unroll
        for (int mf = 0; mf < 4; ++mf)
            #pragma unroll
            for (int i = 0; i < 4; ++i) {
                float pe = __builtin_amdgcn_exp2f(sv[mf][i] - mnew);
                ps += pe;
                p_s[wave][fr][mf * 16 + g * 4 + i] = f2bf(pe);
            }
        ps += __shfl_xor(ps, 16, 64);
        ps += __shfl_xor(ps, 32, 64);
        l_q = l_q * fs + ps;
        float fsr[4];
        #pragma unroll
        for (int i = 0; i < 4; ++i) fsr[i] = __shfl(fs, g * 4 + i, 64);
        #pragma unroll
        for (int n = 0; n < 4; ++n)
            #pragma unroll
            for (int i = 0; i < 4; ++i) acc_o[n][i] *= fsr[i];
        asm volatile("s_waitcnt lgkmcnt(0)" ::: "memory");
        #pragma unroll
        for (int ks = 0; ks < 2; ++ks) {
            short8 ap = *(const short8*)&p_s[wave][fr][ks * 32 + g * 8];
            #pragma unroll
            for (int n = 0; n < 4; ++n) {
                int row = n * 16 + fr, sg = (ks * 4 + g) ^ (row & 7);
                short8 bv = *(const short8*)((const char*)V_s[cur] + row * 128 + sg * 16);
                acc_o[n] = __builtin_amdgcn_mfma_f32_16x16x32_bf16(ap, bv, acc_o[n], 0, 0, 0);
            }
        }
        __builtin_amdgcn_s_barrier();
        cur ^= 1;
    }

    // ---- phase 3: compact live-mem tiles (final m,l; no m/l update) ----
    const int nct = cnt[b];
    for (int ct = 0; ct < nct; ++ct) {
        __syncthreads();
        #pragma unroll
        for (int p = 0; p < 2; ++p) {
            int r = sr + p * 32;
            int row = cidx[b * 2048 + ct * 64 + r];
            glds16(kvb + ((size_t)(b * CTXC + row)) * 1024 + h * DHC + sw,
                   (char*)K_s[0] + wbase + p * 4096);
            glds16(vTc + ((size_t)(b * 1024 + h * DHC + r)) * MAXC + ct * 64 + sw,
                   (char*)V_s[0] + wbase + p * 4096);
        }
        if (tid < 64) em_s[tid] = em_c[b * 2048 + ct * 64 + tid];
        __syncthreads();
        f32x4 sT[4] = {};
        #pragma unroll
        for (int ks = 0; ks < 2; ++ks)
            #pragma unroll
            for (int mf = 0; mf < 4; ++mf) {
                int row = mf * 16 + fr, sg = (ks * 4 + g) ^ (row & 7);
                short8 kk = *(const short8*)((const char*)K_s[0] + row * 128 + sg * 16);
                sT[mf] = __builtin_amdgcn_mfma_f32_16x16x32_bf16(kk, aq[ks], sT[mf], 0, 0, 0);
            }
        #pragma unroll
        for (int mf = 0; mf < 4; ++mf)
            #pragma unroll
            for (int i = 0; i < 4; ++i) {
                int key = mf * 16 + g * 4 + i;
                float pe = __builtin_amdgcn_exp2f(sT[mf][i] * CSC - m_q) * em_s[key];
                p_s[wave][fr][key] = f2bf(pe);
            }
        asm volatile("s_waitcnt lgkmcnt(0)" ::: "memory");
        #pragma unroll
        for (int ks = 0; ks < 2; ++ks) {
            short8 ap = *(const short8*)&p_s[wave][fr][ks * 32 + g * 8];
            #pragma unroll
            for (int n = 0; n < 4; ++n) {
                int row = n * 16 + fr, sg = (ks * 4 + g) ^ (row & 7);
                short8 bv = *(const short8*)((const char*)V_s[0] + row * 128 + sg * 16);
                acc_o[n] = __builtin_amdgcn_mfma_f32_16x16x32_bf16(ap, bv, acc_o[n], 0, 0, 0);
            }
        }
    }

    float linv = 1.0f / l_q;
    float invr[4];
    #pragma unroll
    for (int i = 0; i < 4; ++i) invr[i] = __shfl(linv, g * 4 + i, 64);
    #pragma unroll
    for (int n = 0; n < 4; ++n) {
        #pragma unroll
        for (int i = 0; i < 4; ++i) {
            size_t idx = ((size_t)(b * SEQC + gq + g * 4 + i)) * DIMC + h * DHC + n * 16 + fr;
            outb[idx] = f2bf(acc_o[n][i] * invr[i]);
        }
    }
}

// ---------------- aux writeback ----------------
__global__ void aux_write_kernel(const float* __restrict__ aux, float* __restrict__ dst) {
    dst[0] = aux[0];
}

extern "C" void kernel_launch(void* const* d_in, const int* in_sizes, int n_in,
                              void* d_out, int out_size, void* d_ws, size_t ws_size,
                              hipStream_t stream) {
    const int*   tokens    = (const int*)d_in[0];
    const float* mems      = (const float*)d_in[1];
    const int*   times     = (const int*)d_in[2];
    const float* token_emb = (const float*)d_in[3];
    const float* expire_W  = (const float*)d_in[4];
    const float* expire_b  = (const float*)d_in[5];
    const float* ln1_g     = (const float*)d_in[6];
    const float* ln1_b     = (const float*)d_in[7];
    const float* Wq        = (const float*)d_in[8];
    const float* Wkv       = (const float*)d_in[9];
    const float* Wo        = (const float*)d_in[10];
    const float* bo        = (const float*)d_in[11];
    const float* ln2_g     = (const float*)d_in[12];
    const float* ln2_b     = (const float*)d_in[13];
    const float* W1        = (const float*)d_in[14];
    const float* b1        = (const float*)d_in[15];
    const float* W2        = (const float*)d_in[16];
    const float* b2        = (const float*)d_in[17];
    const float* logits_W  = (const float*)d_in[18];
    const float* logits_b  = (const float*)d_in[19];

    float* out = (float*)d_out;
    float* ws  = (float*)d_ws;

    // workspace layout (float offsets)
    float* x = ws;                                                  //  0       (2,097,152)
    unsigned short* qb_b  = (unsigned short*)(ws + 2097152);        //  1,048,576 f
    unsigned short* kv_b  = (unsigned short*)(ws + 3145728);        //  5,242,880 f (K-only)
    unsigned short* vTl   = (unsigned short*)(ws + 8388608);        //  1,048,576 f
    unsigned short* vTc   = (unsigned short*)(ws + 9437184);        //  1,048,576 f
    unsigned short* xn_b  = (unsigned short*)(ws + 10485760);       //  1,048,576 f
    unsigned short* attn_b= (unsigned short*)(ws + 11534336);       //  1,048,576 f
    unsigned short* ffn_b = (unsigned short*)(ws + 12582912);       //  4,194,304 f
    unsigned short* mem_b = (unsigned short*)(ws + 16777216);       //  4,194,304 f
    unsigned short* x_b   = (unsigned short*)(ws + 20971520);       //  1,048,576 f
    unsigned short* wq_t  = (unsigned short*)(ws + 22020096);       //    524,288 f
    unsigned short* wkv_t = (unsigned short*)(ws + 22544384);       //  1,048,576 f
    unsigned short* wo_t  = (unsigned short*)(ws + 23592960);       //    524,288 f
    unsigned short* w1_t  = (unsigned short*)(ws + 24117248);       //  2,097,152 f
    unsigned short* w2_t  = (unsigned short*)(ws + 26214400);       //  2,097,152 f
    float* exps = ws + 28311552;                                    //      8,192 f
    float* aux  = ws + 28319744;                                    //         16 f
    int*   cidx = (int*)(ws + 28319760);                            //      8,192
    float* em_c = ws + 28327952;                                    //      8,192
    int*   cnt  = (int*)(ws + 28336144);                            //          4
    // FFN2 split-K partials alias kv_b region (K cache dead after attention)
    float* pbuf = ws + 3145728;                                     // 2 x 2,097,152 f
    // logits_W^T aliases qb_b..mem_b (all dead after last layer); ends before x_b
    unsigned short* lw_t = (unsigned short*)(ws + 2097152);         // needs 16,384,000 f

    float* out_logits = out;                // 65,536,000
    float* out_mems   = out + 65536000;     // 33,554,432
    float* out_times  = out + 99090432;     // 8,192

    embed_kernel<<<BC * SEQC, 256, 0, stream>>>(tokens, token_emb, x);
    times_init_kernel<<<32, 256, 0, stream>>>(times, out_times, aux);

    for (int d = 0; d < 4; ++d) {
        const float* mem_d = mems + (size_t)d * BC * MC * DIMC;
        prep_kernel<<<PREP_TOT, 256, 0, stream>>>(
            mem_d, x, expire_W + d * DIMC, expire_b + d, exps, aux,
            mem_b, out_mems + (size_t)d * BC * MC * DIMC,
            ln1_g + d * DIMC, ln1_b + d * DIMC, xn_b,
            Wq + (size_t)d * DIMC * DIMC, Wkv + (size_t)d * DIMC * 2 * DIMC,
            Wo + (size_t)d * DIMC * DIMC, W1 + (size_t)d * DIMC * 4 * DIMC,
            W2 + (size_t)d * 4 * DIMC * DIMC,
            wq_t, wkv_t, wo_t, w1_t, w2_t);
        compact_kernel<<<BC, 64, 0, stream>>>(exps, times + d * MC, cidx, em_c, cnt);
        qkv_gemm_kernel<<<1152, 256, 0, stream>>>(xn_b, mem_b, wq_t, wkv_t,
                                                  cidx, cnt, qb_b, kv_b, vTl, vTc);
        attn_mfma_kernel<<<512, 256, 0, stream>>>(
            qb_b, kv_b, vTl, vTc, cidx, em_c, cnt, attn_b);
        gemm64_kernel<<<dim3(8, 32), 256, 0, stream>>>(
            attn_b, wo_t, bo + d * DIMC, x, x, nullptr, DIMC);
        ln_kernel<<<BC * SEQC, 256, 0, stream>>>(x, ln2_g + d * DIMC, ln2_b + d * DIMC, xn_b);
        ffn1_kernel<<<dim3(32, 16), 256, 0, stream>>>(xn_b, w1_t, b1 + d * 4 * DIMC, ffn_b);
        ffn2_part_kernel<<<dim3(8, 32, 2), 256, 0, stream>>>(ffn_b, w2_t, pbuf);
        if (d < 3) {
            ffn2_red_kernel<<<2048, 256, 0, stream>>>(
                pbuf, pbuf + 2097152, b2 + d * DIMC, x, x, nullptr);
        } else {
            ffn2_red_kernel<<<2048, 256, 0, stream>>>(
                pbuf, pbuf + 2097152, b2 + d * DIMC, x, nullptr, x_b);
        }
    }

    wt_kernel<<<dim3(1000, 32), 256, 0, stream>>>(logits_W, lw_t, DIMC, VOCABC);
    logits_kernel<<<1000, 512, 0, stream>>>(x_b, lw_t, logits_b, out_logits);
    aux_write_kernel<<<1, 1, 0, stream>>>(aux, out + 99098624);
}